// Round 9
// baseline (773.239 us; speedup 1.0000x reference)
//
#include <hip/hip_runtime.h>

typedef unsigned int uint;
typedef unsigned short ushort;
typedef __fp16 half2_t __attribute__((ext_vector_type(2)));
typedef __fp16 half8_t __attribute__((ext_vector_type(8)));
typedef float floatx4 __attribute__((ext_vector_type(4)));

#define SEQ 512
#define BATCH 128
#define HID 128
#define NTAG 32
#define START_TAG 30
#define END_TAG 31

__device__ __forceinline__ float fdot2(uint a, uint b, float c) {
  return __builtin_amdgcn_fdot2(__builtin_bit_cast(half2_t, a),
                                __builtin_bit_cast(half2_t, b), c, false);
}
__device__ __forceinline__ uint packh2(float a, float b) {
  half2_t h = __builtin_amdgcn_cvt_pkrtz(a, b);
  return __builtin_bit_cast(uint, h);
}
__device__ __forceinline__ float frcp(float x) { return __builtin_amdgcn_rcpf(x); }
__device__ __forceinline__ float fsig(float x) { return frcp(1.f + __expf(-x)); }
__device__ __forceinline__ float ftanh(float x) { return 1.f - 2.f * frcp(1.f + __expf(2.f * x)); }
__device__ __forceinline__ float fexp2(float x) { return __builtin_amdgcn_exp2f(x); }
__device__ __forceinline__ float flog2(float x) { return __builtin_amdgcn_logf(x); }

// Quad butterfly sum via DPP quad_perm (VALU pipe, no LDS):
// 0xB1 = quad_perm[1,0,3,2] (xor 1), 0x4E = quad_perm[2,3,0,1] (xor 2).
__device__ __forceinline__ float quad_add(float x) {
  int a = __builtin_bit_cast(int, x);
  int b = __builtin_amdgcn_update_dpp(0, a, 0xB1, 0xF, 0xF, true);
  float y = x + __builtin_bit_cast(float, b);
  int c2 = __builtin_bit_cast(int, y);
  int d2 = __builtin_amdgcn_update_dpp(0, c2, 0x4E, 0xF, 0xF, true);
  return y + __builtin_bit_cast(float, d2);
}
// Quad broadcast of lane L (CTRL = 0x00/0x55/0xAA/0xFF for L=0/1/2/3).
template <int CTRL>
__device__ __forceinline__ float quad_bcast(float x) {
  int a = __builtin_bit_cast(int, x);
  int b = __builtin_amdgcn_update_dpp(0, a, CTRL, 0xF, 0xF, true);
  return __builtin_bit_cast(float, b);
}

// ---------------------------------------------------------------------------
// prep (unchanged from R8)
// ---------------------------------------------------------------------------
__global__ __launch_bounds__(256) void prep_kernel(
    const float* __restrict__ Wihf, const float* __restrict__ Whhf,
    const float* __restrict__ bihf, const float* __restrict__ bhhf,
    const float* __restrict__ Wihb, const float* __restrict__ Whhb,
    const float* __restrict__ bihb, const float* __restrict__ bhhb,
    const float* __restrict__ Wout,
    uint* __restrict__ wihI, uint* __restrict__ whh,
    uint* __restrict__ woutp, float* __restrict__ biasI)
{
  int idx = blockIdx.x * 256 + threadIdx.x;
  if (idx < 65536) {
    int d = idx >> 15, rem = idx & 32767;
    int n = rem >> 6, dw = rem & 63;
    int m = n >> 2, q = n & 3;
    int g = q * 128 + m;
    const float* W = d ? Wihb : Wihf;
    wihI[idx] = packh2(W[g * 128 + 2 * dw], W[g * 128 + 2 * dw + 1]);
  }
  int i2 = idx - 65536;
  if (i2 >= 0 && i2 < 65536) {
    int d = i2 >> 15, rem = i2 & 32767;
    int g = rem >> 6, dw = rem & 63;
    const float* W = d ? Whhb : Whhf;
    whh[i2] = packh2(W[g * 128 + 2 * dw], W[g * 128 + 2 * dw + 1]);
  }
  int i3 = idx - 131072;
  if (i3 >= 0 && i3 < 4096) {
    int k = i3 >> 7, dw = i3 & 127;
    float a, b2;
    if (dw < 64) { a = Wout[k * 256 + 2 * dw]; b2 = Wout[k * 256 + 2 * dw + 1]; }
    else { int j = dw - 64; a = Wout[k * 256 + 128 + 2 * j]; b2 = Wout[k * 256 + 128 + 2 * j + 1]; }
    woutp[i3] = packh2(a, b2);
  }
  int i4 = idx - 135168;
  if (i4 >= 0 && i4 < 1024) {
    int d = i4 >> 9, n = i4 & 511;
    int g = (n & 3) * 128 + (n >> 2);
    biasI[i4] = d ? (bihb[g] + bhhb[g]) : (bihf[g] + bhhf[g]);
  }
}

// ---------------------------------------------------------------------------
// gemmx (unchanged from R8)
// ---------------------------------------------------------------------------
__global__ __launch_bounds__(256, 2) void gemmx_kernel(
    const int* __restrict__ sentence, const float* __restrict__ embed,
    const uint* __restrict__ wihI, const float* __restrict__ biasI,
    uint* __restrict__ gatex, int chunk)
{
  int blk = blockIdx.x;
  int tl = blk & 127, nb = (blk >> 7) & 3, d = blk >> 9;
  int t = chunk * 128 + tl;
  int s = d ? (511 - t) : t;
  __shared__ int tok[128];
  int tid = threadIdx.x;
  if (tid < 128) tok[tid] = sentence[tid * SEQ + s];
  __syncthreads();

  int w = tid >> 6, lane = tid & 63;
  int q = lane >> 4, r = lane & 15;
  int wr = w >> 1, wc = w & 1;
  int r0 = wr * 64;
  int c0 = nb * 128 + wc * 64;

  floatx4 acc[4][4];
#pragma unroll
  for (int i = 0; i < 4; ++i)
#pragma unroll
    for (int j = 0; j < 4; ++j) acc[i][j] = (floatx4){0.f, 0.f, 0.f, 0.f};

  const float4* aptr[4];
#pragma unroll
  for (int i = 0; i < 4; ++i)
    aptr[i] = (const float4*)(embed + (size_t)tok[r0 + i * 16 + r] * HID) + q * 2;
  const uint4* bptr[4];
#pragma unroll
  for (int j = 0; j < 4; ++j)
    bptr[j] = (const uint4*)(wihI + ((size_t)d * 512 + c0 + j * 16 + r) * 64) + q;

#pragma unroll
  for (int kc = 0; kc < 4; ++kc) {
    half8_t af[4], bf[4];
#pragma unroll
    for (int i = 0; i < 4; ++i) {
      float4 x0 = aptr[i][kc * 8];
      float4 x1 = aptr[i][kc * 8 + 1];
      uint4 u;
      u.x = packh2(x0.x, x0.y); u.y = packh2(x0.z, x0.w);
      u.z = packh2(x1.x, x1.y); u.w = packh2(x1.z, x1.w);
      af[i] = __builtin_bit_cast(half8_t, u);
    }
#pragma unroll
    for (int j = 0; j < 4; ++j)
      bf[j] = __builtin_bit_cast(half8_t, bptr[j][kc * 4]);
#pragma unroll
    for (int i = 0; i < 4; ++i)
#pragma unroll
      for (int j = 0; j < 4; ++j)
        acc[i][j] = __builtin_amdgcn_mfma_f32_16x16x32_f16(af[i], bf[j], acc[i][j], 0, 0, 0);
  }

  __fp16* gat = ((__fp16*)gatex) + (size_t)d * 16384 * 512;
#pragma unroll
  for (int j = 0; j < 4; ++j) {
    int n = c0 + j * 16 + r;
    float bb = biasI[d * 512 + n];
#pragma unroll
    for (int i = 0; i < 4; ++i) {
      int rb = r0 + i * 16 + q * 4;
#pragma unroll
      for (int reg = 0; reg < 4; ++reg) {
        float v = acc[i][j][reg] + bb;
        gat[((size_t)(tl * 128 + rb + reg)) * 512 + n] = (__fp16)v;
      }
    }
  }
}

// ---------------------------------------------------------------------------
// LSTM recurrence — R18 (R17 structure + forced weight residency).
// R17 post-mortem: VGPR_Count=56 < the 64 wreg needs -> at 1024 threads
// the allocator's occupancy heuristic targeted 8 waves/SIMD (cap 64),
// sank the weight loads -> L2 re-stream with 2x pressure -> 127us. The
// co-schedule thesis was never tested (precondition unmet). R18 fixes
// residency two ways:
//  * __launch_bounds__(1024, 4): min 4 waves/EU -> VGPR cap 128 >= ~90
//    needed; HW allows floor(512/88)=5 waves/SIMD so 4 fits.
//  * asm "+v" anchors on all 16 wreg uint4s: loads become opaque asm
//    results -> not rematerializable/sinkable. (R10's anchor->scratch
//    failure was budget ~84 < need 128; here budget 128 > need ~90.)
// Expected: VGPR >= 88 (verify!), dur 127 -> 50-62us if two independent
// chains per SIMD interleave (m114). Pre-committed: dur >= 72us with
// VGPR >= 88 -> co-schedule refuted -> revert lstm to R15, pivot.
// ---------------------------------------------------------------------------
__global__ __attribute__((amdgpu_waves_per_eu(4, 4))) __launch_bounds__(1024, 4)
void lstm_kernel(
    const uint* __restrict__ gatex, const uint* __restrict__ whh,
    const float* __restrict__ h0, const float* __restrict__ c0,
    float* __restrict__ statec, uint* __restrict__ hh, int chunk)
{
  const float L2E = 1.4426950408889634f;
  const int wg = blockIdx.x;
  const int tid = threadIdx.x;
  const int p = tid >> 9;          // pair index within WG (0/1)
  const int lt = tid & 511;        // local tid within pair
  const int kq = lt & 3, m = lt >> 2;   // m in 0..127
  const int d = wg >> 6, bpair = wg & 63;
  const int b = bpair * 2 + p;

  __shared__ __align__(16) __fp16 hist[2][128][128];   // 64 KB

  // Lane-constant nonlinearity params: kq==2 -> tanh, else sigmoid.
  const bool isg = (kq == 2);
  const float sl = isg ? (2.f * L2E) : (-L2E);
  const float Ac = isg ? -2.f : 1.f;
  const float Bc = isg ? 1.f : 0.f;

  // Weights: gate g row = g*128+m (64 uints); this thread's quarter = 4 uint4.
  const uint4* wh4 = (const uint4*)whh + (size_t)d * 8192;
  uint4 wreg[4][4];
#pragma unroll
  for (int g = 0; g < 4; ++g) {
    const uint4* row = wh4 + ((size_t)(g * 128 + m)) * 16 + kq * 4;
#pragma unroll
    for (int i = 0; i < 4; ++i) wreg[g][i] = row[i];
  }
  // Anchor: force all 64 weight dwords live in VGPRs across the loop.
#pragma unroll
  for (int g = 0; g < 4; ++g)
#pragma unroll
    for (int i = 0; i < 4; ++i)
      asm volatile("" : "+v"(wreg[g][i].x), "+v"(wreg[g][i].y),
                       "+v"(wreg[g][i].z), "+v"(wreg[g][i].w));

  float c = (chunk == 0) ? c0[(size_t)(d * 128 + b) * 128 + m]
                         : statec[(size_t)(d * 128 + b) * 128 + m];

  if (lt < 64) {
    uint* h127 = (uint*)&hist[p][127][0];
    if (chunk == 0) {
      float2 hv = ((const float2*)(h0 + (size_t)(d * 128 + b) * 128))[lt];
      h127[lt] = packh2(hv.x, hv.y);
    } else {
      int sprev = d ? (511 - (chunk * 128 - 1)) : (chunk * 128 - 1);
      h127[lt] = hh[((size_t)(d * 512 + sprev) * 128 + b) * 64 + lt];
    }
  }
  // Gate-x: this thread's own gate only (ushort at half index 4m+kq).
  const ushort* gxp = (const ushort*)gatex + (size_t)d * 8388608 +
                      (size_t)b * 512 + 4 * m + kq;

  // One LSTM step: consume own-gate gate-x value gxh at timestep tl_.
  auto step = [&](int tl_, ushort gxh) {
    float a0 = 0.f, a1 = 0.f, a2 = 0.f, a3 = 0.f;
    float b0 = 0.f, b1 = 0.f, b2 = 0.f, b3 = 0.f;
    const uint4* z4 = (const uint4*)(&hist[p][(tl_ + 127) & 127][kq * 32]);
#pragma unroll
    for (int i = 0; i < 2; ++i) {
      uint4 z = z4[i];
      a0 = fdot2(z.x, wreg[0][i].x, a0);
      a0 = fdot2(z.y, wreg[0][i].y, a0);
      a0 = fdot2(z.z, wreg[0][i].z, a0);
      a0 = fdot2(z.w, wreg[0][i].w, a0);
      a1 = fdot2(z.x, wreg[1][i].x, a1);
      a1 = fdot2(z.y, wreg[1][i].y, a1);
      a1 = fdot2(z.z, wreg[1][i].z, a1);
      a1 = fdot2(z.w, wreg[1][i].w, a1);
      a2 = fdot2(z.x, wreg[2][i].x, a2);
      a2 = fdot2(z.y, wreg[2][i].y, a2);
      a2 = fdot2(z.z, wreg[2][i].z, a2);
      a2 = fdot2(z.w, wreg[2][i].w, a2);
      a3 = fdot2(z.x, wreg[3][i].x, a3);
      a3 = fdot2(z.y, wreg[3][i].y, a3);
      a3 = fdot2(z.z, wreg[3][i].z, a3);
      a3 = fdot2(z.w, wreg[3][i].w, a3);
    }
#pragma unroll
    for (int i = 2; i < 4; ++i) {
      uint4 z = z4[i];
      b0 = fdot2(z.x, wreg[0][i].x, b0);
      b0 = fdot2(z.y, wreg[0][i].y, b0);
      b0 = fdot2(z.z, wreg[0][i].z, b0);
      b0 = fdot2(z.w, wreg[0][i].w, b0);
      b1 = fdot2(z.x, wreg[1][i].x, b1);
      b1 = fdot2(z.y, wreg[1][i].y, b1);
      b1 = fdot2(z.z, wreg[1][i].z, b1);
      b1 = fdot2(z.w, wreg[1][i].w, b1);
      b2 = fdot2(z.x, wreg[2][i].x, b2);
      b2 = fdot2(z.y, wreg[2][i].y, b2);
      b2 = fdot2(z.z, wreg[2][i].z, b2);
      b2 = fdot2(z.w, wreg[2][i].w, b2);
      b3 = fdot2(z.x, wreg[3][i].x, b3);
      b3 = fdot2(z.y, wreg[3][i].y, b3);
      b3 = fdot2(z.z, wreg[3][i].z, b3);
      b3 = fdot2(z.w, wreg[3][i].w, b3);
    }
    a0 += b0; a1 += b1; a2 += b2; a3 += b3;
    // quad butterfly over k-quarters (DPP, VALU-only): all lanes get totals.
    a0 = quad_add(a0);
    a1 = quad_add(a1);
    a2 = quad_add(a2);
    a3 = quad_add(a3);
    // Select own gate total; add own gate-x; apply own nonlinearity.
    float s01 = (kq & 1) ? a1 : a0;
    float s23 = (kq & 1) ? a3 : a2;
    float own = (kq & 2) ? s23 : s01;
    own += (float)__builtin_bit_cast(__fp16, gxh);
    float e = fexp2(own * sl);
    float r = frcp(1.f + e);
    float out = Ac * r + Bc;   // sig (kq 0,1,3) or tanh (kq 2)
    // Fan the 4 gate values back to all quad lanes.
    float ig = quad_bcast<0x00>(out);
    float fg = quad_bcast<0x55>(out);
    float gg = quad_bcast<0xAA>(out);
    float og = quad_bcast<0xFF>(out);
    c = fg * c + ig * gg;
    float e2 = fexp2(c * (2.f * L2E));
    float r2 = frcp(1.f + e2);
    float th = 1.f - 2.f * r2;
    float hv = og * th;

    if (kq == 0) hist[p][tl_][m] = (__fp16)hv;
    // Barrier WITHOUT vmcnt drain: lgkmcnt(0) covers the ds_write above;
    // prefetched gatex loads stay in flight across the barrier.
    __builtin_amdgcn_sched_barrier(0);
    asm volatile("s_waitcnt lgkmcnt(0)");
    __builtin_amdgcn_sched_barrier(0);
    __builtin_amdgcn_s_barrier();
  };

  // 4-deep gate-x prefetch ring (static indices).
  ushort g0 = gxp[0];
  ushort g1 = gxp[(size_t)1 * 65536];
  ushort g2 = gxp[(size_t)2 * 65536];
  ushort g3 = gxp[(size_t)3 * 65536];
  __syncthreads();

  for (int tl = 0; tl < 128; tl += 4) {
    int i0 = tl + 4 > 127 ? 127 : tl + 4;
    int i1 = tl + 5 > 127 ? 127 : tl + 5;
    int i2 = tl + 6 > 127 ? 127 : tl + 6;
    int i3 = tl + 7 > 127 ? 127 : tl + 7;
    ushort n0 = gxp[(size_t)i0 * 65536];
    ushort n1 = gxp[(size_t)i1 * 65536];
    ushort n2 = gxp[(size_t)i2 * 65536];
    ushort n3 = gxp[(size_t)i3 * 65536];
    step(tl + 0, g0);
    step(tl + 1, g1);
    step(tl + 2, g2);
    step(tl + 3, g3);
    g0 = n0; g1 = n1; g2 = n2; g3 = n3;
  }

  if (kq == 0) statec[(size_t)(d * 128 + b) * 128 + m] = c;

  int base = chunk * 128;
  for (int i = tid; i < 4096; i += 1024) {
    int p2 = i >> 11, r2i = i & 2047;
    int sl2 = r2i >> 4, q4 = r2i & 15;
    int b2 = bpair * 2 + p2;
    int s = d ? (511 - (base + sl2)) : (base + sl2);
    *(uint4*)(&hh[((size_t)(d * 512 + s) * 128 + b2) * 64 + q4 * 4]) =
        *(const uint4*)((const uint*)&hist[p2][sl2][0] + q4 * 4);
  }
}

// ---------------------------------------------------------------------------
// Output projection (unchanged from R8)
// ---------------------------------------------------------------------------
__global__ __launch_bounds__(256) void outproj_kernel(
    const uint* __restrict__ hh, const uint* __restrict__ woutp,
    const float* __restrict__ bout, float* __restrict__ feats)
{
  __shared__ __align__(16) uint4 zrow[8][32];
  __shared__ __align__(16) uint4 wlds[32][32];
  int tid = threadIdx.x;
  for (int j = tid; j < 1024; j += 256) {
    int k = j >> 5, i = j & 31;
    wlds[i][k] = ((const uint4*)woutp)[j];
  }
  int rl = tid >> 5, q = tid & 31;
  int row = blockIdx.x * 8 + rl;
  int b = row >> 9, s = row & 511;
  const uint4* hf4 = (const uint4*)(hh + ((size_t)s * BATCH + b) * 64);
  const uint4* hb4 = (const uint4*)(hh + ((size_t)(SEQ + s) * BATCH + b) * 64);
  zrow[rl][q] = (q < 16) ? hf4[q] : hb4[q - 16];
  __syncthreads();
  int k = q;
  float acc = bout[k];
#pragma unroll
  for (int i = 0; i < 32; ++i) {
    uint4 z = zrow[rl][i];
    uint4 wv = wlds[i][k];
    acc = fdot2(z.x, wv.x, acc);
    acc = fdot2(z.y, wv.y, acc);
    acc = fdot2(z.z, wv.z, acc);
    acc = fdot2(z.w, wv.w, acc);
  }
  feats[(size_t)row * 32 + k] = acc;
}

// ---------------------------------------------------------------------------
// CRF numerator (unchanged)
// ---------------------------------------------------------------------------
__global__ __launch_bounds__(64) void crf_num_kernel(
    const int* __restrict__ tags, const float* __restrict__ feats,
    const float* __restrict__ trans, float* __restrict__ num)
{
  int b = blockIdx.x, l = threadIdx.x;
  const int* tb = tags + b * SEQ;
  float acc = 0.f;
  for (int s = l; s < SEQ; s += 64) {
    int tg = tb[s];
    int pv = (s == 0) ? START_TAG : tb[s - 1];
    acc += trans[pv * NTAG + tg] + feats[((size_t)b * SEQ + s) * NTAG + tg];
  }
#pragma unroll
  for (int msk = 1; msk < 64; msk <<= 1) acc += __shfl_xor(acc, msk);
  if (l == 0) num[b] = acc + trans[tb[SEQ - 1] * NTAG + END_TAG];
}

// ---------------------------------------------------------------------------
// CRF stage A (unchanged from R8)
// ---------------------------------------------------------------------------
__global__ __launch_bounds__(64) void crf_seg_kernel(
    const float* __restrict__ feats, const float* __restrict__ trans,
    uint* __restrict__ segP, float* __restrict__ segL)
{
  const float L2E = 1.4426950408889634f;
  int blk = blockIdx.x;
  int b = blk >> 5, j = blk & 31;
  int tstart = 1 + 16 * j;
  int nsteps = (j == 31) ? 15 : 16;
  int lane = threadIdx.x;
  int c = lane & 15, q = lane >> 4;

  half8_t afr[2];
#pragma unroll
  for (int rt = 0; rt < 2; ++rt) {
    const float* trow = trans + (rt * 16 + c) * 32 + q * 8;
    float e[8];
#pragma unroll
    for (int i = 0; i < 8; ++i) e[i] = fexp2(trow[i] * L2E);
    uint4 u;
    u.x = packh2(e[0], e[1]); u.y = packh2(e[2], e[3]);
    u.z = packh2(e[4], e[5]); u.w = packh2(e[6], e[7]);
    afr[rt] = __builtin_bit_cast(half8_t, u);
  }
  half8_t bfr[2];
#pragma unroll
  for (int ct = 0; ct < 2; ++ct) {
    uint4 u;
    uint vals[8];
#pragma unroll
    for (int i = 0; i < 8; ++i)
      vals[i] = ((q * 8 + i) == (ct * 16 + c)) ? 0x3C00u : 0u;
    u.x = vals[0] | (vals[1] << 16);
    u.y = vals[2] | (vals[3] << 16);
    u.z = vals[4] | (vals[5] << 16);
    u.w = vals[6] | (vals[7] << 16);
    bfr[ct] = __builtin_bit_cast(half8_t, u);
  }

  __shared__ __fp16 P16[32 * 36];

  const float* fb = feats + ((size_t)b * SEQ + tstart) * NTAG;
  float Lacc = 0.f;
  float4 pre0 = *(const float4*)(fb + q * 4);
  float4 pre1 = *(const float4*)(fb + 16 + q * 4);

  for (int s = 0; s < nsteps; ++s) {
    float4 f0 = pre0, f1 = pre1;
    if (s + 1 < nsteps) {
      pre0 = *(const float4*)(fb + (s + 1) * 32 + q * 4);
      pre1 = *(const float4*)(fb + (s + 1) * 32 + 16 + q * 4);
    }
    floatx4 z4 = (floatx4){0.f, 0.f, 0.f, 0.f};
    floatx4 c00 = __builtin_amdgcn_mfma_f32_16x16x32_f16(afr[0], bfr[0], z4, 0, 0, 0);
    floatx4 c01 = __builtin_amdgcn_mfma_f32_16x16x32_f16(afr[0], bfr[1], z4, 0, 0, 0);
    floatx4 c10 = __builtin_amdgcn_mfma_f32_16x16x32_f16(afr[1], bfr[0], z4, 0, 0, 0);
    floatx4 c11 = __builtin_amdgcn_mfma_f32_16x16x32_f16(afr[1], bfr[1], z4, 0, 0, 0);
    float pf0[4], pf1[4];
    pf0[0] = fexp2(f0.x * L2E); pf0[1] = fexp2(f0.y * L2E);
    pf0[2] = fexp2(f0.z * L2E); pf0[3] = fexp2(f0.w * L2E);
    pf1[0] = fexp2(f1.x * L2E); pf1[1] = fexp2(f1.y * L2E);
    pf1[2] = fexp2(f1.z * L2E); pf1[3] = fexp2(f1.w * L2E);
    float v00[4], v01[4], v10[4], v11[4];
#pragma unroll
    for (int rg = 0; rg < 4; ++rg) {
      v00[rg] = c00[rg] * pf0[rg];
      v01[rg] = c01[rg] * pf0[rg];
      v10[rg] = c10[rg] * pf1[rg];
      v11[rg] = c11[rg] * pf1[rg];
    }
    float mx = 0.f;
#pragma unroll
    for (int rg = 0; rg < 4; ++rg)
      mx = fmaxf(mx, fmaxf(fmaxf(v00[rg], v01[rg]), fmaxf(v10[rg], v11[rg])));
    uint ub = (uint)__builtin_amdgcn_readfirstlane((int)__builtin_bit_cast(uint, mx));
    int e = (int)((ub >> 23) & 255u);
    Lacc += (float)(e - 127);
    float sc = __builtin_bit_cast(float, (uint)((254 - e) << 23));

    __syncthreads();
    {
      uint2 wv2;
      wv2.x = packh2(v00[0] * sc, v00[1] * sc);
      wv2.y = packh2(v00[2] * sc, v00[3] * sc);
      *(uint2*)(&P16[c * 36 + q * 4]) = wv2;
      wv2.x = packh2(v10[0] * sc, v10[1] * sc);
      wv2.y = packh2(v10[2] * sc, v10[3] * sc);
      *(uint2*)(&P16[c * 36 + 16 + q * 4]) = wv2;
      wv2.x = packh2(v01[0] * sc, v01[1] * sc);
      wv2.y = packh2(v01[2] * sc, v01[3] * sc);
      *(uint2*)(&P16[(16 + c) * 36 + q * 4]) = wv2;
      wv2.x = packh2(v11[0] * sc, v11[1] * sc);
      wv2.y = packh2(v11[2] * sc, v11[3] * sc);
      *(uint2*)(&P16[(16 + c) * 36 + 16 + q * 4]) = wv2;
    }
    __syncthreads();
    {
      uint2 lo0 = *(const uint2*)(&P16[c * 36 + q * 8]);
      uint2 hi0 = *(const uint2*)(&P16[c * 36 + q * 8 + 4]);
      uint4 u0; u0.x = lo0.x; u0.y = lo0.y; u0.z = hi0.x; u0.w = hi0.y;
      bfr[0] = __builtin_bit_cast(half8_t, u0);
      uint2 lo1 = *(const uint2*)(&P16[(16 + c) * 36 + q * 8]);
      uint2 hi1 = *(const uint2*)(&P16[(16 + c) * 36 + q * 8 + 4]);
      uint4 u1; u1.x = lo1.x; u1.y = lo1.y; u1.z = hi1.x; u1.w = hi1.y;
      bfr[1] = __builtin_bit_cast(half8_t, u1);
    }
  }
  __syncthreads();
  uint* gp = segP + (size_t)blk * 512;
  if (lane < 32) {
    int i = lane;
#pragma unroll
    for (int tp = 0; tp < 16; ++tp) {
      uint lo = (uint)__builtin_bit_cast(unsigned short, P16[(2 * tp) * 36 + i]);
      uint hi = (uint)__builtin_bit_cast(unsigned short, P16[(2 * tp + 1) * 36 + i]);
      gp[i * 16 + tp] = lo | (hi << 16);
    }
  }
  if (lane == 0) segL[blk] = Lacc;
}

// ---------------------------------------------------------------------------
// CRF stage B (unchanged from R8)
// ---------------------------------------------------------------------------
__global__ __launch_bounds__(64) void crf_comb_kernel(
    const float* __restrict__ feats, const float* __restrict__ trans,
    const uint* __restrict__ segP, const float* __restrict__ segL,
    float* __restrict__ den)
{
  const float L2E = 1.4426950408889634f, LN2 = 0.6931471805599453f;
  int b = blockIdx.x, l = threadIdx.x;
  int i = l & 31, hp = l >> 5;
  const float* fb = feats + (size_t)b * SEQ * NTAG;

  float sT = 0.f;
  for (int p = 0; p < 32; ++p) sT += fexp2(trans[i * 32 + p] * L2E);
  float v = (1.f + sT) * fexp2(fb[i] * L2E);
  float L = -10000.f * L2E;

  float vo = __shfl_xor(v, 1);
  uint pv = (i & 1) ? packh2(vo, v) : packh2(v, vo);

  const uint* gp0 = segP + (size_t)b * 32 * 512 + i * 16 + hp * 8;
  uint4 ra = *(const uint4*)(gp0);
  uint4 rb = *(const uint4*)(gp0 + 4);

  for (int seg = 0; seg < 32; ++seg) {
    uint4 ca = ra, cb = rb;
    if (seg + 1 < 32) {
      ra = *(const uint4*)(gp0 + (seg + 1) * 512);
      rb = *(const uint4*)(gp0 + (seg + 1) * 512 + 4);
    }
    float g0 = __shfl(__builtin_bit_cast(float, pv), hp * 16 + 0);
    float g1 = __shfl(__builtin_bit_cast(float, pv), hp * 16 + 2);
    float g2 = __shfl(__builtin_bit_cast(float, pv), hp * 16 + 4);
    float g3 = __shfl(__builtin_bit_cast(float, pv), hp * 16 + 6);
    float g4 = __shfl(__builtin_bit_cast(float, pv), hp * 16 + 8);
    float g5 = __shfl(__builtin_bit_cast(float, pv), hp * 16 + 10);
    float g6 = __shfl(__builtin_bit_cast(float, pv), hp * 16 + 12);
    float g7 = __shfl(__builtin_bit_cast(float, pv), hp * 16 + 14);
    float acc = 0.f;
    acc = fdot2(__builtin_bit_cast(uint, g0), ca.x, acc);
    acc = fdot2(__builtin_bit_cast(uint, g1), ca.y, acc);
    acc = fdot2(__builtin_bit_cast(uint, g2), ca.z, acc);
    acc = fdot2(__builtin_bit_cast(uint, g3), ca.w, acc);
    acc = fdot2(__builtin_bit_cast(uint, g4), cb.x, acc);
    acc = fdot2(__builtin_bit_cast(uint, g5), cb.y, acc);
    acc = fdot2(__builtin_bit_cast(uint, g6), cb.z, acc);
    acc = fdot2(__builtin_bit_cast(uint, g7), cb.w, acc);
    float sm = acc + __shfl_xor(acc, 32);
    uint ub = (uint)__builtin_amdgcn_readfirstlane((int)__builtin_bit_cast(uint, sm));
    int e = (int)((ub >> 23) & 255u);
    L += (float)(e - 127) + segL[b * 32 + seg];
    float sc = __builtin_bit_cast(float, (uint)((254 - e) << 23));
    v = sm * sc;
    float vo2 = __shfl_xor(v, 1);
    pv = (i & 1) ? packh2(vo2, v) : packh2(v, vo2);
  }
  float wv = v * fexp2(trans[i * 32 + END_TAG] * L2E);
#pragma unroll
  for (int msk = 1; msk <= 16; msk <<= 1) wv += __shfl_xor(wv, msk);
  if (l == 0) den[b] = (L + flog2(wv)) * LN2;
}

__global__ __launch_bounds__(128) void final_kernel(
    const float* __restrict__ num, const float* __restrict__ den,
    float* __restrict__ out)
{
  int tid = threadIdx.x;
  float v = num[tid] - den[tid];
#pragma unroll
  for (int msk = 1; msk < 64; msk <<= 1) v += __shfl_xor(v, msk);
  __shared__ float tmp[2];
  if ((tid & 63) == 0) tmp[tid >> 6] = v;
  __syncthreads();
  if (tid == 0) out[0] = (tmp[0] + tmp[1]) * (1.f / 128.f);
}

// ---------------------------------------------------------------------------
// Workspace layout (bytes): same as R8 (gatex region overlaps later-phase
// buffers deliberately — gatex is dead after the chunk loop)
// ---------------------------------------------------------------------------
extern "C" void kernel_launch(void* const* d_in, const int* in_sizes, int n_in,
                              void* d_out, int out_size, void* d_ws, size_t ws_size,
                              hipStream_t stream)
{
  const int* sentence = (const int*)d_in[0];
  const int* tags = (const int*)d_in[1];
  const float* embed = (const float*)d_in[2];
  const float* Wihf = (const float*)d_in[3];
  const float* Whhf = (const float*)d_in[4];
  const float* bihf = (const float*)d_in[5];
  const float* bhhf = (const float*)d_in[6];
  const float* Wihb = (const float*)d_in[7];
  const float* Whhb = (const float*)d_in[8];
  const float* bihb = (const float*)d_in[9];
  const float* bhhb = (const float*)d_in[10];
  const float* Wout = (const float*)d_in[11];
  const float* bout = (const float*)d_in[12];
  const float* trans = (const float*)d_in[13];
  const float* h0 = (const float*)d_in[14];
  const float* c0 = (const float*)d_in[15];
  float* out = (float*)d_out;

  char* ws = (char*)d_ws;
  uint* wihI = (uint*)(ws + 0);
  uint* whh = (uint*)(ws + 262144);
  uint* woutp = (uint*)(ws + 524288);
  float* biasI = (float*)(ws + 540672);
  float* numb = (float*)(ws + 544768);
  float* denb = (float*)(ws + 545280);
  float* statec = (float*)(ws + 545792);
  uint* hh = (uint*)(ws + 1048576);
  uint* gatex = (uint*)(ws + 34603008);
  float* feats = (float*)(ws + 34603008);
  uint* segP = (uint*)(ws + 42991616);
  float* segL = (float*)(ws + 51380224);

  hipLaunchKernelGGL(prep_kernel, dim3(532), dim3(256), 0, stream,
                     Wihf, Whhf, bihf, bhhf, Wihb, Whhb, bihb, bhhb, Wout,
                     wihI, whh, woutp, biasI);
  for (int c = 0; c < 4; ++c) {
    hipLaunchKernelGGL(gemmx_kernel, dim3(1024), dim3(256), 0, stream,
                       sentence, embed, wihI, biasI, gatex, c);
    hipLaunchKernelGGL(lstm_kernel, dim3(128), dim3(1024), 0, stream,
                       gatex, whh, h0, c0, statec, hh, c);
  }
  hipLaunchKernelGGL(outproj_kernel, dim3(8192), dim3(256), 0, stream,
                     hh, woutp, bout, feats);
  hipLaunchKernelGGL(crf_num_kernel, dim3(128), dim3(64), 0, stream,
                     tags, feats, trans, numb);
  hipLaunchKernelGGL(crf_seg_kernel, dim3(4096), dim3(64), 0, stream,
                     feats, trans, segP, segL);
  hipLaunchKernelGGL(crf_comb_kernel, dim3(128), dim3(64), 0, stream,
                     feats, trans, segP, segL, denb);
  hipLaunchKernelGGL(final_kernel, dim3(1), dim3(128), 0, stream,
                     numb, denb, out);
}

// Round 10
// 756.581 us; speedup vs baseline: 1.0220x; 1.0220x over previous
//
#include <hip/hip_runtime.h>

typedef unsigned int uint;
typedef unsigned short ushort;
typedef __fp16 half2_t __attribute__((ext_vector_type(2)));
typedef __fp16 half8_t __attribute__((ext_vector_type(8)));
typedef float floatx4 __attribute__((ext_vector_type(4)));

#define SEQ 512
#define BATCH 128
#define HID 128
#define NTAG 32
#define START_TAG 30
#define END_TAG 31
// hist inner stride (halfs). 168 -> 2*128*168*2B = 86016B LDS: >80KB so only
// ONE 1024-thread WG fits per CU -> occupancy ceiling 4 waves/SIMD -> VGPR
// budget 128 (the R17/R18 failure was the heuristic seeing 2 WGs/CU fit at
// 64KB and capping VGPR at 64, sinking the weights).
#define HSTRIDE 168

__device__ __forceinline__ float fdot2(uint a, uint b, float c) {
  return __builtin_amdgcn_fdot2(__builtin_bit_cast(half2_t, a),
                                __builtin_bit_cast(half2_t, b), c, false);
}
__device__ __forceinline__ uint packh2(float a, float b) {
  half2_t h = __builtin_amdgcn_cvt_pkrtz(a, b);
  return __builtin_bit_cast(uint, h);
}
__device__ __forceinline__ float frcp(float x) { return __builtin_amdgcn_rcpf(x); }
__device__ __forceinline__ float fsig(float x) { return frcp(1.f + __expf(-x)); }
__device__ __forceinline__ float ftanh(float x) { return 1.f - 2.f * frcp(1.f + __expf(2.f * x)); }
__device__ __forceinline__ float fexp2(float x) { return __builtin_amdgcn_exp2f(x); }
__device__ __forceinline__ float flog2(float x) { return __builtin_amdgcn_logf(x); }

// Quad butterfly sum via DPP quad_perm (VALU pipe, no LDS):
// 0xB1 = quad_perm[1,0,3,2] (xor 1), 0x4E = quad_perm[2,3,0,1] (xor 2).
__device__ __forceinline__ float quad_add(float x) {
  int a = __builtin_bit_cast(int, x);
  int b = __builtin_amdgcn_update_dpp(0, a, 0xB1, 0xF, 0xF, true);
  float y = x + __builtin_bit_cast(float, b);
  int c2 = __builtin_bit_cast(int, y);
  int d2 = __builtin_amdgcn_update_dpp(0, c2, 0x4E, 0xF, 0xF, true);
  return y + __builtin_bit_cast(float, d2);
}
// Quad broadcast of lane L (CTRL = 0x00/0x55/0xAA/0xFF for L=0/1/2/3).
template <int CTRL>
__device__ __forceinline__ float quad_bcast(float x) {
  int a = __builtin_bit_cast(int, x);
  int b = __builtin_amdgcn_update_dpp(0, a, CTRL, 0xF, 0xF, true);
  return __builtin_bit_cast(float, b);
}

// ---------------------------------------------------------------------------
// prep (unchanged from R8)
// ---------------------------------------------------------------------------
__global__ __launch_bounds__(256) void prep_kernel(
    const float* __restrict__ Wihf, const float* __restrict__ Whhf,
    const float* __restrict__ bihf, const float* __restrict__ bhhf,
    const float* __restrict__ Wihb, const float* __restrict__ Whhb,
    const float* __restrict__ bihb, const float* __restrict__ bhhb,
    const float* __restrict__ Wout,
    uint* __restrict__ wihI, uint* __restrict__ whh,
    uint* __restrict__ woutp, float* __restrict__ biasI)
{
  int idx = blockIdx.x * 256 + threadIdx.x;
  if (idx < 65536) {
    int d = idx >> 15, rem = idx & 32767;
    int n = rem >> 6, dw = rem & 63;
    int m = n >> 2, q = n & 3;
    int g = q * 128 + m;
    const float* W = d ? Wihb : Wihf;
    wihI[idx] = packh2(W[g * 128 + 2 * dw], W[g * 128 + 2 * dw + 1]);
  }
  int i2 = idx - 65536;
  if (i2 >= 0 && i2 < 65536) {
    int d = i2 >> 15, rem = i2 & 32767;
    int g = rem >> 6, dw = rem & 63;
    const float* W = d ? Whhb : Whhf;
    whh[i2] = packh2(W[g * 128 + 2 * dw], W[g * 128 + 2 * dw + 1]);
  }
  int i3 = idx - 131072;
  if (i3 >= 0 && i3 < 4096) {
    int k = i3 >> 7, dw = i3 & 127;
    float a, b2;
    if (dw < 64) { a = Wout[k * 256 + 2 * dw]; b2 = Wout[k * 256 + 2 * dw + 1]; }
    else { int j = dw - 64; a = Wout[k * 256 + 128 + 2 * j]; b2 = Wout[k * 256 + 128 + 2 * j + 1]; }
    woutp[i3] = packh2(a, b2);
  }
  int i4 = idx - 135168;
  if (i4 >= 0 && i4 < 1024) {
    int d = i4 >> 9, n = i4 & 511;
    int g = (n & 3) * 128 + (n >> 2);
    biasI[i4] = d ? (bihb[g] + bhhb[g]) : (bihf[g] + bhhf[g]);
  }
}

// ---------------------------------------------------------------------------
// gemmx (unchanged from R8)
// ---------------------------------------------------------------------------
__global__ __launch_bounds__(256, 2) void gemmx_kernel(
    const int* __restrict__ sentence, const float* __restrict__ embed,
    const uint* __restrict__ wihI, const float* __restrict__ biasI,
    uint* __restrict__ gatex, int chunk)
{
  int blk = blockIdx.x;
  int tl = blk & 127, nb = (blk >> 7) & 3, d = blk >> 9;
  int t = chunk * 128 + tl;
  int s = d ? (511 - t) : t;
  __shared__ int tok[128];
  int tid = threadIdx.x;
  if (tid < 128) tok[tid] = sentence[tid * SEQ + s];
  __syncthreads();

  int w = tid >> 6, lane = tid & 63;
  int q = lane >> 4, r = lane & 15;
  int wr = w >> 1, wc = w & 1;
  int r0 = wr * 64;
  int c0 = nb * 128 + wc * 64;

  floatx4 acc[4][4];
#pragma unroll
  for (int i = 0; i < 4; ++i)
#pragma unroll
    for (int j = 0; j < 4; ++j) acc[i][j] = (floatx4){0.f, 0.f, 0.f, 0.f};

  const float4* aptr[4];
#pragma unroll
  for (int i = 0; i < 4; ++i)
    aptr[i] = (const float4*)(embed + (size_t)tok[r0 + i * 16 + r] * HID) + q * 2;
  const uint4* bptr[4];
#pragma unroll
  for (int j = 0; j < 4; ++j)
    bptr[j] = (const uint4*)(wihI + ((size_t)d * 512 + c0 + j * 16 + r) * 64) + q;

#pragma unroll
  for (int kc = 0; kc < 4; ++kc) {
    half8_t af[4], bf[4];
#pragma unroll
    for (int i = 0; i < 4; ++i) {
      float4 x0 = aptr[i][kc * 8];
      float4 x1 = aptr[i][kc * 8 + 1];
      uint4 u;
      u.x = packh2(x0.x, x0.y); u.y = packh2(x0.z, x0.w);
      u.z = packh2(x1.x, x1.y); u.w = packh2(x1.z, x1.w);
      af[i] = __builtin_bit_cast(half8_t, u);
    }
#pragma unroll
    for (int j = 0; j < 4; ++j)
      bf[j] = __builtin_bit_cast(half8_t, bptr[j][kc * 4]);
#pragma unroll
    for (int i = 0; i < 4; ++i)
#pragma unroll
      for (int j = 0; j < 4; ++j)
        acc[i][j] = __builtin_amdgcn_mfma_f32_16x16x32_f16(af[i], bf[j], acc[i][j], 0, 0, 0);
  }

  __fp16* gat = ((__fp16*)gatex) + (size_t)d * 16384 * 512;
#pragma unroll
  for (int j = 0; j < 4; ++j) {
    int n = c0 + j * 16 + r;
    float bb = biasI[d * 512 + n];
#pragma unroll
    for (int i = 0; i < 4; ++i) {
      int rb = r0 + i * 16 + q * 4;
#pragma unroll
      for (int reg = 0; reg < 4; ++reg) {
        float v = acc[i][j][reg] + bb;
        gat[((size_t)(tl * 128 + rb + reg)) * 512 + n] = (__fp16)v;
      }
    }
  }
}

// ---------------------------------------------------------------------------
// LSTM recurrence — R19 (R18 structure; LDS-pad forces 1 WG/CU).
// R18 post-mortem: VGPR=52 again — at 64KB LDS TWO 1024-thread WGs fit
// per CU, so the allocator's occupancy heuristic targets 8 waves/SIMD ->
// VGPR cap 64 -> weights sunk -> L2 re-stream (127-129us). launch_bounds
// and asm anchors both failed to override it. R19: pad hist stride to
// HSTRIDE=168 halfs -> LDS 86KB -> only 1 WG/CU fits -> ceiling is 4
// waves/SIMD -> VGPR cap 128 >= ~90 needed. Padding is inside the live
// array's stride (cannot be DCE'd, unlike R9's dead pad). Anchors removed.
// Pre-committed read: VGPR>=88 & dur<=62 -> co-schedule confirmed;
// VGPR>=88 & dur>=72 -> refuted, revert to R15 + pivot; VGPR~52 ->
// allocator not occupancy-driven, revert + pivot.
// ---------------------------------------------------------------------------
__global__ __attribute__((amdgpu_waves_per_eu(4, 4))) __launch_bounds__(1024, 4)
void lstm_kernel(
    const uint* __restrict__ gatex, const uint* __restrict__ whh,
    const float* __restrict__ h0, const float* __restrict__ c0,
    float* __restrict__ statec, uint* __restrict__ hh, int chunk)
{
  const float L2E = 1.4426950408889634f;
  const int wg = blockIdx.x;
  const int tid = threadIdx.x;
  const int p = tid >> 9;          // pair index within WG (0/1)
  const int lt = tid & 511;        // local tid within pair
  const int kq = lt & 3, m = lt >> 2;   // m in 0..127
  const int d = wg >> 6, bpair = wg & 63;
  const int b = bpair * 2 + p;

  __shared__ __align__(16) __fp16 hist[2][128][HSTRIDE];   // 86 KB

  // Lane-constant nonlinearity params: kq==2 -> tanh, else sigmoid.
  const bool isg = (kq == 2);
  const float sl = isg ? (2.f * L2E) : (-L2E);
  const float Ac = isg ? -2.f : 1.f;
  const float Bc = isg ? 1.f : 0.f;

  // Weights: gate g row = g*128+m (64 uints); this thread's quarter = 4 uint4.
  const uint4* wh4 = (const uint4*)whh + (size_t)d * 8192;
  uint4 wreg[4][4];
#pragma unroll
  for (int g = 0; g < 4; ++g) {
    const uint4* row = wh4 + ((size_t)(g * 128 + m)) * 16 + kq * 4;
#pragma unroll
    for (int i = 0; i < 4; ++i) wreg[g][i] = row[i];
  }

  float c = (chunk == 0) ? c0[(size_t)(d * 128 + b) * 128 + m]
                         : statec[(size_t)(d * 128 + b) * 128 + m];

  if (lt < 64) {
    uint* h127 = (uint*)&hist[p][127][0];
    if (chunk == 0) {
      float2 hv = ((const float2*)(h0 + (size_t)(d * 128 + b) * 128))[lt];
      h127[lt] = packh2(hv.x, hv.y);
    } else {
      int sprev = d ? (511 - (chunk * 128 - 1)) : (chunk * 128 - 1);
      h127[lt] = hh[((size_t)(d * 512 + sprev) * 128 + b) * 64 + lt];
    }
  }
  // Gate-x: this thread's own gate only (ushort at half index 4m+kq).
  const ushort* gxp = (const ushort*)gatex + (size_t)d * 8388608 +
                      (size_t)b * 512 + 4 * m + kq;

  // One LSTM step: consume own-gate gate-x value gxh at timestep tl_.
  auto step = [&](int tl_, ushort gxh) {
    float a0 = 0.f, a1 = 0.f, a2 = 0.f, a3 = 0.f;
    float b0 = 0.f, b1 = 0.f, b2 = 0.f, b3 = 0.f;
    const uint4* z4 = (const uint4*)(&hist[p][(tl_ + 127) & 127][kq * 32]);
#pragma unroll
    for (int i = 0; i < 2; ++i) {
      uint4 z = z4[i];
      a0 = fdot2(z.x, wreg[0][i].x, a0);
      a0 = fdot2(z.y, wreg[0][i].y, a0);
      a0 = fdot2(z.z, wreg[0][i].z, a0);
      a0 = fdot2(z.w, wreg[0][i].w, a0);
      a1 = fdot2(z.x, wreg[1][i].x, a1);
      a1 = fdot2(z.y, wreg[1][i].y, a1);
      a1 = fdot2(z.z, wreg[1][i].z, a1);
      a1 = fdot2(z.w, wreg[1][i].w, a1);
      a2 = fdot2(z.x, wreg[2][i].x, a2);
      a2 = fdot2(z.y, wreg[2][i].y, a2);
      a2 = fdot2(z.z, wreg[2][i].z, a2);
      a2 = fdot2(z.w, wreg[2][i].w, a2);
      a3 = fdot2(z.x, wreg[3][i].x, a3);
      a3 = fdot2(z.y, wreg[3][i].y, a3);
      a3 = fdot2(z.z, wreg[3][i].z, a3);
      a3 = fdot2(z.w, wreg[3][i].w, a3);
    }
#pragma unroll
    for (int i = 2; i < 4; ++i) {
      uint4 z = z4[i];
      b0 = fdot2(z.x, wreg[0][i].x, b0);
      b0 = fdot2(z.y, wreg[0][i].y, b0);
      b0 = fdot2(z.z, wreg[0][i].z, b0);
      b0 = fdot2(z.w, wreg[0][i].w, b0);
      b1 = fdot2(z.x, wreg[1][i].x, b1);
      b1 = fdot2(z.y, wreg[1][i].y, b1);
      b1 = fdot2(z.z, wreg[1][i].z, b1);
      b1 = fdot2(z.w, wreg[1][i].w, b1);
      b2 = fdot2(z.x, wreg[2][i].x, b2);
      b2 = fdot2(z.y, wreg[2][i].y, b2);
      b2 = fdot2(z.z, wreg[2][i].z, b2);
      b2 = fdot2(z.w, wreg[2][i].w, b2);
      b3 = fdot2(z.x, wreg[3][i].x, b3);
      b3 = fdot2(z.y, wreg[3][i].y, b3);
      b3 = fdot2(z.z, wreg[3][i].z, b3);
      b3 = fdot2(z.w, wreg[3][i].w, b3);
    }
    a0 += b0; a1 += b1; a2 += b2; a3 += b3;
    // quad butterfly over k-quarters (DPP, VALU-only): all lanes get totals.
    a0 = quad_add(a0);
    a1 = quad_add(a1);
    a2 = quad_add(a2);
    a3 = quad_add(a3);
    // Select own gate total; add own gate-x; apply own nonlinearity.
    float s01 = (kq & 1) ? a1 : a0;
    float s23 = (kq & 1) ? a3 : a2;
    float own = (kq & 2) ? s23 : s01;
    own += (float)__builtin_bit_cast(__fp16, gxh);
    float e = fexp2(own * sl);
    float r = frcp(1.f + e);
    float out = Ac * r + Bc;   // sig (kq 0,1,3) or tanh (kq 2)
    // Fan the 4 gate values back to all quad lanes.
    float ig = quad_bcast<0x00>(out);
    float fg = quad_bcast<0x55>(out);
    float gg = quad_bcast<0xAA>(out);
    float og = quad_bcast<0xFF>(out);
    c = fg * c + ig * gg;
    float e2 = fexp2(c * (2.f * L2E));
    float r2 = frcp(1.f + e2);
    float th = 1.f - 2.f * r2;
    float hv = og * th;

    if (kq == 0) hist[p][tl_][m] = (__fp16)hv;
    // Barrier WITHOUT vmcnt drain: lgkmcnt(0) covers the ds_write above;
    // prefetched gatex loads stay in flight across the barrier.
    __builtin_amdgcn_sched_barrier(0);
    asm volatile("s_waitcnt lgkmcnt(0)");
    __builtin_amdgcn_sched_barrier(0);
    __builtin_amdgcn_s_barrier();
  };

  // 4-deep gate-x prefetch ring (static indices).
  ushort g0 = gxp[0];
  ushort g1 = gxp[(size_t)1 * 65536];
  ushort g2 = gxp[(size_t)2 * 65536];
  ushort g3 = gxp[(size_t)3 * 65536];
  __syncthreads();

  for (int tl = 0; tl < 128; tl += 4) {
    int i0 = tl + 4 > 127 ? 127 : tl + 4;
    int i1 = tl + 5 > 127 ? 127 : tl + 5;
    int i2 = tl + 6 > 127 ? 127 : tl + 6;
    int i3 = tl + 7 > 127 ? 127 : tl + 7;
    ushort n0 = gxp[(size_t)i0 * 65536];
    ushort n1 = gxp[(size_t)i1 * 65536];
    ushort n2 = gxp[(size_t)i2 * 65536];
    ushort n3 = gxp[(size_t)i3 * 65536];
    step(tl + 0, g0);
    step(tl + 1, g1);
    step(tl + 2, g2);
    step(tl + 3, g3);
    g0 = n0; g1 = n1; g2 = n2; g3 = n3;
  }

  if (kq == 0) statec[(size_t)(d * 128 + b) * 128 + m] = c;

  int base = chunk * 128;
  for (int i = tid; i < 4096; i += 1024) {
    int p2 = i >> 11, r2i = i & 2047;
    int sl2 = r2i >> 4, q4 = r2i & 15;
    int b2 = bpair * 2 + p2;
    int s = d ? (511 - (base + sl2)) : (base + sl2);
    *(uint4*)(&hh[((size_t)(d * 512 + s) * 128 + b2) * 64 + q4 * 4]) =
        *(const uint4*)((const uint*)&hist[p2][sl2][0] + q4 * 4);
  }
}

// ---------------------------------------------------------------------------
// Output projection (unchanged from R8)
// ---------------------------------------------------------------------------
__global__ __launch_bounds__(256) void outproj_kernel(
    const uint* __restrict__ hh, const uint* __restrict__ woutp,
    const float* __restrict__ bout, float* __restrict__ feats)
{
  __shared__ __align__(16) uint4 zrow[8][32];
  __shared__ __align__(16) uint4 wlds[32][32];
  int tid = threadIdx.x;
  for (int j = tid; j < 1024; j += 256) {
    int k = j >> 5, i = j & 31;
    wlds[i][k] = ((const uint4*)woutp)[j];
  }
  int rl = tid >> 5, q = tid & 31;
  int row = blockIdx.x * 8 + rl;
  int b = row >> 9, s = row & 511;
  const uint4* hf4 = (const uint4*)(hh + ((size_t)s * BATCH + b) * 64);
  const uint4* hb4 = (const uint4*)(hh + ((size_t)(SEQ + s) * BATCH + b) * 64);
  zrow[rl][q] = (q < 16) ? hf4[q] : hb4[q - 16];
  __syncthreads();
  int k = q;
  float acc = bout[k];
#pragma unroll
  for (int i = 0; i < 32; ++i) {
    uint4 z = zrow[rl][i];
    uint4 wv = wlds[i][k];
    acc = fdot2(z.x, wv.x, acc);
    acc = fdot2(z.y, wv.y, acc);
    acc = fdot2(z.z, wv.z, acc);
    acc = fdot2(z.w, wv.w, acc);
  }
  feats[(size_t)row * 32 + k] = acc;
}

// ---------------------------------------------------------------------------
// CRF numerator (unchanged)
// ---------------------------------------------------------------------------
__global__ __launch_bounds__(64) void crf_num_kernel(
    const int* __restrict__ tags, const float* __restrict__ feats,
    const float* __restrict__ trans, float* __restrict__ num)
{
  int b = blockIdx.x, l = threadIdx.x;
  const int* tb = tags + b * SEQ;
  float acc = 0.f;
  for (int s = l; s < SEQ; s += 64) {
    int tg = tb[s];
    int pv = (s == 0) ? START_TAG : tb[s - 1];
    acc += trans[pv * NTAG + tg] + feats[((size_t)b * SEQ + s) * NTAG + tg];
  }
#pragma unroll
  for (int msk = 1; msk < 64; msk <<= 1) acc += __shfl_xor(acc, msk);
  if (l == 0) num[b] = acc + trans[tb[SEQ - 1] * NTAG + END_TAG];
}

// ---------------------------------------------------------------------------
// CRF stage A (unchanged from R8)
// ---------------------------------------------------------------------------
__global__ __launch_bounds__(64) void crf_seg_kernel(
    const float* __restrict__ feats, const float* __restrict__ trans,
    uint* __restrict__ segP, float* __restrict__ segL)
{
  const float L2E = 1.4426950408889634f;
  int blk = blockIdx.x;
  int b = blk >> 5, j = blk & 31;
  int tstart = 1 + 16 * j;
  int nsteps = (j == 31) ? 15 : 16;
  int lane = threadIdx.x;
  int c = lane & 15, q = lane >> 4;

  half8_t afr[2];
#pragma unroll
  for (int rt = 0; rt < 2; ++rt) {
    const float* trow = trans + (rt * 16 + c) * 32 + q * 8;
    float e[8];
#pragma unroll
    for (int i = 0; i < 8; ++i) e[i] = fexp2(trow[i] * L2E);
    uint4 u;
    u.x = packh2(e[0], e[1]); u.y = packh2(e[2], e[3]);
    u.z = packh2(e[4], e[5]); u.w = packh2(e[6], e[7]);
    afr[rt] = __builtin_bit_cast(half8_t, u);
  }
  half8_t bfr[2];
#pragma unroll
  for (int ct = 0; ct < 2; ++ct) {
    uint4 u;
    uint vals[8];
#pragma unroll
    for (int i = 0; i < 8; ++i)
      vals[i] = ((q * 8 + i) == (ct * 16 + c)) ? 0x3C00u : 0u;
    u.x = vals[0] | (vals[1] << 16);
    u.y = vals[2] | (vals[3] << 16);
    u.z = vals[4] | (vals[5] << 16);
    u.w = vals[6] | (vals[7] << 16);
    bfr[ct] = __builtin_bit_cast(half8_t, u);
  }

  __shared__ __fp16 P16[32 * 36];

  const float* fb = feats + ((size_t)b * SEQ + tstart) * NTAG;
  float Lacc = 0.f;
  float4 pre0 = *(const float4*)(fb + q * 4);
  float4 pre1 = *(const float4*)(fb + 16 + q * 4);

  for (int s = 0; s < nsteps; ++s) {
    float4 f0 = pre0, f1 = pre1;
    if (s + 1 < nsteps) {
      pre0 = *(const float4*)(fb + (s + 1) * 32 + q * 4);
      pre1 = *(const float4*)(fb + (s + 1) * 32 + 16 + q * 4);
    }
    floatx4 z4 = (floatx4){0.f, 0.f, 0.f, 0.f};
    floatx4 c00 = __builtin_amdgcn_mfma_f32_16x16x32_f16(afr[0], bfr[0], z4, 0, 0, 0);
    floatx4 c01 = __builtin_amdgcn_mfma_f32_16x16x32_f16(afr[0], bfr[1], z4, 0, 0, 0);
    floatx4 c10 = __builtin_amdgcn_mfma_f32_16x16x32_f16(afr[1], bfr[0], z4, 0, 0, 0);
    floatx4 c11 = __builtin_amdgcn_mfma_f32_16x16x32_f16(afr[1], bfr[1], z4, 0, 0, 0);
    float pf0[4], pf1[4];
    pf0[0] = fexp2(f0.x * L2E); pf0[1] = fexp2(f0.y * L2E);
    pf0[2] = fexp2(f0.z * L2E); pf0[3] = fexp2(f0.w * L2E);
    pf1[0] = fexp2(f1.x * L2E); pf1[1] = fexp2(f1.y * L2E);
    pf1[2] = fexp2(f1.z * L2E); pf1[3] = fexp2(f1.w * L2E);
    float v00[4], v01[4], v10[4], v11[4];
#pragma unroll
    for (int rg = 0; rg < 4; ++rg) {
      v00[rg] = c00[rg] * pf0[rg];
      v01[rg] = c01[rg] * pf0[rg];
      v10[rg] = c10[rg] * pf1[rg];
      v11[rg] = c11[rg] * pf1[rg];
    }
    float mx = 0.f;
#pragma unroll
    for (int rg = 0; rg < 4; ++rg)
      mx = fmaxf(mx, fmaxf(fmaxf(v00[rg], v01[rg]), fmaxf(v10[rg], v11[rg])));
    uint ub = (uint)__builtin_amdgcn_readfirstlane((int)__builtin_bit_cast(uint, mx));
    int e = (int)((ub >> 23) & 255u);
    Lacc += (float)(e - 127);
    float sc = __builtin_bit_cast(float, (uint)((254 - e) << 23));

    __syncthreads();
    {
      uint2 wv2;
      wv2.x = packh2(v00[0] * sc, v00[1] * sc);
      wv2.y = packh2(v00[2] * sc, v00[3] * sc);
      *(uint2*)(&P16[c * 36 + q * 4]) = wv2;
      wv2.x = packh2(v10[0] * sc, v10[1] * sc);
      wv2.y = packh2(v10[2] * sc, v10[3] * sc);
      *(uint2*)(&P16[c * 36 + 16 + q * 4]) = wv2;
      wv2.x = packh2(v01[0] * sc, v01[1] * sc);
      wv2.y = packh2(v01[2] * sc, v01[3] * sc);
      *(uint2*)(&P16[(16 + c) * 36 + q * 4]) = wv2;
      wv2.x = packh2(v11[0] * sc, v11[1] * sc);
      wv2.y = packh2(v11[2] * sc, v11[3] * sc);
      *(uint2*)(&P16[(16 + c) * 36 + 16 + q * 4]) = wv2;
    }
    __syncthreads();
    {
      uint2 lo0 = *(const uint2*)(&P16[c * 36 + q * 8]);
      uint2 hi0 = *(const uint2*)(&P16[c * 36 + q * 8 + 4]);
      uint4 u0; u0.x = lo0.x; u0.y = lo0.y; u0.z = hi0.x; u0.w = hi0.y;
      bfr[0] = __builtin_bit_cast(half8_t, u0);
      uint2 lo1 = *(const uint2*)(&P16[(16 + c) * 36 + q * 8]);
      uint2 hi1 = *(const uint2*)(&P16[(16 + c) * 36 + q * 8 + 4]);
      uint4 u1; u1.x = lo1.x; u1.y = lo1.y; u1.z = hi1.x; u1.w = hi1.y;
      bfr[1] = __builtin_bit_cast(half8_t, u1);
    }
  }
  __syncthreads();
  uint* gp = segP + (size_t)blk * 512;
  if (lane < 32) {
    int i = lane;
#pragma unroll
    for (int tp = 0; tp < 16; ++tp) {
      uint lo = (uint)__builtin_bit_cast(unsigned short, P16[(2 * tp) * 36 + i]);
      uint hi = (uint)__builtin_bit_cast(unsigned short, P16[(2 * tp + 1) * 36 + i]);
      gp[i * 16 + tp] = lo | (hi << 16);
    }
  }
  if (lane == 0) segL[blk] = Lacc;
}

// ---------------------------------------------------------------------------
// CRF stage B (unchanged from R8)
// ---------------------------------------------------------------------------
__global__ __launch_bounds__(64) void crf_comb_kernel(
    const float* __restrict__ feats, const float* __restrict__ trans,
    const uint* __restrict__ segP, const float* __restrict__ segL,
    float* __restrict__ den)
{
  const float L2E = 1.4426950408889634f, LN2 = 0.6931471805599453f;
  int b = blockIdx.x, l = threadIdx.x;
  int i = l & 31, hp = l >> 5;
  const float* fb = feats + (size_t)b * SEQ * NTAG;

  float sT = 0.f;
  for (int p = 0; p < 32; ++p) sT += fexp2(trans[i * 32 + p] * L2E);
  float v = (1.f + sT) * fexp2(fb[i] * L2E);
  float L = -10000.f * L2E;

  float vo = __shfl_xor(v, 1);
  uint pv = (i & 1) ? packh2(vo, v) : packh2(v, vo);

  const uint* gp0 = segP + (size_t)b * 32 * 512 + i * 16 + hp * 8;
  uint4 ra = *(const uint4*)(gp0);
  uint4 rb = *(const uint4*)(gp0 + 4);

  for (int seg = 0; seg < 32; ++seg) {
    uint4 ca = ra, cb = rb;
    if (seg + 1 < 32) {
      ra = *(const uint4*)(gp0 + (seg + 1) * 512);
      rb = *(const uint4*)(gp0 + (seg + 1) * 512 + 4);
    }
    float g0 = __shfl(__builtin_bit_cast(float, pv), hp * 16 + 0);
    float g1 = __shfl(__builtin_bit_cast(float, pv), hp * 16 + 2);
    float g2 = __shfl(__builtin_bit_cast(float, pv), hp * 16 + 4);
    float g3 = __shfl(__builtin_bit_cast(float, pv), hp * 16 + 6);
    float g4 = __shfl(__builtin_bit_cast(float, pv), hp * 16 + 8);
    float g5 = __shfl(__builtin_bit_cast(float, pv), hp * 16 + 10);
    float g6 = __shfl(__builtin_bit_cast(float, pv), hp * 16 + 12);
    float g7 = __shfl(__builtin_bit_cast(float, pv), hp * 16 + 14);
    float acc = 0.f;
    acc = fdot2(__builtin_bit_cast(uint, g0), ca.x, acc);
    acc = fdot2(__builtin_bit_cast(uint, g1), ca.y, acc);
    acc = fdot2(__builtin_bit_cast(uint, g2), ca.z, acc);
    acc = fdot2(__builtin_bit_cast(uint, g3), ca.w, acc);
    acc = fdot2(__builtin_bit_cast(uint, g4), cb.x, acc);
    acc = fdot2(__builtin_bit_cast(uint, g5), cb.y, acc);
    acc = fdot2(__builtin_bit_cast(uint, g6), cb.z, acc);
    acc = fdot2(__builtin_bit_cast(uint, g7), cb.w, acc);
    float sm = acc + __shfl_xor(acc, 32);
    uint ub = (uint)__builtin_amdgcn_readfirstlane((int)__builtin_bit_cast(uint, sm));
    int e = (int)((ub >> 23) & 255u);
    L += (float)(e - 127) + segL[b * 32 + seg];
    float sc = __builtin_bit_cast(float, (uint)((254 - e) << 23));
    v = sm * sc;
    float vo2 = __shfl_xor(v, 1);
    pv = (i & 1) ? packh2(vo2, v) : packh2(v, vo2);
  }
  float wv = v * fexp2(trans[i * 32 + END_TAG] * L2E);
#pragma unroll
  for (int msk = 1; msk <= 16; msk <<= 1) wv += __shfl_xor(wv, msk);
  if (l == 0) den[b] = (L + flog2(wv)) * LN2;
}

__global__ __launch_bounds__(128) void final_kernel(
    const float* __restrict__ num, const float* __restrict__ den,
    float* __restrict__ out)
{
  int tid = threadIdx.x;
  float v = num[tid] - den[tid];
#pragma unroll
  for (int msk = 1; msk < 64; msk <<= 1) v += __shfl_xor(v, msk);
  __shared__ float tmp[2];
  if ((tid & 63) == 0) tmp[tid >> 6] = v;
  __syncthreads();
  if (tid == 0) out[0] = (tmp[0] + tmp[1]) * (1.f / 128.f);
}

// ---------------------------------------------------------------------------
// Workspace layout (bytes): same as R8 (gatex region overlaps later-phase
// buffers deliberately — gatex is dead after the chunk loop)
// ---------------------------------------------------------------------------
extern "C" void kernel_launch(void* const* d_in, const int* in_sizes, int n_in,
                              void* d_out, int out_size, void* d_ws, size_t ws_size,
                              hipStream_t stream)
{
  const int* sentence = (const int*)d_in[0];
  const int* tags = (const int*)d_in[1];
  const float* embed = (const float*)d_in[2];
  const float* Wihf = (const float*)d_in[3];
  const float* Whhf = (const float*)d_in[4];
  const float* bihf = (const float*)d_in[5];
  const float* bhhf = (const float*)d_in[6];
  const float* Wihb = (const float*)d_in[7];
  const float* Whhb = (const float*)d_in[8];
  const float* bihb = (const float*)d_in[9];
  const float* bhhb = (const float*)d_in[10];
  const float* Wout = (const float*)d_in[11];
  const float* bout = (const float*)d_in[12];
  const float* trans = (const float*)d_in[13];
  const float* h0 = (const float*)d_in[14];
  const float* c0 = (const float*)d_in[15];
  float* out = (float*)d_out;

  char* ws = (char*)d_ws;
  uint* wihI = (uint*)(ws + 0);
  uint* whh = (uint*)(ws + 262144);
  uint* woutp = (uint*)(ws + 524288);
  float* biasI = (float*)(ws + 540672);
  float* numb = (float*)(ws + 544768);
  float* denb = (float*)(ws + 545280);
  float* statec = (float*)(ws + 545792);
  uint* hh = (uint*)(ws + 1048576);
  uint* gatex = (uint*)(ws + 34603008);
  float* feats = (float*)(ws + 34603008);
  uint* segP = (uint*)(ws + 42991616);
  float* segL = (float*)(ws + 51380224);

  hipLaunchKernelGGL(prep_kernel, dim3(532), dim3(256), 0, stream,
                     Wihf, Whhf, bihf, bhhf, Wihb, Whhb, bihb, bhhb, Wout,
                     wihI, whh, woutp, biasI);
  for (int c = 0; c < 4; ++c) {
    hipLaunchKernelGGL(gemmx_kernel, dim3(1024), dim3(256), 0, stream,
                       sentence, embed, wihI, biasI, gatex, c);
    hipLaunchKernelGGL(lstm_kernel, dim3(128), dim3(1024), 0, stream,
                       gatex, whh, h0, c0, statec, hh, c);
  }
  hipLaunchKernelGGL(outproj_kernel, dim3(8192), dim3(256), 0, stream,
                     hh, woutp, bout, feats);
  hipLaunchKernelGGL(crf_num_kernel, dim3(128), dim3(64), 0, stream,
                     tags, feats, trans, numb);
  hipLaunchKernelGGL(crf_seg_kernel, dim3(4096), dim3(64), 0, stream,
                     feats, trans, segP, segL);
  hipLaunchKernelGGL(crf_comb_kernel, dim3(128), dim3(64), 0, stream,
                     feats, trans, segP, segL, denb);
  hipLaunchKernelGGL(final_kernel, dim3(1), dim3(128), 0, stream,
                     numb, denb, out);
}

// Round 12
// 547.143 us; speedup vs baseline: 1.4132x; 1.3828x over previous
//
#include <hip/hip_runtime.h>

typedef unsigned int uint;
typedef unsigned short ushort;
typedef __fp16 half2_t __attribute__((ext_vector_type(2)));
typedef __fp16 half8_t __attribute__((ext_vector_type(8)));
typedef float floatx4 __attribute__((ext_vector_type(4)));

#define SEQ 512
#define BATCH 128
#define HID 128
#define NTAG 32
#define START_TAG 30
#define END_TAG 31

__device__ __forceinline__ float fdot2(uint a, uint b, float c) {
  return __builtin_amdgcn_fdot2(__builtin_bit_cast(half2_t, a),
                                __builtin_bit_cast(half2_t, b), c, false);
}
__device__ __forceinline__ uint packh2(float a, float b) {
  half2_t h = __builtin_amdgcn_cvt_pkrtz(a, b);
  return __builtin_bit_cast(uint, h);
}
__device__ __forceinline__ float frcp(float x) { return __builtin_amdgcn_rcpf(x); }
__device__ __forceinline__ float fsig(float x) { return frcp(1.f + __expf(-x)); }
__device__ __forceinline__ float ftanh(float x) { return 1.f - 2.f * frcp(1.f + __expf(2.f * x)); }
__device__ __forceinline__ float fexp2(float x) { return __builtin_amdgcn_exp2f(x); }
__device__ __forceinline__ float flog2(float x) { return __builtin_amdgcn_logf(x); }

// Quad butterfly sum via DPP quad_perm (VALU pipe, no LDS):
// 0xB1 = quad_perm[1,0,3,2] (xor 1), 0x4E = quad_perm[2,3,0,1] (xor 2).
__device__ __forceinline__ float quad_add(float x) {
  int a = __builtin_bit_cast(int, x);
  int b = __builtin_amdgcn_update_dpp(0, a, 0xB1, 0xF, 0xF, true);
  float y = x + __builtin_bit_cast(float, b);
  int c2 = __builtin_bit_cast(int, y);
  int d2 = __builtin_amdgcn_update_dpp(0, c2, 0x4E, 0xF, 0xF, true);
  return y + __builtin_bit_cast(float, d2);
}
// Quad broadcast of lane L (CTRL = 0x00/0x55/0xAA/0xFF for L=0/1/2/3).
template <int CTRL>
__device__ __forceinline__ float quad_bcast(float x) {
  int a = __builtin_bit_cast(int, x);
  int b = __builtin_amdgcn_update_dpp(0, a, CTRL, 0xF, 0xF, true);
  return __builtin_bit_cast(float, b);
}

// ---------------------------------------------------------------------------
// prep (unchanged from R8)
// ---------------------------------------------------------------------------
__global__ __launch_bounds__(256) void prep_kernel(
    const float* __restrict__ Wihf, const float* __restrict__ Whhf,
    const float* __restrict__ bihf, const float* __restrict__ bhhf,
    const float* __restrict__ Wihb, const float* __restrict__ Whhb,
    const float* __restrict__ bihb, const float* __restrict__ bhhb,
    const float* __restrict__ Wout,
    uint* __restrict__ wihI, uint* __restrict__ whh,
    uint* __restrict__ woutp, float* __restrict__ biasI)
{
  int idx = blockIdx.x * 256 + threadIdx.x;
  if (idx < 65536) {
    int d = idx >> 15, rem = idx & 32767;
    int n = rem >> 6, dw = rem & 63;
    int m = n >> 2, q = n & 3;
    int g = q * 128 + m;
    const float* W = d ? Wihb : Wihf;
    wihI[idx] = packh2(W[g * 128 + 2 * dw], W[g * 128 + 2 * dw + 1]);
  }
  int i2 = idx - 65536;
  if (i2 >= 0 && i2 < 65536) {
    int d = i2 >> 15, rem = i2 & 32767;
    int g = rem >> 6, dw = rem & 63;
    const float* W = d ? Whhb : Whhf;
    whh[i2] = packh2(W[g * 128 + 2 * dw], W[g * 128 + 2 * dw + 1]);
  }
  int i3 = idx - 131072;
  if (i3 >= 0 && i3 < 4096) {
    int k = i3 >> 7, dw = i3 & 127;
    float a, b2;
    if (dw < 64) { a = Wout[k * 256 + 2 * dw]; b2 = Wout[k * 256 + 2 * dw + 1]; }
    else { int j = dw - 64; a = Wout[k * 256 + 128 + 2 * j]; b2 = Wout[k * 256 + 128 + 2 * j + 1]; }
    woutp[i3] = packh2(a, b2);
  }
  int i4 = idx - 135168;
  if (i4 >= 0 && i4 < 1024) {
    int d = i4 >> 9, n = i4 & 511;
    int g = (n & 3) * 128 + (n >> 2);
    biasI[i4] = d ? (bihb[g] + bhhb[g]) : (bihf[g] + bhhf[g]);
  }
}

// ---------------------------------------------------------------------------
// gemmx (unchanged from R8)
// ---------------------------------------------------------------------------
__global__ __launch_bounds__(256, 2) void gemmx_kernel(
    const int* __restrict__ sentence, const float* __restrict__ embed,
    const uint* __restrict__ wihI, const float* __restrict__ biasI,
    uint* __restrict__ gatex, int chunk)
{
  int blk = blockIdx.x;
  int tl = blk & 127, nb = (blk >> 7) & 3, d = blk >> 9;
  int t = chunk * 128 + tl;
  int s = d ? (511 - t) : t;
  __shared__ int tok[128];
  int tid = threadIdx.x;
  if (tid < 128) tok[tid] = sentence[tid * SEQ + s];
  __syncthreads();

  int w = tid >> 6, lane = tid & 63;
  int q = lane >> 4, r = lane & 15;
  int wr = w >> 1, wc = w & 1;
  int r0 = wr * 64;
  int c0 = nb * 128 + wc * 64;

  floatx4 acc[4][4];
#pragma unroll
  for (int i = 0; i < 4; ++i)
#pragma unroll
    for (int j = 0; j < 4; ++j) acc[i][j] = (floatx4){0.f, 0.f, 0.f, 0.f};

  const float4* aptr[4];
#pragma unroll
  for (int i = 0; i < 4; ++i)
    aptr[i] = (const float4*)(embed + (size_t)tok[r0 + i * 16 + r] * HID) + q * 2;
  const uint4* bptr[4];
#pragma unroll
  for (int j = 0; j < 4; ++j)
    bptr[j] = (const uint4*)(wihI + ((size_t)d * 512 + c0 + j * 16 + r) * 64) + q;

#pragma unroll
  for (int kc = 0; kc < 4; ++kc) {
    half8_t af[4], bf[4];
#pragma unroll
    for (int i = 0; i < 4; ++i) {
      float4 x0 = aptr[i][kc * 8];
      float4 x1 = aptr[i][kc * 8 + 1];
      uint4 u;
      u.x = packh2(x0.x, x0.y); u.y = packh2(x0.z, x0.w);
      u.z = packh2(x1.x, x1.y); u.w = packh2(x1.z, x1.w);
      af[i] = __builtin_bit_cast(half8_t, u);
    }
#pragma unroll
    for (int j = 0; j < 4; ++j)
      bf[j] = __builtin_bit_cast(half8_t, bptr[j][kc * 4]);
#pragma unroll
    for (int i = 0; i < 4; ++i)
#pragma unroll
      for (int j = 0; j < 4; ++j)
        acc[i][j] = __builtin_amdgcn_mfma_f32_16x16x32_f16(af[i], bf[j], acc[i][j], 0, 0, 0);
  }

  __fp16* gat = ((__fp16*)gatex) + (size_t)d * 16384 * 512;
#pragma unroll
  for (int j = 0; j < 4; ++j) {
    int n = c0 + j * 16 + r;
    float bb = biasI[d * 512 + n];
#pragma unroll
    for (int i = 0; i < 4; ++i) {
      int rb = r0 + i * 16 + q * 4;
#pragma unroll
      for (int reg = 0; reg < 4; ++reg) {
        float v = acc[i][j][reg] + bb;
        gat[((size_t)(tl * 128 + rb + reg)) * 512 + n] = (__fp16)v;
      }
    }
  }
}

// ---------------------------------------------------------------------------
// LSTM recurrence — R15 verbatim (best measured: 79.3us/dispatch, VGPR 88,
// weights resident). R16-R19: two-pair co-schedule needs 1024-thr WGs, and
// 1024-thr WGs cap VGPR at ~56 on this toolchain regardless of LDS padding
// (86KB, 1 WG/CU), launch_bounds, waves_per_eu, or asm anchors -> weights
// sink to L2 re-stream (126-129us). Reverted per pre-commitment.
// ---------------------------------------------------------------------------
__global__ __attribute__((amdgpu_waves_per_eu(2, 2))) __launch_bounds__(512)
void lstm_kernel(
    const uint* __restrict__ gatex, const uint* __restrict__ whh,
    const float* __restrict__ h0, const float* __restrict__ c0,
    float* __restrict__ statec, uint* __restrict__ hh, int chunk)
{
  const float L2E = 1.4426950408889634f;
  const int wg = blockIdx.x;
  const int d = wg >> 7, b = wg & 127;
  const int tid = threadIdx.x;
  const int kq = tid & 3, m = tid >> 2;

  __shared__ __align__(16) __fp16 hist[128][128];   // 32 KB

  // Lane-constant nonlinearity params: kq==2 -> tanh, else sigmoid.
  const bool isg = (kq == 2);
  const float sl = isg ? (2.f * L2E) : (-L2E);
  const float Ac = isg ? -2.f : 1.f;
  const float Bc = isg ? 1.f : 0.f;

  // Weights: gate g row = g*128+m (64 uints); this thread's quarter = 4 uint4.
  const uint4* wh4 = (const uint4*)whh + (size_t)d * 8192;
  uint4 wreg[4][4];
#pragma unroll
  for (int g = 0; g < 4; ++g) {
    const uint4* row = wh4 + ((size_t)(g * 128 + m)) * 16 + kq * 4;
#pragma unroll
    for (int i = 0; i < 4; ++i) wreg[g][i] = row[i];
  }

  float c = (chunk == 0) ? c0[(size_t)(d * 128 + b) * 128 + m]
                         : statec[(size_t)(d * 128 + b) * 128 + m];

  if (tid < 64) {
    uint* h127 = (uint*)&hist[127][0];
    if (chunk == 0) {
      float2 hv = ((const float2*)(h0 + (size_t)(d * 128 + b) * 128))[tid];
      h127[tid] = packh2(hv.x, hv.y);
    } else {
      int sprev = d ? (511 - (chunk * 128 - 1)) : (chunk * 128 - 1);
      h127[tid] = hh[((size_t)(d * 512 + sprev) * 128 + b) * 64 + tid];
    }
  }
  // Gate-x: this thread's own gate only (ushort at half index 4m+kq).
  const ushort* gxp = (const ushort*)gatex + (size_t)d * 8388608 +
                      (size_t)b * 512 + 4 * m + kq;

  // One LSTM step: consume own-gate gate-x value gxh at timestep tl_.
  auto step = [&](int tl_, ushort gxh) {
    float a0 = 0.f, a1 = 0.f, a2 = 0.f, a3 = 0.f;
    float b0 = 0.f, b1 = 0.f, b2 = 0.f, b3 = 0.f;
    const uint4* z4 = (const uint4*)(&hist[(tl_ + 127) & 127][kq * 32]);
#pragma unroll
    for (int i = 0; i < 2; ++i) {
      uint4 z = z4[i];
      a0 = fdot2(z.x, wreg[0][i].x, a0);
      a0 = fdot2(z.y, wreg[0][i].y, a0);
      a0 = fdot2(z.z, wreg[0][i].z, a0);
      a0 = fdot2(z.w, wreg[0][i].w, a0);
      a1 = fdot2(z.x, wreg[1][i].x, a1);
      a1 = fdot2(z.y, wreg[1][i].y, a1);
      a1 = fdot2(z.z, wreg[1][i].z, a1);
      a1 = fdot2(z.w, wreg[1][i].w, a1);
      a2 = fdot2(z.x, wreg[2][i].x, a2);
      a2 = fdot2(z.y, wreg[2][i].y, a2);
      a2 = fdot2(z.z, wreg[2][i].z, a2);
      a2 = fdot2(z.w, wreg[2][i].w, a2);
      a3 = fdot2(z.x, wreg[3][i].x, a3);
      a3 = fdot2(z.y, wreg[3][i].y, a3);
      a3 = fdot2(z.z, wreg[3][i].z, a3);
      a3 = fdot2(z.w, wreg[3][i].w, a3);
    }
#pragma unroll
    for (int i = 2; i < 4; ++i) {
      uint4 z = z4[i];
      b0 = fdot2(z.x, wreg[0][i].x, b0);
      b0 = fdot2(z.y, wreg[0][i].y, b0);
      b0 = fdot2(z.z, wreg[0][i].z, b0);
      b0 = fdot2(z.w, wreg[0][i].w, b0);
      b1 = fdot2(z.x, wreg[1][i].x, b1);
      b1 = fdot2(z.y, wreg[1][i].y, b1);
      b1 = fdot2(z.z, wreg[1][i].z, b1);
      b1 = fdot2(z.w, wreg[1][i].w, b1);
      b2 = fdot2(z.x, wreg[2][i].x, b2);
      b2 = fdot2(z.y, wreg[2][i].y, b2);
      b2 = fdot2(z.z, wreg[2][i].z, b2);
      b2 = fdot2(z.w, wreg[2][i].w, b2);
      b3 = fdot2(z.x, wreg[3][i].x, b3);
      b3 = fdot2(z.y, wreg[3][i].y, b3);
      b3 = fdot2(z.z, wreg[3][i].z, b3);
      b3 = fdot2(z.w, wreg[3][i].w, b3);
    }
    a0 += b0; a1 += b1; a2 += b2; a3 += b3;
    // quad butterfly over k-quarters (DPP, VALU-only): all lanes get totals.
    a0 = quad_add(a0);
    a1 = quad_add(a1);
    a2 = quad_add(a2);
    a3 = quad_add(a3);
    // Select own gate total; add own gate-x; apply own nonlinearity.
    float s01 = (kq & 1) ? a1 : a0;
    float s23 = (kq & 1) ? a3 : a2;
    float own = (kq & 2) ? s23 : s01;
    own += (float)__builtin_bit_cast(__fp16, gxh);
    float e = fexp2(own * sl);
    float r = frcp(1.f + e);
    float out = Ac * r + Bc;   // sig (kq 0,1,3) or tanh (kq 2)
    // Fan the 4 gate values back to all quad lanes.
    float ig = quad_bcast<0x00>(out);
    float fg = quad_bcast<0x55>(out);
    float gg = quad_bcast<0xAA>(out);
    float og = quad_bcast<0xFF>(out);
    c = fg * c + ig * gg;
    float e2 = fexp2(c * (2.f * L2E));
    float r2 = frcp(1.f + e2);
    float th = 1.f - 2.f * r2;
    float hv = og * th;

    if (kq == 0) hist[tl_][m] = (__fp16)hv;
    // Barrier WITHOUT vmcnt drain: lgkmcnt(0) covers the ds_write above;
    // prefetched gatex loads stay in flight across the barrier.
    __builtin_amdgcn_sched_barrier(0);
    asm volatile("s_waitcnt lgkmcnt(0)");
    __builtin_amdgcn_sched_barrier(0);
    __builtin_amdgcn_s_barrier();
  };

  // 4-deep gate-x prefetch ring (static indices).
  ushort g0 = gxp[0];
  ushort g1 = gxp[(size_t)1 * 65536];
  ushort g2 = gxp[(size_t)2 * 65536];
  ushort g3 = gxp[(size_t)3 * 65536];
  __syncthreads();

  for (int tl = 0; tl < 128; tl += 4) {
    int i0 = tl + 4 > 127 ? 127 : tl + 4;
    int i1 = tl + 5 > 127 ? 127 : tl + 5;
    int i2 = tl + 6 > 127 ? 127 : tl + 6;
    int i3 = tl + 7 > 127 ? 127 : tl + 7;
    ushort n0 = gxp[(size_t)i0 * 65536];
    ushort n1 = gxp[(size_t)i1 * 65536];
    ushort n2 = gxp[(size_t)i2 * 65536];
    ushort n3 = gxp[(size_t)i3 * 65536];
    step(tl + 0, g0);
    step(tl + 1, g1);
    step(tl + 2, g2);
    step(tl + 3, g3);
    g0 = n0; g1 = n1; g2 = n2; g3 = n3;
  }

  if (kq == 0) statec[(size_t)(d * 128 + b) * 128 + m] = c;

  int base = chunk * 128;
  for (int i = tid; i < 2048; i += 512) {
    int sl2 = i >> 4, q4 = i & 15;
    int s = d ? (511 - (base + sl2)) : (base + sl2);
    *(uint4*)(&hh[((size_t)(d * 512 + s) * 128 + b) * 64 + q4 * 4]) =
        *(const uint4*)((const uint*)&hist[sl2][0] + q4 * 4);
  }
}

// ---------------------------------------------------------------------------
// Output projection — MFMA rewrite (R20, resubmitted after infra flake).
// Old: 8192 blocks each loading ALL of Wout (16KB) into LDS for 8 rows
// (134MB redundant L2 traffic) + LDS-pipe-bound dot loop. New: plain GEMM
// [65536x256]x[256x32] on MFMA, zero LDS. B (Wout) fragments in registers;
// A streams from hh as coalesced uint4. Fragment mapping identical to the
// verified gemmx kernel. 1024 blocks x 256 thr, 64 rows/block.
// ---------------------------------------------------------------------------
__global__ __launch_bounds__(256) void outproj_kernel(
    const uint* __restrict__ hh, const uint* __restrict__ woutp,
    const float* __restrict__ bout, float* __restrict__ feats)
{
  int tid = threadIdx.x;
  int w = tid >> 6, lane = tid & 63;
  int q = lane >> 4, c = lane & 15;
  int row0 = blockIdx.x * 64 + w * 16;

  // B fragments: tile t covers tags t*16+c; ks walks K=256 in 32-chunks.
  const uint4* wp4 = (const uint4*)woutp;
  uint4 bf0[8], bf1[8];
#pragma unroll
  for (int ks = 0; ks < 8; ++ks) {
    bf0[ks] = wp4[(size_t)c * 32 + ks * 4 + q];
    bf1[ks] = wp4[(size_t)(16 + c) * 32 + ks * 4 + q];
  }

  // This lane's A row: row = b*512 + s (b major), z = [h_fwd | h_bwd].
  int rr = row0 + c;
  int br = rr >> 9, sr = rr & 511;
  const uint4* af4 = (const uint4*)(hh + ((size_t)(sr * BATCH + br)) * 64);
  const uint4* ab4 = (const uint4*)(hh + ((size_t)((SEQ + sr) * BATCH + br)) * 64);

  floatx4 acc0 = (floatx4){0.f, 0.f, 0.f, 0.f};
  floatx4 acc1 = (floatx4){0.f, 0.f, 0.f, 0.f};
#pragma unroll
  for (int ks = 0; ks < 8; ++ks) {
    uint4 a = (ks < 4) ? af4[ks * 4 + q] : ab4[(ks - 4) * 4 + q];
    half8_t af = __builtin_bit_cast(half8_t, a);
    acc0 = __builtin_amdgcn_mfma_f32_16x16x32_f16(
        af, __builtin_bit_cast(half8_t, bf0[ks]), acc0, 0, 0, 0);
    acc1 = __builtin_amdgcn_mfma_f32_16x16x32_f16(
        af, __builtin_bit_cast(half8_t, bf1[ks]), acc1, 0, 0, 0);
  }

  float bb0 = bout[c], bb1 = bout[16 + c];
#pragma unroll
  for (int reg = 0; reg < 4; ++reg) {
    int orow = row0 + q * 4 + reg;
    feats[(size_t)orow * 32 + c] = acc0[reg] + bb0;
    feats[(size_t)orow * 32 + 16 + c] = acc1[reg] + bb1;
  }
}

// ---------------------------------------------------------------------------
// CRF numerator (unchanged)
// ---------------------------------------------------------------------------
__global__ __launch_bounds__(64) void crf_num_kernel(
    const int* __restrict__ tags, const float* __restrict__ feats,
    const float* __restrict__ trans, float* __restrict__ num)
{
  int b = blockIdx.x, l = threadIdx.x;
  const int* tb = tags + b * SEQ;
  float acc = 0.f;
  for (int s = l; s < SEQ; s += 64) {
    int tg = tb[s];
    int pv = (s == 0) ? START_TAG : tb[s - 1];
    acc += trans[pv * NTAG + tg] + feats[((size_t)b * SEQ + s) * NTAG + tg];
  }
#pragma unroll
  for (int msk = 1; msk < 64; msk <<= 1) acc += __shfl_xor(acc, msk);
  if (l == 0) num[b] = acc + trans[tb[SEQ - 1] * NTAG + END_TAG];
}

// ---------------------------------------------------------------------------
// CRF stage A (unchanged from R8)
// ---------------------------------------------------------------------------
__global__ __launch_bounds__(64) void crf_seg_kernel(
    const float* __restrict__ feats, const float* __restrict__ trans,
    uint* __restrict__ segP, float* __restrict__ segL)
{
  const float L2E = 1.4426950408889634f;
  int blk = blockIdx.x;
  int b = blk >> 5, j = blk & 31;
  int tstart = 1 + 16 * j;
  int nsteps = (j == 31) ? 15 : 16;
  int lane = threadIdx.x;
  int c = lane & 15, q = lane >> 4;

  half8_t afr[2];
#pragma unroll
  for (int rt = 0; rt < 2; ++rt) {
    const float* trow = trans + (rt * 16 + c) * 32 + q * 8;
    float e[8];
#pragma unroll
    for (int i = 0; i < 8; ++i) e[i] = fexp2(trow[i] * L2E);
    uint4 u;
    u.x = packh2(e[0], e[1]); u.y = packh2(e[2], e[3]);
    u.z = packh2(e[4], e[5]); u.w = packh2(e[6], e[7]);
    afr[rt] = __builtin_bit_cast(half8_t, u);
  }
  half8_t bfr[2];
#pragma unroll
  for (int ct = 0; ct < 2; ++ct) {
    uint4 u;
    uint vals[8];
#pragma unroll
    for (int i = 0; i < 8; ++i)
      vals[i] = ((q * 8 + i) == (ct * 16 + c)) ? 0x3C00u : 0u;
    u.x = vals[0] | (vals[1] << 16);
    u.y = vals[2] | (vals[3] << 16);
    u.z = vals[4] | (vals[5] << 16);
    u.w = vals[6] | (vals[7] << 16);
    bfr[ct] = __builtin_bit_cast(half8_t, u);
  }

  __shared__ __fp16 P16[32 * 36];

  const float* fb = feats + ((size_t)b * SEQ + tstart) * NTAG;
  float Lacc = 0.f;
  float4 pre0 = *(const float4*)(fb + q * 4);
  float4 pre1 = *(const float4*)(fb + 16 + q * 4);

  for (int s = 0; s < nsteps; ++s) {
    float4 f0 = pre0, f1 = pre1;
    if (s + 1 < nsteps) {
      pre0 = *(const float4*)(fb + (s + 1) * 32 + q * 4);
      pre1 = *(const float4*)(fb + (s + 1) * 32 + 16 + q * 4);
    }
    floatx4 z4 = (floatx4){0.f, 0.f, 0.f, 0.f};
    floatx4 c00 = __builtin_amdgcn_mfma_f32_16x16x32_f16(afr[0], bfr[0], z4, 0, 0, 0);
    floatx4 c01 = __builtin_amdgcn_mfma_f32_16x16x32_f16(afr[0], bfr[1], z4, 0, 0, 0);
    floatx4 c10 = __builtin_amdgcn_mfma_f32_16x16x32_f16(afr[1], bfr[0], z4, 0, 0, 0);
    floatx4 c11 = __builtin_amdgcn_mfma_f32_16x16x32_f16(afr[1], bfr[1], z4, 0, 0, 0);
    float pf0[4], pf1[4];
    pf0[0] = fexp2(f0.x * L2E); pf0[1] = fexp2(f0.y * L2E);
    pf0[2] = fexp2(f0.z * L2E); pf0[3] = fexp2(f0.w * L2E);
    pf1[0] = fexp2(f1.x * L2E); pf1[1] = fexp2(f1.y * L2E);
    pf1[2] = fexp2(f1.z * L2E); pf1[3] = fexp2(f1.w * L2E);
    float v00[4], v01[4], v10[4], v11[4];
#pragma unroll
    for (int rg = 0; rg < 4; ++rg) {
      v00[rg] = c00[rg] * pf0[rg];
      v01[rg] = c01[rg] * pf0[rg];
      v10[rg] = c10[rg] * pf1[rg];
      v11[rg] = c11[rg] * pf1[rg];
    }
    float mx = 0.f;
#pragma unroll
    for (int rg = 0; rg < 4; ++rg)
      mx = fmaxf(mx, fmaxf(fmaxf(v00[rg], v01[rg]), fmaxf(v10[rg], v11[rg])));
    uint ub = (uint)__builtin_amdgcn_readfirstlane((int)__builtin_bit_cast(uint, mx));
    int e = (int)((ub >> 23) & 255u);
    Lacc += (float)(e - 127);
    float sc = __builtin_bit_cast(float, (uint)((254 - e) << 23));

    __syncthreads();
    {
      uint2 wv2;
      wv2.x = packh2(v00[0] * sc, v00[1] * sc);
      wv2.y = packh2(v00[2] * sc, v00[3] * sc);
      *(uint2*)(&P16[c * 36 + q * 4]) = wv2;
      wv2.x = packh2(v10[0] * sc, v10[1] * sc);
      wv2.y = packh2(v10[2] * sc, v10[3] * sc);
      *(uint2*)(&P16[c * 36 + 16 + q * 4]) = wv2;
      wv2.x = packh2(v01[0] * sc, v01[1] * sc);
      wv2.y = packh2(v01[2] * sc, v01[3] * sc);
      *(uint2*)(&P16[(16 + c) * 36 + q * 4]) = wv2;
      wv2.x = packh2(v11[0] * sc, v11[1] * sc);
      wv2.y = packh2(v11[2] * sc, v11[3] * sc);
      *(uint2*)(&P16[(16 + c) * 36 + 16 + q * 4]) = wv2;
    }
    __syncthreads();
    {
      uint2 lo0 = *(const uint2*)(&P16[c * 36 + q * 8]);
      uint2 hi0 = *(const uint2*)(&P16[c * 36 + q * 8 + 4]);
      uint4 u0; u0.x = lo0.x; u0.y = lo0.y; u0.z = hi0.x; u0.w = hi0.y;
      bfr[0] = __builtin_bit_cast(half8_t, u0);
      uint2 lo1 = *(const uint2*)(&P16[(16 + c) * 36 + q * 8]);
      uint2 hi1 = *(const uint2*)(&P16[(16 + c) * 36 + q * 8 + 4]);
      uint4 u1; u1.x = lo1.x; u1.y = lo1.y; u1.z = hi1.x; u1.w = hi1.y;
      bfr[1] = __builtin_bit_cast(half8_t, u1);
    }
  }
  __syncthreads();
  uint* gp = segP + (size_t)blk * 512;
  if (lane < 32) {
    int i = lane;
#pragma unroll
    for (int tp = 0; tp < 16; ++tp) {
      uint lo = (uint)__builtin_bit_cast(unsigned short, P16[(2 * tp) * 36 + i]);
      uint hi = (uint)__builtin_bit_cast(unsigned short, P16[(2 * tp + 1) * 36 + i]);
      gp[i * 16 + tp] = lo | (hi << 16);
    }
  }
  if (lane == 0) segL[blk] = Lacc;
}

// ---------------------------------------------------------------------------
// CRF stage B (unchanged from R8)
// ---------------------------------------------------------------------------
__global__ __launch_bounds__(64) void crf_comb_kernel(
    const float* __restrict__ feats, const float* __restrict__ trans,
    const uint* __restrict__ segP, const float* __restrict__ segL,
    float* __restrict__ den)
{
  const float L2E = 1.4426950408889634f, LN2 = 0.6931471805599453f;
  int b = blockIdx.x, l = threadIdx.x;
  int i = l & 31, hp = l >> 5;
  const float* fb = feats + (size_t)b * SEQ * NTAG;

  float sT = 0.f;
  for (int p = 0; p < 32; ++p) sT += fexp2(trans[i * 32 + p] * L2E);
  float v = (1.f + sT) * fexp2(fb[i] * L2E);
  float L = -10000.f * L2E;

  float vo = __shfl_xor(v, 1);
  uint pv = (i & 1) ? packh2(vo, v) : packh2(v, vo);

  const uint* gp0 = segP + (size_t)b * 32 * 512 + i * 16 + hp * 8;
  uint4 ra = *(const uint4*)(gp0);
  uint4 rb = *(const uint4*)(gp0 + 4);

  for (int seg = 0; seg < 32; ++seg) {
    uint4 ca = ra, cb = rb;
    if (seg + 1 < 32) {
      ra = *(const uint4*)(gp0 + (seg + 1) * 512);
      rb = *(const uint4*)(gp0 + (seg + 1) * 512 + 4);
    }
    float g0 = __shfl(__builtin_bit_cast(float, pv), hp * 16 + 0);
    float g1 = __shfl(__builtin_bit_cast(float, pv), hp * 16 + 2);
    float g2 = __shfl(__builtin_bit_cast(float, pv), hp * 16 + 4);
    float g3 = __shfl(__builtin_bit_cast(float, pv), hp * 16 + 6);
    float g4 = __shfl(__builtin_bit_cast(float, pv), hp * 16 + 8);
    float g5 = __shfl(__builtin_bit_cast(float, pv), hp * 16 + 10);
    float g6 = __shfl(__builtin_bit_cast(float, pv), hp * 16 + 12);
    float g7 = __shfl(__builtin_bit_cast(float, pv), hp * 16 + 14);
    float acc = 0.f;
    acc = fdot2(__builtin_bit_cast(uint, g0), ca.x, acc);
    acc = fdot2(__builtin_bit_cast(uint, g1), ca.y, acc);
    acc = fdot2(__builtin_bit_cast(uint, g2), ca.z, acc);
    acc = fdot2(__builtin_bit_cast(uint, g3), ca.w, acc);
    acc = fdot2(__builtin_bit_cast(uint, g4), cb.x, acc);
    acc = fdot2(__builtin_bit_cast(uint, g5), cb.y, acc);
    acc = fdot2(__builtin_bit_cast(uint, g6), cb.z, acc);
    acc = fdot2(__builtin_bit_cast(uint, g7), cb.w, acc);
    float sm = acc + __shfl_xor(acc, 32);
    uint ub = (uint)__builtin_amdgcn_readfirstlane((int)__builtin_bit_cast(uint, sm));
    int e = (int)((ub >> 23) & 255u);
    L += (float)(e - 127) + segL[b * 32 + seg];
    float sc = __builtin_bit_cast(float, (uint)((254 - e) << 23));
    v = sm * sc;
    float vo2 = __shfl_xor(v, 1);
    pv = (i & 1) ? packh2(vo2, v) : packh2(v, vo2);
  }
  float wv = v * fexp2(trans[i * 32 + END_TAG] * L2E);
#pragma unroll
  for (int msk = 1; msk <= 16; msk <<= 1) wv += __shfl_xor(wv, msk);
  if (l == 0) den[b] = (L + flog2(wv)) * LN2;
}

__global__ __launch_bounds__(128) void final_kernel(
    const float* __restrict__ num, const float* __restrict__ den,
    float* __restrict__ out)
{
  int tid = threadIdx.x;
  float v = num[tid] - den[tid];
#pragma unroll
  for (int msk = 1; msk < 64; msk <<= 1) v += __shfl_xor(v, msk);
  __shared__ float tmp[2];
  if ((tid & 63) == 0) tmp[tid >> 6] = v;
  __syncthreads();
  if (tid == 0) out[0] = (tmp[0] + tmp[1]) * (1.f / 128.f);
}

// ---------------------------------------------------------------------------
// Workspace layout (bytes): same as R8 (gatex region overlaps later-phase
// buffers deliberately — gatex is dead after the chunk loop)
// ---------------------------------------------------------------------------
extern "C" void kernel_launch(void* const* d_in, const int* in_sizes, int n_in,
                              void* d_out, int out_size, void* d_ws, size_t ws_size,
                              hipStream_t stream)
{
  const int* sentence = (const int*)d_in[0];
  const int* tags = (const int*)d_in[1];
  const float* embed = (const float*)d_in[2];
  const float* Wihf = (const float*)d_in[3];
  const float* Whhf = (const float*)d_in[4];
  const float* bihf = (const float*)d_in[5];
  const float* bhhf = (const float*)d_in[6];
  const float* Wihb = (const float*)d_in[7];
  const float* Whhb = (const float*)d_in[8];
  const float* bihb = (const float*)d_in[9];
  const float* bhhb = (const float*)d_in[10];
  const float* Wout = (const float*)d_in[11];
  const float* bout = (const float*)d_in[12];
  const float* trans = (const float*)d_in[13];
  const float* h0 = (const float*)d_in[14];
  const float* c0 = (const float*)d_in[15];
  float* out = (float*)d_out;

  char* ws = (char*)d_ws;
  uint* wihI = (uint*)(ws + 0);
  uint* whh = (uint*)(ws + 262144);
  uint* woutp = (uint*)(ws + 524288);
  float* biasI = (float*)(ws + 540672);
  float* numb = (float*)(ws + 544768);
  float* denb = (float*)(ws + 545280);
  float* statec = (float*)(ws + 545792);
  uint* hh = (uint*)(ws + 1048576);
  uint* gatex = (uint*)(ws + 34603008);
  float* feats = (float*)(ws + 34603008);
  uint* segP = (uint*)(ws + 42991616);
  float* segL = (float*)(ws + 51380224);

  hipLaunchKernelGGL(prep_kernel, dim3(532), dim3(256), 0, stream,
                     Wihf, Whhf, bihf, bhhf, Wihb, Whhb, bihb, bhhb, Wout,
                     wihI, whh, woutp, biasI);
  for (int c = 0; c < 4; ++c) {
    hipLaunchKernelGGL(gemmx_kernel, dim3(1024), dim3(256), 0, stream,
                       sentence, embed, wihI, biasI, gatex, c);
    hipLaunchKernelGGL(lstm_kernel, dim3(256), dim3(512), 0, stream,
                       gatex, whh, h0, c0, statec, hh, c);
  }
  hipLaunchKernelGGL(outproj_kernel, dim3(1024), dim3(256), 0, stream,
                     hh, woutp, bout, feats);
  hipLaunchKernelGGL(crf_num_kernel, dim3(128), dim3(64), 0, stream,
                     tags, feats, trans, numb);
  hipLaunchKernelGGL(crf_seg_kernel, dim3(4096), dim3(64), 0, stream,
                     feats, trans, segP, segL);
  hipLaunchKernelGGL(crf_comb_kernel, dim3(128), dim3(64), 0, stream,
                     feats, trans, segP, segL, denb);
  hipLaunchKernelGGL(final_kernel, dim3(1), dim3(128), 0, stream,
                     numb, denb, out);
}

// Round 13
// 518.404 us; speedup vs baseline: 1.4916x; 1.0554x over previous
//
#include <hip/hip_runtime.h>

typedef unsigned int uint;
typedef unsigned short ushort;
typedef __fp16 half2_t __attribute__((ext_vector_type(2)));
typedef __fp16 half8_t __attribute__((ext_vector_type(8)));
typedef float floatx4 __attribute__((ext_vector_type(4)));

#define SEQ 512
#define BATCH 128
#define HID 128
#define NTAG 32
#define START_TAG 30
#define END_TAG 31

__device__ __forceinline__ float fdot2(uint a, uint b, float c) {
  return __builtin_amdgcn_fdot2(__builtin_bit_cast(half2_t, a),
                                __builtin_bit_cast(half2_t, b), c, false);
}
__device__ __forceinline__ uint packh2(float a, float b) {
  half2_t h = __builtin_amdgcn_cvt_pkrtz(a, b);
  return __builtin_bit_cast(uint, h);
}
__device__ __forceinline__ float frcp(float x) { return __builtin_amdgcn_rcpf(x); }
__device__ __forceinline__ float fexp2(float x) { return __builtin_amdgcn_exp2f(x); }
__device__ __forceinline__ float flog2(float x) { return __builtin_amdgcn_logf(x); }

// Quad butterfly sum via DPP quad_perm (VALU pipe, no LDS).
__device__ __forceinline__ float quad_add(float x) {
  int a = __builtin_bit_cast(int, x);
  int b = __builtin_amdgcn_update_dpp(0, a, 0xB1, 0xF, 0xF, true);
  float y = x + __builtin_bit_cast(float, b);
  int c2 = __builtin_bit_cast(int, y);
  int d2 = __builtin_amdgcn_update_dpp(0, c2, 0x4E, 0xF, 0xF, true);
  return y + __builtin_bit_cast(float, d2);
}
template <int CTRL>
__device__ __forceinline__ float quad_bcast(float x) {
  int a = __builtin_bit_cast(int, x);
  int b = __builtin_amdgcn_update_dpp(0, a, CTRL, 0xF, 0xF, true);
  return __builtin_bit_cast(float, b);
}

// ---------------------------------------------------------------------------
// prep (unchanged)
// ---------------------------------------------------------------------------
__global__ __launch_bounds__(256) void prep_kernel(
    const float* __restrict__ Wihf, const float* __restrict__ Whhf,
    const float* __restrict__ bihf, const float* __restrict__ bhhf,
    const float* __restrict__ Wihb, const float* __restrict__ Whhb,
    const float* __restrict__ bihb, const float* __restrict__ bhhb,
    const float* __restrict__ Wout,
    uint* __restrict__ wihI, uint* __restrict__ whh,
    uint* __restrict__ woutp, float* __restrict__ biasI)
{
  int idx = blockIdx.x * 256 + threadIdx.x;
  if (idx < 65536) {
    int d = idx >> 15, rem = idx & 32767;
    int n = rem >> 6, dw = rem & 63;
    int m = n >> 2, q = n & 3;
    int g = q * 128 + m;
    const float* W = d ? Wihb : Wihf;
    wihI[idx] = packh2(W[g * 128 + 2 * dw], W[g * 128 + 2 * dw + 1]);
  }
  int i2 = idx - 65536;
  if (i2 >= 0 && i2 < 65536) {
    int d = i2 >> 15, rem = i2 & 32767;
    int g = rem >> 6, dw = rem & 63;
    const float* W = d ? Whhb : Whhf;
    whh[i2] = packh2(W[g * 128 + 2 * dw], W[g * 128 + 2 * dw + 1]);
  }
  int i3 = idx - 131072;
  if (i3 >= 0 && i3 < 4096) {
    int k = i3 >> 7, dw = i3 & 127;
    float a, b2;
    if (dw < 64) { a = Wout[k * 256 + 2 * dw]; b2 = Wout[k * 256 + 2 * dw + 1]; }
    else { int j = dw - 64; a = Wout[k * 256 + 128 + 2 * j]; b2 = Wout[k * 256 + 128 + 2 * j + 1]; }
    woutp[i3] = packh2(a, b2);
  }
  int i4 = idx - 135168;
  if (i4 >= 0 && i4 < 1024) {
    int d = i4 >> 9, n = i4 & 511;
    int g = (n & 3) * 128 + (n >> 2);
    biasI[i4] = d ? (bihb[g] + bhhb[g]) : (bihf[g] + bhhf[g]);
  }
}

// ---------------------------------------------------------------------------
// gemmx core, templated on whether gatex holds one chunk (small ws) or all
// 512 timesteps (big ws). ALLT: row index uses global t; else local tl.
// ---------------------------------------------------------------------------
template <bool ALLT>
__device__ __forceinline__ void gemmx_body(
    const int* __restrict__ sentence, const float* __restrict__ embed,
    const uint* __restrict__ wihI, const float* __restrict__ biasI,
    uint* __restrict__ gatex, int chunk, int blk)
{
  int tl = blk & 127, nb = (blk >> 7) & 3, d = blk >> 9;
  int t = chunk * 128 + tl;
  int s = d ? (511 - t) : t;
  __shared__ int tok[128];
  int tid = threadIdx.x;
  if (tid < 128) tok[tid] = sentence[tid * SEQ + s];
  __syncthreads();

  int w = tid >> 6, lane = tid & 63;
  int q = lane >> 4, r = lane & 15;
  int wr = w >> 1, wc = w & 1;
  int r0 = wr * 64;
  int c0 = nb * 128 + wc * 64;

  floatx4 acc[4][4];
#pragma unroll
  for (int i = 0; i < 4; ++i)
#pragma unroll
    for (int j = 0; j < 4; ++j) acc[i][j] = (floatx4){0.f, 0.f, 0.f, 0.f};

  const float4* aptr[4];
#pragma unroll
  for (int i = 0; i < 4; ++i)
    aptr[i] = (const float4*)(embed + (size_t)tok[r0 + i * 16 + r] * HID) + q * 2;
  const uint4* bptr[4];
#pragma unroll
  for (int j = 0; j < 4; ++j)
    bptr[j] = (const uint4*)(wihI + ((size_t)d * 512 + c0 + j * 16 + r) * 64) + q;

#pragma unroll
  for (int kc = 0; kc < 4; ++kc) {
    half8_t af[4], bf[4];
#pragma unroll
    for (int i = 0; i < 4; ++i) {
      float4 x0 = aptr[i][kc * 8];
      float4 x1 = aptr[i][kc * 8 + 1];
      uint4 u;
      u.x = packh2(x0.x, x0.y); u.y = packh2(x0.z, x0.w);
      u.z = packh2(x1.x, x1.y); u.w = packh2(x1.z, x1.w);
      af[i] = __builtin_bit_cast(half8_t, u);
    }
#pragma unroll
    for (int j = 0; j < 4; ++j)
      bf[j] = __builtin_bit_cast(half8_t, bptr[j][kc * 4]);
#pragma unroll
    for (int i = 0; i < 4; ++i)
#pragma unroll
      for (int j = 0; j < 4; ++j)
        acc[i][j] = __builtin_amdgcn_mfma_f32_16x16x32_f16(af[i], bf[j], acc[i][j], 0, 0, 0);
  }

  size_t dstride = ALLT ? (size_t)65536 * 512 : (size_t)16384 * 512;
  int rowbase = (ALLT ? t : tl) * 128;
  __fp16* gat = ((__fp16*)gatex) + (size_t)d * dstride;
#pragma unroll
  for (int j = 0; j < 4; ++j) {
    int n = c0 + j * 16 + r;
    float bb = biasI[d * 512 + n];
#pragma unroll
    for (int i = 0; i < 4; ++i) {
      int rb = r0 + i * 16 + q * 4;
#pragma unroll
      for (int reg = 0; reg < 4; ++reg) {
        float v = acc[i][j][reg] + bb;
        gat[((size_t)(rowbase + rb + reg)) * 512 + n] = (__fp16)v;
      }
    }
  }
}

__global__ __launch_bounds__(256, 2) void gemmx_kernel(
    const int* __restrict__ sentence, const float* __restrict__ embed,
    const uint* __restrict__ wihI, const float* __restrict__ biasI,
    uint* __restrict__ gatex, int chunk)
{
  gemmx_body<false>(sentence, embed, wihI, biasI, gatex, chunk, blockIdx.x);
}

__global__ __launch_bounds__(256, 2) void gemmx_all_kernel(
    const int* __restrict__ sentence, const float* __restrict__ embed,
    const uint* __restrict__ wihI, const float* __restrict__ biasI,
    uint* __restrict__ gatex)
{
  gemmx_body<true>(sentence, embed, wihI, biasI, gatex,
                   blockIdx.x >> 10, blockIdx.x & 1023);
}

// ---------------------------------------------------------------------------
// LSTM step core (R15 structure, shared by both lstm kernels).
// GXSTRIDE_D: gatex d-stride in halfs (chunked: 8388608, all-t: 33554432).
// ---------------------------------------------------------------------------
struct LstmCtx {
  uint4 wreg[4][4];
  float sl, Ac, Bc;
  int kq, m;
};

__device__ __forceinline__ void lstm_step(
    LstmCtx& cx, __fp16 (*hist)[128], int row_r, int row_w, ushort gxh,
    float& c)
{
  const float L2E = 1.4426950408889634f;
  float a0 = 0.f, a1 = 0.f, a2 = 0.f, a3 = 0.f;
  float b0 = 0.f, b1 = 0.f, b2 = 0.f, b3 = 0.f;
  const uint4* z4 = (const uint4*)(&hist[row_r][cx.kq * 32]);
#pragma unroll
  for (int i = 0; i < 2; ++i) {
    uint4 z = z4[i];
    a0 = fdot2(z.x, cx.wreg[0][i].x, a0);
    a0 = fdot2(z.y, cx.wreg[0][i].y, a0);
    a0 = fdot2(z.z, cx.wreg[0][i].z, a0);
    a0 = fdot2(z.w, cx.wreg[0][i].w, a0);
    a1 = fdot2(z.x, cx.wreg[1][i].x, a1);
    a1 = fdot2(z.y, cx.wreg[1][i].y, a1);
    a1 = fdot2(z.z, cx.wreg[1][i].z, a1);
    a1 = fdot2(z.w, cx.wreg[1][i].w, a1);
    a2 = fdot2(z.x, cx.wreg[2][i].x, a2);
    a2 = fdot2(z.y, cx.wreg[2][i].y, a2);
    a2 = fdot2(z.z, cx.wreg[2][i].z, a2);
    a2 = fdot2(z.w, cx.wreg[2][i].w, a2);
    a3 = fdot2(z.x, cx.wreg[3][i].x, a3);
    a3 = fdot2(z.y, cx.wreg[3][i].y, a3);
    a3 = fdot2(z.z, cx.wreg[3][i].z, a3);
    a3 = fdot2(z.w, cx.wreg[3][i].w, a3);
  }
#pragma unroll
  for (int i = 2; i < 4; ++i) {
    uint4 z = z4[i];
    b0 = fdot2(z.x, cx.wreg[0][i].x, b0);
    b0 = fdot2(z.y, cx.wreg[0][i].y, b0);
    b0 = fdot2(z.z, cx.wreg[0][i].z, b0);
    b0 = fdot2(z.w, cx.wreg[0][i].w, b0);
    b1 = fdot2(z.x, cx.wreg[1][i].x, b1);
    b1 = fdot2(z.y, cx.wreg[1][i].y, b1);
    b1 = fdot2(z.z, cx.wreg[1][i].z, b1);
    b1 = fdot2(z.w, cx.wreg[1][i].w, b1);
    b2 = fdot2(z.x, cx.wreg[2][i].x, b2);
    b2 = fdot2(z.y, cx.wreg[2][i].y, b2);
    b2 = fdot2(z.z, cx.wreg[2][i].z, b2);
    b2 = fdot2(z.w, cx.wreg[2][i].w, b2);
    b3 = fdot2(z.x, cx.wreg[3][i].x, b3);
    b3 = fdot2(z.y, cx.wreg[3][i].y, b3);
    b3 = fdot2(z.z, cx.wreg[3][i].z, b3);
    b3 = fdot2(z.w, cx.wreg[3][i].w, b3);
  }
  a0 += b0; a1 += b1; a2 += b2; a3 += b3;
  a0 = quad_add(a0);
  a1 = quad_add(a1);
  a2 = quad_add(a2);
  a3 = quad_add(a3);
  float s01 = (cx.kq & 1) ? a1 : a0;
  float s23 = (cx.kq & 1) ? a3 : a2;
  float own = (cx.kq & 2) ? s23 : s01;
  own += (float)__builtin_bit_cast(__fp16, gxh);
  float e = fexp2(own * cx.sl);
  float r = frcp(1.f + e);
  float out = cx.Ac * r + cx.Bc;
  float ig = quad_bcast<0x00>(out);
  float fg = quad_bcast<0x55>(out);
  float gg = quad_bcast<0xAA>(out);
  float og = quad_bcast<0xFF>(out);
  c = fg * c + ig * gg;
  float e2 = fexp2(c * (2.f * L2E));
  float r2 = frcp(1.f + e2);
  float th = 1.f - 2.f * r2;
  float hv = og * th;

  if (cx.kq == 0) hist[row_w][cx.m] = (__fp16)hv;
  // Barrier WITHOUT vmcnt drain (prefetched gx loads stay in flight).
  __builtin_amdgcn_sched_barrier(0);
  asm volatile("s_waitcnt lgkmcnt(0)");
  __builtin_amdgcn_sched_barrier(0);
  __builtin_amdgcn_s_barrier();
}

__device__ __forceinline__ void lstm_init(LstmCtx& cx, const uint* whh,
                                          int d, int tid)
{
  const float L2E = 1.4426950408889634f;
  cx.kq = tid & 3;
  cx.m = tid >> 2;
  const bool isg = (cx.kq == 2);
  cx.sl = isg ? (2.f * L2E) : (-L2E);
  cx.Ac = isg ? -2.f : 1.f;
  cx.Bc = isg ? 1.f : 0.f;
  const uint4* wh4 = (const uint4*)whh + (size_t)d * 8192;
#pragma unroll
  for (int g = 0; g < 4; ++g) {
    const uint4* row = wh4 + ((size_t)(g * 128 + cx.m)) * 16 + cx.kq * 4;
#pragma unroll
    for (int i = 0; i < 4; ++i) cx.wreg[g][i] = row[i];
  }
}

// ---------------------------------------------------------------------------
// Chunked lstm (small-ws fallback; R15 verbatim behavior).
// ---------------------------------------------------------------------------
__global__ __attribute__((amdgpu_waves_per_eu(2, 2))) __launch_bounds__(512)
void lstm_kernel(
    const uint* __restrict__ gatex, const uint* __restrict__ whh,
    const float* __restrict__ h0, const float* __restrict__ c0,
    float* __restrict__ statec, uint* __restrict__ hh, int chunk)
{
  const int wg = blockIdx.x;
  const int d = wg >> 7, b = wg & 127;
  const int tid = threadIdx.x;

  __shared__ __align__(16) __fp16 hist[128][128];   // 32 KB
  LstmCtx cx;
  lstm_init(cx, whh, d, tid);

  float c = (chunk == 0) ? c0[(size_t)(d * 128 + b) * 128 + cx.m]
                         : statec[(size_t)(d * 128 + b) * 128 + cx.m];

  if (tid < 64) {
    uint* h127 = (uint*)&hist[127][0];
    if (chunk == 0) {
      float2 hv = ((const float2*)(h0 + (size_t)(d * 128 + b) * 128))[tid];
      h127[tid] = packh2(hv.x, hv.y);
    } else {
      int sprev = d ? (511 - (chunk * 128 - 1)) : (chunk * 128 - 1);
      h127[tid] = hh[((size_t)(d * 512 + sprev) * 128 + b) * 64 + tid];
    }
  }
  const ushort* gxp = (const ushort*)gatex + (size_t)d * 8388608 +
                      (size_t)b * 512 + 4 * cx.m + cx.kq;

  ushort g0 = gxp[0];
  ushort g1 = gxp[(size_t)1 * 65536];
  ushort g2 = gxp[(size_t)2 * 65536];
  ushort g3 = gxp[(size_t)3 * 65536];
  __syncthreads();

  for (int tl = 0; tl < 128; tl += 4) {
    int i0 = tl + 4 > 127 ? 127 : tl + 4;
    int i1 = tl + 5 > 127 ? 127 : tl + 5;
    int i2 = tl + 6 > 127 ? 127 : tl + 6;
    int i3 = tl + 7 > 127 ? 127 : tl + 7;
    ushort n0 = gxp[(size_t)i0 * 65536];
    ushort n1 = gxp[(size_t)i1 * 65536];
    ushort n2 = gxp[(size_t)i2 * 65536];
    ushort n3 = gxp[(size_t)i3 * 65536];
    lstm_step(cx, hist, (tl + 127) & 127, tl + 0, g0, c);
    lstm_step(cx, hist, (tl + 0) & 127, tl + 1, g1, c);
    lstm_step(cx, hist, (tl + 1) & 127, tl + 2, g2, c);
    lstm_step(cx, hist, (tl + 2) & 127, tl + 3, g3, c);
    g0 = n0; g1 = n1; g2 = n2; g3 = n3;
  }

  if (cx.kq == 0) statec[(size_t)(d * 128 + b) * 128 + cx.m] = c;

  int base = chunk * 128;
  for (int i = tid; i < 2048; i += 512) {
    int sl2 = i >> 4, q4 = i & 15;
    int s = d ? (511 - (base + sl2)) : (base + sl2);
    *(uint4*)(&hh[((size_t)(d * 512 + s) * 128 + b) * 64 + q4 * 4]) =
        *(const uint4*)((const uint*)&hist[sl2][0] + q4 * 4);
  }
}

// ---------------------------------------------------------------------------
// All-timestep lstm (big-ws path): one dispatch loops 512 steps. Saves 3
// launches + 3x (statec roundtrip, h127 reload, weight reload). hh dumped
// per 128-step chunk (hist ring is fully consumed at those boundaries).
// ---------------------------------------------------------------------------
__global__ __attribute__((amdgpu_waves_per_eu(2, 2))) __launch_bounds__(512)
void lstm_all_kernel(
    const uint* __restrict__ gatex, const uint* __restrict__ whh,
    const float* __restrict__ h0, const float* __restrict__ c0,
    uint* __restrict__ hh)
{
  const int wg = blockIdx.x;
  const int d = wg >> 7, b = wg & 127;
  const int tid = threadIdx.x;

  __shared__ __align__(16) __fp16 hist[128][128];   // 32 KB
  LstmCtx cx;
  lstm_init(cx, whh, d, tid);

  float c = c0[(size_t)(d * 128 + b) * 128 + cx.m];

  if (tid < 64) {
    uint* h127 = (uint*)&hist[127][0];
    float2 hv = ((const float2*)(h0 + (size_t)(d * 128 + b) * 128))[tid];
    h127[tid] = packh2(hv.x, hv.y);
  }
  const ushort* gxp = (const ushort*)gatex + (size_t)d * 33554432 +
                      (size_t)b * 512 + 4 * cx.m + cx.kq;

  ushort g0 = gxp[0];
  ushort g1 = gxp[(size_t)1 * 65536];
  ushort g2 = gxp[(size_t)2 * 65536];
  ushort g3 = gxp[(size_t)3 * 65536];
  __syncthreads();

  for (int tl = 0; tl < 512; tl += 4) {
    int i0 = tl + 4 > 511 ? 511 : tl + 4;
    int i1 = tl + 5 > 511 ? 511 : tl + 5;
    int i2 = tl + 6 > 511 ? 511 : tl + 6;
    int i3 = tl + 7 > 511 ? 511 : tl + 7;
    ushort n0 = gxp[(size_t)i0 * 65536];
    ushort n1 = gxp[(size_t)i1 * 65536];
    ushort n2 = gxp[(size_t)i2 * 65536];
    ushort n3 = gxp[(size_t)i3 * 65536];
    lstm_step(cx, hist, (tl + 127) & 127, (tl + 0) & 127, g0, c);
    lstm_step(cx, hist, (tl + 0) & 127, (tl + 1) & 127, g1, c);
    lstm_step(cx, hist, (tl + 1) & 127, (tl + 2) & 127, g2, c);
    lstm_step(cx, hist, (tl + 2) & 127, (tl + 3) & 127, g3, c);
    g0 = n0; g1 = n1; g2 = n2; g3 = n3;

    if (((tl + 3) & 127) == 127) {
      // hist rows 0..127 now hold h(ch*128 .. ch*128+127); dump to hh.
      int base = ((tl + 3) >> 7) * 128;
      for (int i = tid; i < 2048; i += 512) {
        int sl2 = i >> 4, q4 = i & 15;
        int s = d ? (511 - (base + sl2)) : (base + sl2);
        *(uint4*)(&hh[((size_t)(d * 512 + s) * 128 + b) * 64 + q4 * 4]) =
            *(const uint4*)((const uint*)&hist[sl2][0] + q4 * 4);
      }
      __syncthreads();
    }
  }
}

// ---------------------------------------------------------------------------
// Output projection — MFMA GEMM [65536x256]x[256x32], zero LDS.
// ---------------------------------------------------------------------------
__global__ __launch_bounds__(256) void outproj_kernel(
    const uint* __restrict__ hh, const uint* __restrict__ woutp,
    const float* __restrict__ bout, float* __restrict__ feats)
{
  int tid = threadIdx.x;
  int w = tid >> 6, lane = tid & 63;
  int q = lane >> 4, c = lane & 15;
  int row0 = blockIdx.x * 64 + w * 16;

  const uint4* wp4 = (const uint4*)woutp;
  uint4 bf0[8], bf1[8];
#pragma unroll
  for (int ks = 0; ks < 8; ++ks) {
    bf0[ks] = wp4[(size_t)c * 32 + ks * 4 + q];
    bf1[ks] = wp4[(size_t)(16 + c) * 32 + ks * 4 + q];
  }

  int rr = row0 + c;
  int br = rr >> 9, sr = rr & 511;
  const uint4* af4 = (const uint4*)(hh + ((size_t)(sr * BATCH + br)) * 64);
  const uint4* ab4 = (const uint4*)(hh + ((size_t)((SEQ + sr) * BATCH + br)) * 64);

  floatx4 acc0 = (floatx4){0.f, 0.f, 0.f, 0.f};
  floatx4 acc1 = (floatx4){0.f, 0.f, 0.f, 0.f};
#pragma unroll
  for (int ks = 0; ks < 8; ++ks) {
    uint4 a = (ks < 4) ? af4[ks * 4 + q] : ab4[(ks - 4) * 4 + q];
    half8_t af = __builtin_bit_cast(half8_t, a);
    acc0 = __builtin_amdgcn_mfma_f32_16x16x32_f16(
        af, __builtin_bit_cast(half8_t, bf0[ks]), acc0, 0, 0, 0);
    acc1 = __builtin_amdgcn_mfma_f32_16x16x32_f16(
        af, __builtin_bit_cast(half8_t, bf1[ks]), acc1, 0, 0, 0);
  }

  float bb0 = bout[c], bb1 = bout[16 + c];
#pragma unroll
  for (int reg = 0; reg < 4; ++reg) {
    int orow = row0 + q * 4 + reg;
    feats[(size_t)orow * 32 + c] = acc0[reg] + bb0;
    feats[(size_t)orow * 32 + 16 + c] = acc1[reg] + bb1;
  }
}

// ---------------------------------------------------------------------------
// CRF stage A (unchanged)
// ---------------------------------------------------------------------------
__global__ __launch_bounds__(64) void crf_seg_kernel(
    const float* __restrict__ feats, const float* __restrict__ trans,
    uint* __restrict__ segP, float* __restrict__ segL)
{
  const float L2E = 1.4426950408889634f;
  int blk = blockIdx.x;
  int b = blk >> 5, j = blk & 31;
  int tstart = 1 + 16 * j;
  int nsteps = (j == 31) ? 15 : 16;
  int lane = threadIdx.x;
  int c = lane & 15, q = lane >> 4;

  half8_t afr[2];
#pragma unroll
  for (int rt = 0; rt < 2; ++rt) {
    const float* trow = trans + (rt * 16 + c) * 32 + q * 8;
    float e[8];
#pragma unroll
    for (int i = 0; i < 8; ++i) e[i] = fexp2(trow[i] * L2E);
    uint4 u;
    u.x = packh2(e[0], e[1]); u.y = packh2(e[2], e[3]);
    u.z = packh2(e[4], e[5]); u.w = packh2(e[6], e[7]);
    afr[rt] = __builtin_bit_cast(half8_t, u);
  }
  half8_t bfr[2];
#pragma unroll
  for (int ct = 0; ct < 2; ++ct) {
    uint4 u;
    uint vals[8];
#pragma unroll
    for (int i = 0; i < 8; ++i)
      vals[i] = ((q * 8 + i) == (ct * 16 + c)) ? 0x3C00u : 0u;
    u.x = vals[0] | (vals[1] << 16);
    u.y = vals[2] | (vals[3] << 16);
    u.z = vals[4] | (vals[5] << 16);
    u.w = vals[6] | (vals[7] << 16);
    bfr[ct] = __builtin_bit_cast(half8_t, u);
  }

  __shared__ __fp16 P16[32 * 36];

  const float* fb = feats + ((size_t)b * SEQ + tstart) * NTAG;
  float Lacc = 0.f;
  float4 pre0 = *(const float4*)(fb + q * 4);
  float4 pre1 = *(const float4*)(fb + 16 + q * 4);

  for (int s = 0; s < nsteps; ++s) {
    float4 f0 = pre0, f1 = pre1;
    if (s + 1 < nsteps) {
      pre0 = *(const float4*)(fb + (s + 1) * 32 + q * 4);
      pre1 = *(const float4*)(fb + (s + 1) * 32 + 16 + q * 4);
    }
    floatx4 z4 = (floatx4){0.f, 0.f, 0.f, 0.f};
    floatx4 c00 = __builtin_amdgcn_mfma_f32_16x16x32_f16(afr[0], bfr[0], z4, 0, 0, 0);
    floatx4 c01 = __builtin_amdgcn_mfma_f32_16x16x32_f16(afr[0], bfr[1], z4, 0, 0, 0);
    floatx4 c10 = __builtin_amdgcn_mfma_f32_16x16x32_f16(afr[1], bfr[0], z4, 0, 0, 0);
    floatx4 c11 = __builtin_amdgcn_mfma_f32_16x16x32_f16(afr[1], bfr[1], z4, 0, 0, 0);
    float pf0[4], pf1[4];
    pf0[0] = fexp2(f0.x * L2E); pf0[1] = fexp2(f0.y * L2E);
    pf0[2] = fexp2(f0.z * L2E); pf0[3] = fexp2(f0.w * L2E);
    pf1[0] = fexp2(f1.x * L2E); pf1[1] = fexp2(f1.y * L2E);
    pf1[2] = fexp2(f1.z * L2E); pf1[3] = fexp2(f1.w * L2E);
    float v00[4], v01[4], v10[4], v11[4];
#pragma unroll
    for (int rg = 0; rg < 4; ++rg) {
      v00[rg] = c00[rg] * pf0[rg];
      v01[rg] = c01[rg] * pf0[rg];
      v10[rg] = c10[rg] * pf1[rg];
      v11[rg] = c11[rg] * pf1[rg];
    }
    float mx = 0.f;
#pragma unroll
    for (int rg = 0; rg < 4; ++rg)
      mx = fmaxf(mx, fmaxf(fmaxf(v00[rg], v01[rg]), fmaxf(v10[rg], v11[rg])));
    uint ub = (uint)__builtin_amdgcn_readfirstlane((int)__builtin_bit_cast(uint, mx));
    int e = (int)((ub >> 23) & 255u);
    Lacc += (float)(e - 127);
    float sc = __builtin_bit_cast(float, (uint)((254 - e) << 23));

    __syncthreads();
    {
      uint2 wv2;
      wv2.x = packh2(v00[0] * sc, v00[1] * sc);
      wv2.y = packh2(v00[2] * sc, v00[3] * sc);
      *(uint2*)(&P16[c * 36 + q * 4]) = wv2;
      wv2.x = packh2(v10[0] * sc, v10[1] * sc);
      wv2.y = packh2(v10[2] * sc, v10[3] * sc);
      *(uint2*)(&P16[c * 36 + 16 + q * 4]) = wv2;
      wv2.x = packh2(v01[0] * sc, v01[1] * sc);
      wv2.y = packh2(v01[2] * sc, v01[3] * sc);
      *(uint2*)(&P16[(16 + c) * 36 + q * 4]) = wv2;
      wv2.x = packh2(v11[0] * sc, v11[1] * sc);
      wv2.y = packh2(v11[2] * sc, v11[3] * sc);
      *(uint2*)(&P16[(16 + c) * 36 + 16 + q * 4]) = wv2;
    }
    __syncthreads();
    {
      uint2 lo0 = *(const uint2*)(&P16[c * 36 + q * 8]);
      uint2 hi0 = *(const uint2*)(&P16[c * 36 + q * 8 + 4]);
      uint4 u0; u0.x = lo0.x; u0.y = lo0.y; u0.z = hi0.x; u0.w = hi0.y;
      bfr[0] = __builtin_bit_cast(half8_t, u0);
      uint2 lo1 = *(const uint2*)(&P16[(16 + c) * 36 + q * 8]);
      uint2 hi1 = *(const uint2*)(&P16[(16 + c) * 36 + q * 8 + 4]);
      uint4 u1; u1.x = lo1.x; u1.y = lo1.y; u1.z = hi1.x; u1.w = hi1.y;
      bfr[1] = __builtin_bit_cast(half8_t, u1);
    }
  }
  __syncthreads();
  uint* gp = segP + (size_t)blk * 512;
  if (lane < 32) {
    int i = lane;
#pragma unroll
    for (int tp = 0; tp < 16; ++tp) {
      uint lo = (uint)__builtin_bit_cast(unsigned short, P16[(2 * tp) * 36 + i]);
      uint hi = (uint)__builtin_bit_cast(unsigned short, P16[(2 * tp + 1) * 36 + i]);
      gp[i * 16 + tp] = lo | (hi << 16);
    }
  }
  if (lane == 0) segL[blk] = Lacc;
}

// ---------------------------------------------------------------------------
// CRF stage B + numerator merged (same grid/block shape; independent work;
// saves one launch).
// ---------------------------------------------------------------------------
__global__ __launch_bounds__(64) void crf_comb_kernel(
    const int* __restrict__ tags, const float* __restrict__ feats,
    const float* __restrict__ trans, const uint* __restrict__ segP,
    const float* __restrict__ segL, float* __restrict__ num,
    float* __restrict__ den)
{
  const float L2E = 1.4426950408889634f, LN2 = 0.6931471805599453f;
  int b = blockIdx.x, l = threadIdx.x;

  // --- numerator (whole wave) ---
  {
    const int* tb = tags + b * SEQ;
    float acc = 0.f;
    for (int s = l; s < SEQ; s += 64) {
      int tg = tb[s];
      int pv = (s == 0) ? START_TAG : tb[s - 1];
      acc += trans[pv * NTAG + tg] + feats[((size_t)b * SEQ + s) * NTAG + tg];
    }
#pragma unroll
    for (int msk = 1; msk < 64; msk <<= 1) acc += __shfl_xor(acc, msk);
    if (l == 0) num[b] = acc + trans[tb[SEQ - 1] * NTAG + END_TAG];
  }

  // --- denominator combine ---
  int i = l & 31, hp = l >> 5;
  const float* fb = feats + (size_t)b * SEQ * NTAG;

  float sT = 0.f;
  for (int p = 0; p < 32; ++p) sT += fexp2(trans[i * 32 + p] * L2E);
  float v = (1.f + sT) * fexp2(fb[i] * L2E);
  float L = -10000.f * L2E;

  float vo = __shfl_xor(v, 1);
  uint pv = (i & 1) ? packh2(vo, v) : packh2(v, vo);

  const uint* gp0 = segP + (size_t)b * 32 * 512 + i * 16 + hp * 8;
  uint4 ra = *(const uint4*)(gp0);
  uint4 rb = *(const uint4*)(gp0 + 4);

  for (int seg = 0; seg < 32; ++seg) {
    uint4 ca = ra, cb = rb;
    if (seg + 1 < 32) {
      ra = *(const uint4*)(gp0 + (seg + 1) * 512);
      rb = *(const uint4*)(gp0 + (seg + 1) * 512 + 4);
    }
    float g0 = __shfl(__builtin_bit_cast(float, pv), hp * 16 + 0);
    float g1 = __shfl(__builtin_bit_cast(float, pv), hp * 16 + 2);
    float g2 = __shfl(__builtin_bit_cast(float, pv), hp * 16 + 4);
    float g3 = __shfl(__builtin_bit_cast(float, pv), hp * 16 + 6);
    float g4 = __shfl(__builtin_bit_cast(float, pv), hp * 16 + 8);
    float g5 = __shfl(__builtin_bit_cast(float, pv), hp * 16 + 10);
    float g6 = __shfl(__builtin_bit_cast(float, pv), hp * 16 + 12);
    float g7 = __shfl(__builtin_bit_cast(float, pv), hp * 16 + 14);
    float acc = 0.f;
    acc = fdot2(__builtin_bit_cast(uint, g0), ca.x, acc);
    acc = fdot2(__builtin_bit_cast(uint, g1), ca.y, acc);
    acc = fdot2(__builtin_bit_cast(uint, g2), ca.z, acc);
    acc = fdot2(__builtin_bit_cast(uint, g3), ca.w, acc);
    acc = fdot2(__builtin_bit_cast(uint, g4), cb.x, acc);
    acc = fdot2(__builtin_bit_cast(uint, g5), cb.y, acc);
    acc = fdot2(__builtin_bit_cast(uint, g6), cb.z, acc);
    acc = fdot2(__builtin_bit_cast(uint, g7), cb.w, acc);
    float sm = acc + __shfl_xor(acc, 32);
    uint ub = (uint)__builtin_amdgcn_readfirstlane((int)__builtin_bit_cast(uint, sm));
    int e = (int)((ub >> 23) & 255u);
    L += (float)(e - 127) + segL[b * 32 + seg];
    float sc = __builtin_bit_cast(float, (uint)((254 - e) << 23));
    v = sm * sc;
    float vo2 = __shfl_xor(v, 1);
    pv = (i & 1) ? packh2(vo2, v) : packh2(v, vo2);
  }
  float wv = v * fexp2(trans[i * 32 + END_TAG] * L2E);
#pragma unroll
  for (int msk = 1; msk <= 16; msk <<= 1) wv += __shfl_xor(wv, msk);
  if (l == 0) den[b] = (L + flog2(wv)) * LN2;
}

__global__ __launch_bounds__(128) void final_kernel(
    const float* __restrict__ num, const float* __restrict__ den,
    float* __restrict__ out)
{
  int tid = threadIdx.x;
  float v = num[tid] - den[tid];
#pragma unroll
  for (int msk = 1; msk < 64; msk <<= 1) v += __shfl_xor(v, msk);
  __shared__ float tmp[2];
  if ((tid & 63) == 0) tmp[tid >> 6] = v;
  __syncthreads();
  if (tid == 0) out[0] = (tmp[0] + tmp[1]) * (1.f / 128.f);
}

// ---------------------------------------------------------------------------
// Workspace layouts.
// Small (ws < 169MB): chunked gatex (33.5MB), 12 dispatches — proven 547us.
// Big  (ws >= 168820736): gatex holds all 512 steps (134MB at 34603008);
// feats/segP/segL overlay the dead gatex region after lstm. 7 dispatches.
// ---------------------------------------------------------------------------
extern "C" void kernel_launch(void* const* d_in, const int* in_sizes, int n_in,
                              void* d_out, int out_size, void* d_ws, size_t ws_size,
                              hipStream_t stream)
{
  const int* sentence = (const int*)d_in[0];
  const int* tags = (const int*)d_in[1];
  const float* embed = (const float*)d_in[2];
  const float* Wihf = (const float*)d_in[3];
  const float* Whhf = (const float*)d_in[4];
  const float* bihf = (const float*)d_in[5];
  const float* bhhf = (const float*)d_in[6];
  const float* Wihb = (const float*)d_in[7];
  const float* Whhb = (const float*)d_in[8];
  const float* bihb = (const float*)d_in[9];
  const float* bhhb = (const float*)d_in[10];
  const float* Wout = (const float*)d_in[11];
  const float* bout = (const float*)d_in[12];
  const float* trans = (const float*)d_in[13];
  const float* h0 = (const float*)d_in[14];
  const float* c0 = (const float*)d_in[15];
  float* out = (float*)d_out;

  char* ws = (char*)d_ws;
  uint* wihI = (uint*)(ws + 0);
  uint* whh = (uint*)(ws + 262144);
  uint* woutp = (uint*)(ws + 524288);
  float* biasI = (float*)(ws + 540672);
  float* numb = (float*)(ws + 544768);
  float* denb = (float*)(ws + 545280);
  float* statec = (float*)(ws + 545792);
  uint* hh = (uint*)(ws + 1048576);
  uint* gatex = (uint*)(ws + 34603008);
  float* feats = (float*)(ws + 34603008);
  uint* segP = (uint*)(ws + 42991616);
  float* segL = (float*)(ws + 51380224);

  hipLaunchKernelGGL(prep_kernel, dim3(532), dim3(256), 0, stream,
                     Wihf, Whhf, bihf, bhhf, Wihb, Whhb, bihb, bhhb, Wout,
                     wihI, whh, woutp, biasI);

  bool big = ws_size >= 168820736ull;
  if (big) {
    // gatexAll occupies [34603008, 168820736); feats/segP/segL overlay it
    // after lstm completes (gatex dead by then).
    hipLaunchKernelGGL(gemmx_all_kernel, dim3(4096), dim3(256), 0, stream,
                       sentence, embed, wihI, biasI, gatex);
    hipLaunchKernelGGL(lstm_all_kernel, dim3(256), dim3(512), 0, stream,
                       gatex, whh, h0, c0, hh);
  } else {
    for (int c = 0; c < 4; ++c) {
      hipLaunchKernelGGL(gemmx_kernel, dim3(1024), dim3(256), 0, stream,
                         sentence, embed, wihI, biasI, gatex, c);
      hipLaunchKernelGGL(lstm_kernel, dim3(256), dim3(512), 0, stream,
                         gatex, whh, h0, c0, statec, hh, c);
    }
  }

  hipLaunchKernelGGL(outproj_kernel, dim3(1024), dim3(256), 0, stream,
                     hh, woutp, bout, feats);
  hipLaunchKernelGGL(crf_seg_kernel, dim3(4096), dim3(64), 0, stream,
                     feats, trans, segP, segL);
  hipLaunchKernelGGL(crf_comb_kernel, dim3(128), dim3(64), 0, stream,
                     tags, feats, trans, segP, segL, numb, denb);
  hipLaunchKernelGGL(final_kernel, dim3(1), dim3(128), 0, stream,
                     numb, denb, out);
}

// Round 14
// 503.436 us; speedup vs baseline: 1.5359x; 1.0297x over previous
//
#include <hip/hip_runtime.h>

typedef unsigned int uint;
typedef unsigned short ushort;
typedef __fp16 half2_t __attribute__((ext_vector_type(2)));
typedef __fp16 half8_t __attribute__((ext_vector_type(8)));
typedef float floatx4 __attribute__((ext_vector_type(4)));

#define SEQ 512
#define BATCH 128
#define HID 128
#define NTAG 32
#define START_TAG 30
#define END_TAG 31

__device__ __forceinline__ float fdot2(uint a, uint b, float c) {
  return __builtin_amdgcn_fdot2(__builtin_bit_cast(half2_t, a),
                                __builtin_bit_cast(half2_t, b), c, false);
}
__device__ __forceinline__ uint packh2(float a, float b) {
  half2_t h = __builtin_amdgcn_cvt_pkrtz(a, b);
  return __builtin_bit_cast(uint, h);
}
__device__ __forceinline__ float frcp(float x) { return __builtin_amdgcn_rcpf(x); }
__device__ __forceinline__ float fexp2(float x) { return __builtin_amdgcn_exp2f(x); }
__device__ __forceinline__ float flog2(float x) { return __builtin_amdgcn_logf(x); }

// Quad butterfly sum via DPP quad_perm (VALU pipe, no LDS).
__device__ __forceinline__ float quad_add(float x) {
  int a = __builtin_bit_cast(int, x);
  int b = __builtin_amdgcn_update_dpp(0, a, 0xB1, 0xF, 0xF, true);
  float y = x + __builtin_bit_cast(float, b);
  int c2 = __builtin_bit_cast(int, y);
  int d2 = __builtin_amdgcn_update_dpp(0, c2, 0x4E, 0xF, 0xF, true);
  return y + __builtin_bit_cast(float, d2);
}
template <int CTRL>
__device__ __forceinline__ float quad_bcast(float x) {
  int a = __builtin_bit_cast(int, x);
  int b = __builtin_amdgcn_update_dpp(0, a, CTRL, 0xF, 0xF, true);
  return __builtin_bit_cast(float, b);
}

// ---------------------------------------------------------------------------
// prep — R22: adds sentence transpose (sentT[s][b]) so gemmx's token load
// becomes one coalesced 512B read instead of 128 stride-2KB loads.
// ---------------------------------------------------------------------------
__global__ __launch_bounds__(256) void prep_kernel(
    const float* __restrict__ Wihf, const float* __restrict__ Whhf,
    const float* __restrict__ bihf, const float* __restrict__ bhhf,
    const float* __restrict__ Wihb, const float* __restrict__ Whhb,
    const float* __restrict__ bihb, const float* __restrict__ bhhb,
    const float* __restrict__ Wout, const int* __restrict__ sentence,
    uint* __restrict__ wihI, uint* __restrict__ whh,
    uint* __restrict__ woutp, float* __restrict__ biasI,
    int* __restrict__ sentT)
{
  int idx = blockIdx.x * 256 + threadIdx.x;
  if (idx < 65536) {
    int d = idx >> 15, rem = idx & 32767;
    int n = rem >> 6, dw = rem & 63;
    int m = n >> 2, q = n & 3;
    int g = q * 128 + m;
    const float* W = d ? Wihb : Wihf;
    wihI[idx] = packh2(W[g * 128 + 2 * dw], W[g * 128 + 2 * dw + 1]);
  }
  int i2 = idx - 65536;
  if (i2 >= 0 && i2 < 65536) {
    int d = i2 >> 15, rem = i2 & 32767;
    int g = rem >> 6, dw = rem & 63;
    const float* W = d ? Whhb : Whhf;
    whh[i2] = packh2(W[g * 128 + 2 * dw], W[g * 128 + 2 * dw + 1]);
  }
  int i3 = idx - 131072;
  if (i3 >= 0 && i3 < 4096) {
    int k = i3 >> 7, dw = i3 & 127;
    float a, b2;
    if (dw < 64) { a = Wout[k * 256 + 2 * dw]; b2 = Wout[k * 256 + 2 * dw + 1]; }
    else { int j = dw - 64; a = Wout[k * 256 + 128 + 2 * j]; b2 = Wout[k * 256 + 128 + 2 * j + 1]; }
    woutp[i3] = packh2(a, b2);
  }
  int i4 = idx - 135168;
  if (i4 >= 0 && i4 < 1024) {
    int d = i4 >> 9, n = i4 & 511;
    int g = (n & 3) * 128 + (n >> 2);
    biasI[i4] = d ? (bihb[g] + bhhb[g]) : (bihf[g] + bhhf[g]);
  }
  int i5 = idx - 136192;
  if (i5 >= 0 && i5 < 65536) {
    int b = i5 & 127, s = i5 >> 7;
    sentT[i5] = sentence[b * SEQ + s];
  }
}

// ---------------------------------------------------------------------------
// gemmx core — R22: LDS-staged coalesced output.
// Old: 64 scalar fp16 stores/thread -> 4x 32B segments per wave-store at
// 1KB stride (worst-case write coalescing on 134MB of gatex). New: stage
// the block's 128x128 fp16 tile in LDS (stride 136 halfs: 16B-aligned,
// bank-safe), fold bias there, then write out as 16B/lane uint4 stores
// (16 lanes = 256B contiguous bursts).
// ---------------------------------------------------------------------------
template <bool ALLT>
__device__ __forceinline__ void gemmx_body(
    const int* __restrict__ sentT, const float* __restrict__ embed,
    const uint* __restrict__ wihI, const float* __restrict__ biasI,
    uint* __restrict__ gatex, int chunk, int blk)
{
  int tl = blk & 127, nb = (blk >> 7) & 3, d = blk >> 9;
  int t = chunk * 128 + tl;
  int s = d ? (511 - t) : t;
  __shared__ int tok[128];
  __shared__ __align__(16) __fp16 tile[128][136];   // ~34.8 KB
  int tid = threadIdx.x;
  if (tid < 128) tok[tid] = sentT[s * 128 + tid];
  __syncthreads();

  int w = tid >> 6, lane = tid & 63;
  int q = lane >> 4, r = lane & 15;
  int wr = w >> 1, wc = w & 1;
  int r0 = wr * 64;
  int cl0 = wc * 64;               // local col base within block's 128 cols
  int c0 = nb * 128 + cl0;         // global col base

  floatx4 acc[4][4];
#pragma unroll
  for (int i = 0; i < 4; ++i)
#pragma unroll
    for (int j = 0; j < 4; ++j) acc[i][j] = (floatx4){0.f, 0.f, 0.f, 0.f};

  const float4* aptr[4];
#pragma unroll
  for (int i = 0; i < 4; ++i)
    aptr[i] = (const float4*)(embed + (size_t)tok[r0 + i * 16 + r] * HID) + q * 2;
  const uint4* bptr[4];
#pragma unroll
  for (int j = 0; j < 4; ++j)
    bptr[j] = (const uint4*)(wihI + ((size_t)d * 512 + c0 + j * 16 + r) * 64) + q;

#pragma unroll
  for (int kc = 0; kc < 4; ++kc) {
    half8_t af[4], bf[4];
#pragma unroll
    for (int i = 0; i < 4; ++i) {
      float4 x0 = aptr[i][kc * 8];
      float4 x1 = aptr[i][kc * 8 + 1];
      uint4 u;
      u.x = packh2(x0.x, x0.y); u.y = packh2(x0.z, x0.w);
      u.z = packh2(x1.x, x1.y); u.w = packh2(x1.z, x1.w);
      af[i] = __builtin_bit_cast(half8_t, u);
    }
#pragma unroll
    for (int j = 0; j < 4; ++j)
      bf[j] = __builtin_bit_cast(half8_t, bptr[j][kc * 4]);
#pragma unroll
    for (int i = 0; i < 4; ++i)
#pragma unroll
      for (int j = 0; j < 4; ++j)
        acc[i][j] = __builtin_amdgcn_mfma_f32_16x16x32_f16(af[i], bf[j], acc[i][j], 0, 0, 0);
  }

  // Stage C (+bias) into LDS.
#pragma unroll
  for (int j = 0; j < 4; ++j) {
    int cl = cl0 + j * 16 + r;
    float bb = biasI[d * 512 + nb * 128 + cl];
#pragma unroll
    for (int i = 0; i < 4; ++i) {
      int rb = r0 + i * 16 + q * 4;
#pragma unroll
      for (int reg = 0; reg < 4; ++reg)
        tile[rb + reg][cl] = (__fp16)(acc[i][j][reg] + bb);
    }
  }
  __syncthreads();

  // Coalesced write-out: 8 passes x (16 rows x 16 uint4); 16 lanes = 256B.
  size_t dstride = ALLT ? (size_t)65536 * 512 : (size_t)16384 * 512;
  int rowbase = (ALLT ? t : tl) * 128;
  __fp16* gat = ((__fp16*)gatex) + (size_t)d * dstride;
  int prow = tid >> 4, pseg = tid & 15;
#pragma unroll
  for (int pass = 0; pass < 8; ++pass) {
    int row = pass * 16 + prow;
    uint4 v = *(const uint4*)(&tile[row][pseg * 8]);
    *(uint4*)(gat + ((size_t)(rowbase + row)) * 512 + nb * 128 + pseg * 8) = v;
  }
}

__global__ __launch_bounds__(256, 2) void gemmx_kernel(
    const int* __restrict__ sentT, const float* __restrict__ embed,
    const uint* __restrict__ wihI, const float* __restrict__ biasI,
    uint* __restrict__ gatex, int chunk)
{
  gemmx_body<false>(sentT, embed, wihI, biasI, gatex, chunk, blockIdx.x);
}

__global__ __launch_bounds__(256, 2) void gemmx_all_kernel(
    const int* __restrict__ sentT, const float* __restrict__ embed,
    const uint* __restrict__ wihI, const float* __restrict__ biasI,
    uint* __restrict__ gatex)
{
  gemmx_body<true>(sentT, embed, wihI, biasI, gatex,
                   blockIdx.x >> 10, blockIdx.x & 1023);
}

// ---------------------------------------------------------------------------
// LSTM step core (R15 structure; verified).
// ---------------------------------------------------------------------------
struct LstmCtx {
  uint4 wreg[4][4];
  float sl, Ac, Bc;
  int kq, m;
};

__device__ __forceinline__ void lstm_step(
    LstmCtx& cx, __fp16 (*hist)[128], int row_r, int row_w, ushort gxh,
    float& c)
{
  const float L2E = 1.4426950408889634f;
  float a0 = 0.f, a1 = 0.f, a2 = 0.f, a3 = 0.f;
  float b0 = 0.f, b1 = 0.f, b2 = 0.f, b3 = 0.f;
  const uint4* z4 = (const uint4*)(&hist[row_r][cx.kq * 32]);
#pragma unroll
  for (int i = 0; i < 2; ++i) {
    uint4 z = z4[i];
    a0 = fdot2(z.x, cx.wreg[0][i].x, a0);
    a0 = fdot2(z.y, cx.wreg[0][i].y, a0);
    a0 = fdot2(z.z, cx.wreg[0][i].z, a0);
    a0 = fdot2(z.w, cx.wreg[0][i].w, a0);
    a1 = fdot2(z.x, cx.wreg[1][i].x, a1);
    a1 = fdot2(z.y, cx.wreg[1][i].y, a1);
    a1 = fdot2(z.z, cx.wreg[1][i].z, a1);
    a1 = fdot2(z.w, cx.wreg[1][i].w, a1);
    a2 = fdot2(z.x, cx.wreg[2][i].x, a2);
    a2 = fdot2(z.y, cx.wreg[2][i].y, a2);
    a2 = fdot2(z.z, cx.wreg[2][i].z, a2);
    a2 = fdot2(z.w, cx.wreg[2][i].w, a2);
    a3 = fdot2(z.x, cx.wreg[3][i].x, a3);
    a3 = fdot2(z.y, cx.wreg[3][i].y, a3);
    a3 = fdot2(z.z, cx.wreg[3][i].z, a3);
    a3 = fdot2(z.w, cx.wreg[3][i].w, a3);
  }
#pragma unroll
  for (int i = 2; i < 4; ++i) {
    uint4 z = z4[i];
    b0 = fdot2(z.x, cx.wreg[0][i].x, b0);
    b0 = fdot2(z.y, cx.wreg[0][i].y, b0);
    b0 = fdot2(z.z, cx.wreg[0][i].z, b0);
    b0 = fdot2(z.w, cx.wreg[0][i].w, b0);
    b1 = fdot2(z.x, cx.wreg[1][i].x, b1);
    b1 = fdot2(z.y, cx.wreg[1][i].y, b1);
    b1 = fdot2(z.z, cx.wreg[1][i].z, b1);
    b1 = fdot2(z.w, cx.wreg[1][i].w, b1);
    b2 = fdot2(z.x, cx.wreg[2][i].x, b2);
    b2 = fdot2(z.y, cx.wreg[2][i].y, b2);
    b2 = fdot2(z.z, cx.wreg[2][i].z, b2);
    b2 = fdot2(z.w, cx.wreg[2][i].w, b2);
    b3 = fdot2(z.x, cx.wreg[3][i].x, b3);
    b3 = fdot2(z.y, cx.wreg[3][i].y, b3);
    b3 = fdot2(z.z, cx.wreg[3][i].z, b3);
    b3 = fdot2(z.w, cx.wreg[3][i].w, b3);
  }
  a0 += b0; a1 += b1; a2 += b2; a3 += b3;
  a0 = quad_add(a0);
  a1 = quad_add(a1);
  a2 = quad_add(a2);
  a3 = quad_add(a3);
  float s01 = (cx.kq & 1) ? a1 : a0;
  float s23 = (cx.kq & 1) ? a3 : a2;
  float own = (cx.kq & 2) ? s23 : s01;
  own += (float)__builtin_bit_cast(__fp16, gxh);
  float e = fexp2(own * cx.sl);
  float r = frcp(1.f + e);
  float out = cx.Ac * r + cx.Bc;
  float ig = quad_bcast<0x00>(out);
  float fg = quad_bcast<0x55>(out);
  float gg = quad_bcast<0xAA>(out);
  float og = quad_bcast<0xFF>(out);
  c = fg * c + ig * gg;
  float e2 = fexp2(c * (2.f * L2E));
  float r2 = frcp(1.f + e2);
  float th = 1.f - 2.f * r2;
  float hv = og * th;

  if (cx.kq == 0) hist[row_w][cx.m] = (__fp16)hv;
  __builtin_amdgcn_sched_barrier(0);
  asm volatile("s_waitcnt lgkmcnt(0)");
  __builtin_amdgcn_sched_barrier(0);
  __builtin_amdgcn_s_barrier();
}

__device__ __forceinline__ void lstm_init(LstmCtx& cx, const uint* whh,
                                          int d, int tid)
{
  const float L2E = 1.4426950408889634f;
  cx.kq = tid & 3;
  cx.m = tid >> 2;
  const bool isg = (cx.kq == 2);
  cx.sl = isg ? (2.f * L2E) : (-L2E);
  cx.Ac = isg ? -2.f : 1.f;
  cx.Bc = isg ? 1.f : 0.f;
  const uint4* wh4 = (const uint4*)whh + (size_t)d * 8192;
#pragma unroll
  for (int g = 0; g < 4; ++g) {
    const uint4* row = wh4 + ((size_t)(g * 128 + cx.m)) * 16 + cx.kq * 4;
#pragma unroll
    for (int i = 0; i < 4; ++i) cx.wreg[g][i] = row[i];
  }
}

// ---------------------------------------------------------------------------
// Chunked lstm (small-ws fallback).
// ---------------------------------------------------------------------------
__global__ __attribute__((amdgpu_waves_per_eu(2, 2))) __launch_bounds__(512)
void lstm_kernel(
    const uint* __restrict__ gatex, const uint* __restrict__ whh,
    const float* __restrict__ h0, const float* __restrict__ c0,
    float* __restrict__ statec, uint* __restrict__ hh, int chunk)
{
  const int wg = blockIdx.x;
  const int d = wg >> 7, b = wg & 127;
  const int tid = threadIdx.x;

  __shared__ __align__(16) __fp16 hist[128][128];   // 32 KB
  LstmCtx cx;
  lstm_init(cx, whh, d, tid);

  float c = (chunk == 0) ? c0[(size_t)(d * 128 + b) * 128 + cx.m]
                         : statec[(size_t)(d * 128 + b) * 128 + cx.m];

  if (tid < 64) {
    uint* h127 = (uint*)&hist[127][0];
    if (chunk == 0) {
      float2 hv = ((const float2*)(h0 + (size_t)(d * 128 + b) * 128))[tid];
      h127[tid] = packh2(hv.x, hv.y);
    } else {
      int sprev = d ? (511 - (chunk * 128 - 1)) : (chunk * 128 - 1);
      h127[tid] = hh[((size_t)(d * 512 + sprev) * 128 + b) * 64 + tid];
    }
  }
  const ushort* gxp = (const ushort*)gatex + (size_t)d * 8388608 +
                      (size_t)b * 512 + 4 * cx.m + cx.kq;

  ushort g0 = gxp[0];
  ushort g1 = gxp[(size_t)1 * 65536];
  ushort g2 = gxp[(size_t)2 * 65536];
  ushort g3 = gxp[(size_t)3 * 65536];
  __syncthreads();

  for (int tl = 0; tl < 128; tl += 4) {
    int i0 = tl + 4 > 127 ? 127 : tl + 4;
    int i1 = tl + 5 > 127 ? 127 : tl + 5;
    int i2 = tl + 6 > 127 ? 127 : tl + 6;
    int i3 = tl + 7 > 127 ? 127 : tl + 7;
    ushort n0 = gxp[(size_t)i0 * 65536];
    ushort n1 = gxp[(size_t)i1 * 65536];
    ushort n2 = gxp[(size_t)i2 * 65536];
    ushort n3 = gxp[(size_t)i3 * 65536];
    lstm_step(cx, hist, (tl + 127) & 127, tl + 0, g0, c);
    lstm_step(cx, hist, (tl + 0) & 127, tl + 1, g1, c);
    lstm_step(cx, hist, (tl + 1) & 127, tl + 2, g2, c);
    lstm_step(cx, hist, (tl + 2) & 127, tl + 3, g3, c);
    g0 = n0; g1 = n1; g2 = n2; g3 = n3;
  }

  if (cx.kq == 0) statec[(size_t)(d * 128 + b) * 128 + cx.m] = c;

  int base = chunk * 128;
  for (int i = tid; i < 2048; i += 512) {
    int sl2 = i >> 4, q4 = i & 15;
    int s = d ? (511 - (base + sl2)) : (base + sl2);
    *(uint4*)(&hh[((size_t)(d * 512 + s) * 128 + b) * 64 + q4 * 4]) =
        *(const uint4*)((const uint*)&hist[sl2][0] + q4 * 4);
  }
}

// ---------------------------------------------------------------------------
// All-timestep lstm (big-ws path; verified R13 at 296us).
// ---------------------------------------------------------------------------
__global__ __attribute__((amdgpu_waves_per_eu(2, 2))) __launch_bounds__(512)
void lstm_all_kernel(
    const uint* __restrict__ gatex, const uint* __restrict__ whh,
    const float* __restrict__ h0, const float* __restrict__ c0,
    uint* __restrict__ hh)
{
  const int wg = blockIdx.x;
  const int d = wg >> 7, b = wg & 127;
  const int tid = threadIdx.x;

  __shared__ __align__(16) __fp16 hist[128][128];   // 32 KB
  LstmCtx cx;
  lstm_init(cx, whh, d, tid);

  float c = c0[(size_t)(d * 128 + b) * 128 + cx.m];

  if (tid < 64) {
    uint* h127 = (uint*)&hist[127][0];
    float2 hv = ((const float2*)(h0 + (size_t)(d * 128 + b) * 128))[tid];
    h127[tid] = packh2(hv.x, hv.y);
  }
  const ushort* gxp = (const ushort*)gatex + (size_t)d * 33554432 +
                      (size_t)b * 512 + 4 * cx.m + cx.kq;

  ushort g0 = gxp[0];
  ushort g1 = gxp[(size_t)1 * 65536];
  ushort g2 = gxp[(size_t)2 * 65536];
  ushort g3 = gxp[(size_t)3 * 65536];
  __syncthreads();

  for (int tl = 0; tl < 512; tl += 4) {
    int i0 = tl + 4 > 511 ? 511 : tl + 4;
    int i1 = tl + 5 > 511 ? 511 : tl + 5;
    int i2 = tl + 6 > 511 ? 511 : tl + 6;
    int i3 = tl + 7 > 511 ? 511 : tl + 7;
    ushort n0 = gxp[(size_t)i0 * 65536];
    ushort n1 = gxp[(size_t)i1 * 65536];
    ushort n2 = gxp[(size_t)i2 * 65536];
    ushort n3 = gxp[(size_t)i3 * 65536];
    lstm_step(cx, hist, (tl + 127) & 127, (tl + 0) & 127, g0, c);
    lstm_step(cx, hist, (tl + 0) & 127, (tl + 1) & 127, g1, c);
    lstm_step(cx, hist, (tl + 1) & 127, (tl + 2) & 127, g2, c);
    lstm_step(cx, hist, (tl + 2) & 127, (tl + 3) & 127, g3, c);
    g0 = n0; g1 = n1; g2 = n2; g3 = n3;

    if (((tl + 3) & 127) == 127) {
      int base = ((tl + 3) >> 7) * 128;
      for (int i = tid; i < 2048; i += 512) {
        int sl2 = i >> 4, q4 = i & 15;
        int s = d ? (511 - (base + sl2)) : (base + sl2);
        *(uint4*)(&hh[((size_t)(d * 512 + s) * 128 + b) * 64 + q4 * 4]) =
            *(const uint4*)((const uint*)&hist[sl2][0] + q4 * 4);
      }
      __syncthreads();
    }
  }
}

// ---------------------------------------------------------------------------
// Output projection — MFMA GEMM [65536x256]x[256x32], zero LDS (verified).
// ---------------------------------------------------------------------------
__global__ __launch_bounds__(256) void outproj_kernel(
    const uint* __restrict__ hh, const uint* __restrict__ woutp,
    const float* __restrict__ bout, float* __restrict__ feats)
{
  int tid = threadIdx.x;
  int w = tid >> 6, lane = tid & 63;
  int q = lane >> 4, c = lane & 15;
  int row0 = blockIdx.x * 64 + w * 16;

  const uint4* wp4 = (const uint4*)woutp;
  uint4 bf0[8], bf1[8];
#pragma unroll
  for (int ks = 0; ks < 8; ++ks) {
    bf0[ks] = wp4[(size_t)c * 32 + ks * 4 + q];
    bf1[ks] = wp4[(size_t)(16 + c) * 32 + ks * 4 + q];
  }

  int rr = row0 + c;
  int br = rr >> 9, sr = rr & 511;
  const uint4* af4 = (const uint4*)(hh + ((size_t)(sr * BATCH + br)) * 64);
  const uint4* ab4 = (const uint4*)(hh + ((size_t)((SEQ + sr) * BATCH + br)) * 64);

  floatx4 acc0 = (floatx4){0.f, 0.f, 0.f, 0.f};
  floatx4 acc1 = (floatx4){0.f, 0.f, 0.f, 0.f};
#pragma unroll
  for (int ks = 0; ks < 8; ++ks) {
    uint4 a = (ks < 4) ? af4[ks * 4 + q] : ab4[(ks - 4) * 4 + q];
    half8_t af = __builtin_bit_cast(half8_t, a);
    acc0 = __builtin_amdgcn_mfma_f32_16x16x32_f16(
        af, __builtin_bit_cast(half8_t, bf0[ks]), acc0, 0, 0, 0);
    acc1 = __builtin_amdgcn_mfma_f32_16x16x32_f16(
        af, __builtin_bit_cast(half8_t, bf1[ks]), acc1, 0, 0, 0);
  }

  float bb0 = bout[c], bb1 = bout[16 + c];
#pragma unroll
  for (int reg = 0; reg < 4; ++reg) {
    int orow = row0 + q * 4 + reg;
    feats[(size_t)orow * 32 + c] = acc0[reg] + bb0;
    feats[(size_t)orow * 32 + 16 + c] = acc1[reg] + bb1;
  }
}

// ---------------------------------------------------------------------------
// CRF stage A (unchanged, verified)
// ---------------------------------------------------------------------------
__global__ __launch_bounds__(64) void crf_seg_kernel(
    const float* __restrict__ feats, const float* __restrict__ trans,
    uint* __restrict__ segP, float* __restrict__ segL)
{
  const float L2E = 1.4426950408889634f;
  int blk = blockIdx.x;
  int b = blk >> 5, j = blk & 31;
  int tstart = 1 + 16 * j;
  int nsteps = (j == 31) ? 15 : 16;
  int lane = threadIdx.x;
  int c = lane & 15, q = lane >> 4;

  half8_t afr[2];
#pragma unroll
  for (int rt = 0; rt < 2; ++rt) {
    const float* trow = trans + (rt * 16 + c) * 32 + q * 8;
    float e[8];
#pragma unroll
    for (int i = 0; i < 8; ++i) e[i] = fexp2(trow[i] * L2E);
    uint4 u;
    u.x = packh2(e[0], e[1]); u.y = packh2(e[2], e[3]);
    u.z = packh2(e[4], e[5]); u.w = packh2(e[6], e[7]);
    afr[rt] = __builtin_bit_cast(half8_t, u);
  }
  half8_t bfr[2];
#pragma unroll
  for (int ct = 0; ct < 2; ++ct) {
    uint4 u;
    uint vals[8];
#pragma unroll
    for (int i = 0; i < 8; ++i)
      vals[i] = ((q * 8 + i) == (ct * 16 + c)) ? 0x3C00u : 0u;
    u.x = vals[0] | (vals[1] << 16);
    u.y = vals[2] | (vals[3] << 16);
    u.z = vals[4] | (vals[5] << 16);
    u.w = vals[6] | (vals[7] << 16);
    bfr[ct] = __builtin_bit_cast(half8_t, u);
  }

  __shared__ __fp16 P16[32 * 36];

  const float* fb = feats + ((size_t)b * SEQ + tstart) * NTAG;
  float Lacc = 0.f;
  float4 pre0 = *(const float4*)(fb + q * 4);
  float4 pre1 = *(const float4*)(fb + 16 + q * 4);

  for (int s = 0; s < nsteps; ++s) {
    float4 f0 = pre0, f1 = pre1;
    if (s + 1 < nsteps) {
      pre0 = *(const float4*)(fb + (s + 1) * 32 + q * 4);
      pre1 = *(const float4*)(fb + (s + 1) * 32 + 16 + q * 4);
    }
    floatx4 z4 = (floatx4){0.f, 0.f, 0.f, 0.f};
    floatx4 c00 = __builtin_amdgcn_mfma_f32_16x16x32_f16(afr[0], bfr[0], z4, 0, 0, 0);
    floatx4 c01 = __builtin_amdgcn_mfma_f32_16x16x32_f16(afr[0], bfr[1], z4, 0, 0, 0);
    floatx4 c10 = __builtin_amdgcn_mfma_f32_16x16x32_f16(afr[1], bfr[0], z4, 0, 0, 0);
    floatx4 c11 = __builtin_amdgcn_mfma_f32_16x16x32_f16(afr[1], bfr[1], z4, 0, 0, 0);
    float pf0[4], pf1[4];
    pf0[0] = fexp2(f0.x * L2E); pf0[1] = fexp2(f0.y * L2E);
    pf0[2] = fexp2(f0.z * L2E); pf0[3] = fexp2(f0.w * L2E);
    pf1[0] = fexp2(f1.x * L2E); pf1[1] = fexp2(f1.y * L2E);
    pf1[2] = fexp2(f1.z * L2E); pf1[3] = fexp2(f1.w * L2E);
    float v00[4], v01[4], v10[4], v11[4];
#pragma unroll
    for (int rg = 0; rg < 4; ++rg) {
      v00[rg] = c00[rg] * pf0[rg];
      v01[rg] = c01[rg] * pf0[rg];
      v10[rg] = c10[rg] * pf1[rg];
      v11[rg] = c11[rg] * pf1[rg];
    }
    float mx = 0.f;
#pragma unroll
    for (int rg = 0; rg < 4; ++rg)
      mx = fmaxf(mx, fmaxf(fmaxf(v00[rg], v01[rg]), fmaxf(v10[rg], v11[rg])));
    uint ub = (uint)__builtin_amdgcn_readfirstlane((int)__builtin_bit_cast(uint, mx));
    int e = (int)((ub >> 23) & 255u);
    Lacc += (float)(e - 127);
    float sc = __builtin_bit_cast(float, (uint)((254 - e) << 23));

    __syncthreads();
    {
      uint2 wv2;
      wv2.x = packh2(v00[0] * sc, v00[1] * sc);
      wv2.y = packh2(v00[2] * sc, v00[3] * sc);
      *(uint2*)(&P16[c * 36 + q * 4]) = wv2;
      wv2.x = packh2(v10[0] * sc, v10[1] * sc);
      wv2.y = packh2(v10[2] * sc, v10[3] * sc);
      *(uint2*)(&P16[c * 36 + 16 + q * 4]) = wv2;
      wv2.x = packh2(v01[0] * sc, v01[1] * sc);
      wv2.y = packh2(v01[2] * sc, v01[3] * sc);
      *(uint2*)(&P16[(16 + c) * 36 + q * 4]) = wv2;
      wv2.x = packh2(v11[0] * sc, v11[1] * sc);
      wv2.y = packh2(v11[2] * sc, v11[3] * sc);
      *(uint2*)(&P16[(16 + c) * 36 + 16 + q * 4]) = wv2;
    }
    __syncthreads();
    {
      uint2 lo0 = *(const uint2*)(&P16[c * 36 + q * 8]);
      uint2 hi0 = *(const uint2*)(&P16[c * 36 + q * 8 + 4]);
      uint4 u0; u0.x = lo0.x; u0.y = lo0.y; u0.z = hi0.x; u0.w = hi0.y;
      bfr[0] = __builtin_bit_cast(half8_t, u0);
      uint2 lo1 = *(const uint2*)(&P16[(16 + c) * 36 + q * 8]);
      uint2 hi1 = *(const uint2*)(&P16[(16 + c) * 36 + q * 8 + 4]);
      uint4 u1; u1.x = lo1.x; u1.y = lo1.y; u1.z = hi1.x; u1.w = hi1.y;
      bfr[1] = __builtin_bit_cast(half8_t, u1);
    }
  }
  __syncthreads();
  uint* gp = segP + (size_t)blk * 512;
  if (lane < 32) {
    int i = lane;
#pragma unroll
    for (int tp = 0; tp < 16; ++tp) {
      uint lo = (uint)__builtin_bit_cast(unsigned short, P16[(2 * tp) * 36 + i]);
      uint hi = (uint)__builtin_bit_cast(unsigned short, P16[(2 * tp + 1) * 36 + i]);
      gp[i * 16 + tp] = lo | (hi << 16);
    }
  }
  if (lane == 0) segL[blk] = Lacc;
}

// ---------------------------------------------------------------------------
// CRF stage B + numerator merged (verified R21)
// ---------------------------------------------------------------------------
__global__ __launch_bounds__(64) void crf_comb_kernel(
    const int* __restrict__ tags, const float* __restrict__ feats,
    const float* __restrict__ trans, const uint* __restrict__ segP,
    const float* __restrict__ segL, float* __restrict__ num,
    float* __restrict__ den)
{
  const float L2E = 1.4426950408889634f, LN2 = 0.6931471805599453f;
  int b = blockIdx.x, l = threadIdx.x;

  {
    const int* tb = tags + b * SEQ;
    float acc = 0.f;
    for (int s = l; s < SEQ; s += 64) {
      int tg = tb[s];
      int pv = (s == 0) ? START_TAG : tb[s - 1];
      acc += trans[pv * NTAG + tg] + feats[((size_t)b * SEQ + s) * NTAG + tg];
    }
#pragma unroll
    for (int msk = 1; msk < 64; msk <<= 1) acc += __shfl_xor(acc, msk);
    if (l == 0) num[b] = acc + trans[tb[SEQ - 1] * NTAG + END_TAG];
  }

  int i = l & 31, hp = l >> 5;
  const float* fb = feats + (size_t)b * SEQ * NTAG;

  float sT = 0.f;
  for (int p = 0; p < 32; ++p) sT += fexp2(trans[i * 32 + p] * L2E);
  float v = (1.f + sT) * fexp2(fb[i] * L2E);
  float L = -10000.f * L2E;

  float vo = __shfl_xor(v, 1);
  uint pv = (i & 1) ? packh2(vo, v) : packh2(v, vo);

  const uint* gp0 = segP + (size_t)b * 32 * 512 + i * 16 + hp * 8;
  uint4 ra = *(const uint4*)(gp0);
  uint4 rb = *(const uint4*)(gp0 + 4);

  for (int seg = 0; seg < 32; ++seg) {
    uint4 ca = ra, cb = rb;
    if (seg + 1 < 32) {
      ra = *(const uint4*)(gp0 + (seg + 1) * 512);
      rb = *(const uint4*)(gp0 + (seg + 1) * 512 + 4);
    }
    float g0 = __shfl(__builtin_bit_cast(float, pv), hp * 16 + 0);
    float g1 = __shfl(__builtin_bit_cast(float, pv), hp * 16 + 2);
    float g2 = __shfl(__builtin_bit_cast(float, pv), hp * 16 + 4);
    float g3 = __shfl(__builtin_bit_cast(float, pv), hp * 16 + 6);
    float g4 = __shfl(__builtin_bit_cast(float, pv), hp * 16 + 8);
    float g5 = __shfl(__builtin_bit_cast(float, pv), hp * 16 + 10);
    float g6 = __shfl(__builtin_bit_cast(float, pv), hp * 16 + 12);
    float g7 = __shfl(__builtin_bit_cast(float, pv), hp * 16 + 14);
    float acc = 0.f;
    acc = fdot2(__builtin_bit_cast(uint, g0), ca.x, acc);
    acc = fdot2(__builtin_bit_cast(uint, g1), ca.y, acc);
    acc = fdot2(__builtin_bit_cast(uint, g2), ca.z, acc);
    acc = fdot2(__builtin_bit_cast(uint, g3), ca.w, acc);
    acc = fdot2(__builtin_bit_cast(uint, g4), cb.x, acc);
    acc = fdot2(__builtin_bit_cast(uint, g5), cb.y, acc);
    acc = fdot2(__builtin_bit_cast(uint, g6), cb.z, acc);
    acc = fdot2(__builtin_bit_cast(uint, g7), cb.w, acc);
    float sm = acc + __shfl_xor(acc, 32);
    uint ub = (uint)__builtin_amdgcn_readfirstlane((int)__builtin_bit_cast(uint, sm));
    int e = (int)((ub >> 23) & 255u);
    L += (float)(e - 127) + segL[b * 32 + seg];
    float sc = __builtin_bit_cast(float, (uint)((254 - e) << 23));
    v = sm * sc;
    float vo2 = __shfl_xor(v, 1);
    pv = (i & 1) ? packh2(vo2, v) : packh2(v, vo2);
  }
  float wv = v * fexp2(trans[i * 32 + END_TAG] * L2E);
#pragma unroll
  for (int msk = 1; msk <= 16; msk <<= 1) wv += __shfl_xor(wv, msk);
  if (l == 0) den[b] = (L + flog2(wv)) * LN2;
}

__global__ __launch_bounds__(128) void final_kernel(
    const float* __restrict__ num, const float* __restrict__ den,
    float* __restrict__ out)
{
  int tid = threadIdx.x;
  float v = num[tid] - den[tid];
#pragma unroll
  for (int msk = 1; msk < 64; msk <<= 1) v += __shfl_xor(v, msk);
  __shared__ float tmp[2];
  if ((tid & 63) == 0) tmp[tid >> 6] = v;
  __syncthreads();
  if (tid == 0) out[0] = (tmp[0] + tmp[1]) * (1.f / 128.f);
}

// ---------------------------------------------------------------------------
// Workspace layouts. sentT (256KB) sits in the gap before hh.
// Small (ws < 169MB): chunked gatex, 13 dispatches.
// Big  (ws >= 168820736): gatexAll = [34603008, 168820736); feats/segP/segL
// overlay it after lstm. 7 dispatches.
// ---------------------------------------------------------------------------
extern "C" void kernel_launch(void* const* d_in, const int* in_sizes, int n_in,
                              void* d_out, int out_size, void* d_ws, size_t ws_size,
                              hipStream_t stream)
{
  const int* sentence = (const int*)d_in[0];
  const int* tags = (const int*)d_in[1];
  const float* embed = (const float*)d_in[2];
  const float* Wihf = (const float*)d_in[3];
  const float* Whhf = (const float*)d_in[4];
  const float* bihf = (const float*)d_in[5];
  const float* bhhf = (const float*)d_in[6];
  const float* Wihb = (const float*)d_in[7];
  const float* Whhb = (const float*)d_in[8];
  const float* bihb = (const float*)d_in[9];
  const float* bhhb = (const float*)d_in[10];
  const float* Wout = (const float*)d_in[11];
  const float* bout = (const float*)d_in[12];
  const float* trans = (const float*)d_in[13];
  const float* h0 = (const float*)d_in[14];
  const float* c0 = (const float*)d_in[15];
  float* out = (float*)d_out;

  char* ws = (char*)d_ws;
  uint* wihI = (uint*)(ws + 0);
  uint* whh = (uint*)(ws + 262144);
  uint* woutp = (uint*)(ws + 524288);
  float* biasI = (float*)(ws + 540672);
  float* numb = (float*)(ws + 544768);
  float* denb = (float*)(ws + 545280);
  float* statec = (float*)(ws + 545792);
  int* sentT = (int*)(ws + 700416);
  uint* hh = (uint*)(ws + 1048576);
  uint* gatex = (uint*)(ws + 34603008);
  float* feats = (float*)(ws + 34603008);
  uint* segP = (uint*)(ws + 42991616);
  float* segL = (float*)(ws + 51380224);

  hipLaunchKernelGGL(prep_kernel, dim3(788), dim3(256), 0, stream,
                     Wihf, Whhf, bihf, bhhf, Wihb, Whhb, bihb, bhhb, Wout,
                     sentence, wihI, whh, woutp, biasI, sentT);

  bool big = ws_size >= 168820736ull;
  if (big) {
    hipLaunchKernelGGL(gemmx_all_kernel, dim3(4096), dim3(256), 0, stream,
                       sentT, embed, wihI, biasI, gatex);
    hipLaunchKernelGGL(lstm_all_kernel, dim3(256), dim3(512), 0, stream,
                       gatex, whh, h0, c0, hh);
  } else {
    for (int c = 0; c < 4; ++c) {
      hipLaunchKernelGGL(gemmx_kernel, dim3(1024), dim3(256), 0, stream,
                         sentT, embed, wihI, biasI, gatex, c);
      hipLaunchKernelGGL(lstm_kernel, dim3(256), dim3(512), 0, stream,
                         gatex, whh, h0, c0, statec, hh, c);
    }
  }

  hipLaunchKernelGGL(outproj_kernel, dim3(1024), dim3(256), 0, stream,
                     hh, woutp, bout, feats);
  hipLaunchKernelGGL(crf_seg_kernel, dim3(4096), dim3(64), 0, stream,
                     feats, trans, segP, segL);
  hipLaunchKernelGGL(crf_comb_kernel, dim3(128), dim3(64), 0, stream,
                     tags, feats, trans, segP, segL, numb, denb);
  hipLaunchKernelGGL(final_kernel, dim3(1), dim3(128), 0, stream,
                     numb, denb, out);
}

// Round 15
// 482.783 us; speedup vs baseline: 1.6016x; 1.0428x over previous
//
#include <hip/hip_runtime.h>

typedef unsigned int uint;
typedef unsigned short ushort;
typedef __fp16 half2_t __attribute__((ext_vector_type(2)));
typedef __fp16 half8_t __attribute__((ext_vector_type(8)));
typedef float floatx4 __attribute__((ext_vector_type(4)));

#define SEQ 512
#define BATCH 128
#define HID 128
#define NTAG 32
#define START_TAG 30
#define END_TAG 31

__device__ __forceinline__ float fdot2(uint a, uint b, float c) {
  return __builtin_amdgcn_fdot2(__builtin_bit_cast(half2_t, a),
                                __builtin_bit_cast(half2_t, b), c, false);
}
__device__ __forceinline__ uint packh2(float a, float b) {
  half2_t h = __builtin_amdgcn_cvt_pkrtz(a, b);
  return __builtin_bit_cast(uint, h);
}
__device__ __forceinline__ float frcp(float x) { return __builtin_amdgcn_rcpf(x); }
__device__ __forceinline__ float fexp2(float x) { return __builtin_amdgcn_exp2f(x); }
__device__ __forceinline__ float flog2(float x) { return __builtin_amdgcn_logf(x); }

// Quad butterfly sum via DPP quad_perm (VALU pipe, no LDS).
__device__ __forceinline__ float quad_add(float x) {
  int a = __builtin_bit_cast(int, x);
  int b = __builtin_amdgcn_update_dpp(0, a, 0xB1, 0xF, 0xF, true);
  float y = x + __builtin_bit_cast(float, b);
  int c2 = __builtin_bit_cast(int, y);
  int d2 = __builtin_amdgcn_update_dpp(0, c2, 0x4E, 0xF, 0xF, true);
  return y + __builtin_bit_cast(float, d2);
}
template <int CTRL>
__device__ __forceinline__ float quad_bcast(float x) {
  int a = __builtin_bit_cast(int, x);
  int b = __builtin_amdgcn_update_dpp(0, a, CTRL, 0xF, 0xF, true);
  return __builtin_bit_cast(float, b);
}

// ---------------------------------------------------------------------------
// prep — R23: adds embed fp32->fp16 one-pass conversion (embedH, 8.2MB)
// using the SAME cvt_pkrtz RTZ conversion gemmx applied per-element, so
// numerics are bit-identical. embedH lives in the hh region (dead until
// lstm, which runs after gemmx in the big path).
// ---------------------------------------------------------------------------
__global__ __launch_bounds__(256) void prep_kernel(
    const float* __restrict__ Wihf, const float* __restrict__ Whhf,
    const float* __restrict__ bihf, const float* __restrict__ bhhf,
    const float* __restrict__ Wihb, const float* __restrict__ Whhb,
    const float* __restrict__ bihb, const float* __restrict__ bhhb,
    const float* __restrict__ Wout, const int* __restrict__ sentence,
    const float* __restrict__ embed,
    uint* __restrict__ wihI, uint* __restrict__ whh,
    uint* __restrict__ woutp, float* __restrict__ biasI,
    int* __restrict__ sentT, uint* __restrict__ embH)
{
  int idx = blockIdx.x * 256 + threadIdx.x;
  if (idx < 65536) {
    int d = idx >> 15, rem = idx & 32767;
    int n = rem >> 6, dw = rem & 63;
    int m = n >> 2, q = n & 3;
    int g = q * 128 + m;
    const float* W = d ? Wihb : Wihf;
    wihI[idx] = packh2(W[g * 128 + 2 * dw], W[g * 128 + 2 * dw + 1]);
  }
  int i2 = idx - 65536;
  if (i2 >= 0 && i2 < 65536) {
    int d = i2 >> 15, rem = i2 & 32767;
    int g = rem >> 6, dw = rem & 63;
    const float* W = d ? Whhb : Whhf;
    whh[i2] = packh2(W[g * 128 + 2 * dw], W[g * 128 + 2 * dw + 1]);
  }
  int i3 = idx - 131072;
  if (i3 >= 0 && i3 < 4096) {
    int k = i3 >> 7, dw = i3 & 127;
    float a, b2;
    if (dw < 64) { a = Wout[k * 256 + 2 * dw]; b2 = Wout[k * 256 + 2 * dw + 1]; }
    else { int j = dw - 64; a = Wout[k * 256 + 128 + 2 * j]; b2 = Wout[k * 256 + 128 + 2 * j + 1]; }
    woutp[i3] = packh2(a, b2);
  }
  int i4 = idx - 135168;
  if (i4 >= 0 && i4 < 1024) {
    int d = i4 >> 9, n = i4 & 511;
    int g = (n & 3) * 128 + (n >> 2);
    biasI[i4] = d ? (bihb[g] + bhhb[g]) : (bihf[g] + bhhf[g]);
  }
  int i5 = idx - 136192;
  if (i5 >= 0 && i5 < 65536) {
    int b = i5 & 127, s = i5 >> 7;
    sentT[i5] = sentence[b * SEQ + s];
  }
  int i6 = idx - 201728;
  if (i6 >= 0 && i6 < 2097152) {
    embH[i6] = packh2(embed[2 * i6], embed[2 * i6 + 1]);
  }
}

// ---------------------------------------------------------------------------
// gemmx core. ALLT (big-ws) path reads pre-converted fp16 embedH (halves
// gather traffic, kills 64 packh2/thread); chunked fallback keeps fp32
// embed (embedH region is clobbered by its interleaved lstm).
// Output staged in LDS, written as coalesced 16B/lane bursts (R22).
// ---------------------------------------------------------------------------
template <bool ALLT>
__device__ __forceinline__ void gemmx_body(
    const int* __restrict__ sentT, const float* __restrict__ embed,
    const uint* __restrict__ embH,
    const uint* __restrict__ wihI, const float* __restrict__ biasI,
    uint* __restrict__ gatex, int chunk, int blk)
{
  int tl = blk & 127, nb = (blk >> 7) & 3, d = blk >> 9;
  int t = chunk * 128 + tl;
  int s = d ? (511 - t) : t;
  __shared__ int tok[128];
  __shared__ __align__(16) __fp16 tile[128][136];   // ~34.8 KB
  int tid = threadIdx.x;
  if (tid < 128) tok[tid] = sentT[s * 128 + tid];
  __syncthreads();

  int w = tid >> 6, lane = tid & 63;
  int q = lane >> 4, r = lane & 15;
  int wr = w >> 1, wc = w & 1;
  int r0 = wr * 64;
  int cl0 = wc * 64;
  int c0 = nb * 128 + cl0;

  floatx4 acc[4][4];
#pragma unroll
  for (int i = 0; i < 4; ++i)
#pragma unroll
    for (int j = 0; j < 4; ++j) acc[i][j] = (floatx4){0.f, 0.f, 0.f, 0.f};

  const uint4* bptr[4];
#pragma unroll
  for (int j = 0; j < 4; ++j)
    bptr[j] = (const uint4*)(wihI + ((size_t)d * 512 + c0 + j * 16 + r) * 64) + q;

  if constexpr (ALLT) {
    const uint4* aptr[4];
#pragma unroll
    for (int i = 0; i < 4; ++i)
      aptr[i] = (const uint4*)embH + (size_t)tok[r0 + i * 16 + r] * 16 + q;
#pragma unroll
    for (int kc = 0; kc < 4; ++kc) {
      half8_t af[4], bf[4];
#pragma unroll
      for (int i = 0; i < 4; ++i)
        af[i] = __builtin_bit_cast(half8_t, aptr[i][kc * 4]);
#pragma unroll
      for (int j = 0; j < 4; ++j)
        bf[j] = __builtin_bit_cast(half8_t, bptr[j][kc * 4]);
#pragma unroll
      for (int i = 0; i < 4; ++i)
#pragma unroll
        for (int j = 0; j < 4; ++j)
          acc[i][j] = __builtin_amdgcn_mfma_f32_16x16x32_f16(af[i], bf[j], acc[i][j], 0, 0, 0);
    }
  } else {
    const float4* aptr[4];
#pragma unroll
    for (int i = 0; i < 4; ++i)
      aptr[i] = (const float4*)(embed + (size_t)tok[r0 + i * 16 + r] * HID) + q * 2;
#pragma unroll
    for (int kc = 0; kc < 4; ++kc) {
      half8_t af[4], bf[4];
#pragma unroll
      for (int i = 0; i < 4; ++i) {
        float4 x0 = aptr[i][kc * 8];
        float4 x1 = aptr[i][kc * 8 + 1];
        uint4 u;
        u.x = packh2(x0.x, x0.y); u.y = packh2(x0.z, x0.w);
        u.z = packh2(x1.x, x1.y); u.w = packh2(x1.z, x1.w);
        af[i] = __builtin_bit_cast(half8_t, u);
      }
#pragma unroll
      for (int j = 0; j < 4; ++j)
        bf[j] = __builtin_bit_cast(half8_t, bptr[j][kc * 4]);
#pragma unroll
      for (int i = 0; i < 4; ++i)
#pragma unroll
        for (int j = 0; j < 4; ++j)
          acc[i][j] = __builtin_amdgcn_mfma_f32_16x16x32_f16(af[i], bf[j], acc[i][j], 0, 0, 0);
    }
  }

  // Stage C (+bias) into LDS.
#pragma unroll
  for (int j = 0; j < 4; ++j) {
    int cl = cl0 + j * 16 + r;
    float bb = biasI[d * 512 + nb * 128 + cl];
#pragma unroll
    for (int i = 0; i < 4; ++i) {
      int rb = r0 + i * 16 + q * 4;
#pragma unroll
      for (int reg = 0; reg < 4; ++reg)
        tile[rb + reg][cl] = (__fp16)(acc[i][j][reg] + bb);
    }
  }
  __syncthreads();

  size_t dstride = ALLT ? (size_t)65536 * 512 : (size_t)16384 * 512;
  int rowbase = (ALLT ? t : tl) * 128;
  __fp16* gat = ((__fp16*)gatex) + (size_t)d * dstride;
  int prow = tid >> 4, pseg = tid & 15;
#pragma unroll
  for (int pass = 0; pass < 8; ++pass) {
    int row = pass * 16 + prow;
    uint4 v = *(const uint4*)(&tile[row][pseg * 8]);
    *(uint4*)(gat + ((size_t)(rowbase + row)) * 512 + nb * 128 + pseg * 8) = v;
  }
}

__global__ __launch_bounds__(256, 2) void gemmx_kernel(
    const int* __restrict__ sentT, const float* __restrict__ embed,
    const uint* __restrict__ wihI, const float* __restrict__ biasI,
    uint* __restrict__ gatex, int chunk)
{
  gemmx_body<false>(sentT, embed, nullptr, wihI, biasI, gatex, chunk, blockIdx.x);
}

__global__ __launch_bounds__(256, 2) void gemmx_all_kernel(
    const int* __restrict__ sentT, const uint* __restrict__ embH,
    const uint* __restrict__ wihI, const float* __restrict__ biasI,
    uint* __restrict__ gatex)
{
  gemmx_body<true>(sentT, nullptr, embH, wihI, biasI, gatex,
                   blockIdx.x >> 10, blockIdx.x & 1023);
}

// ---------------------------------------------------------------------------
// LSTM step core (R15 structure; verified).
// ---------------------------------------------------------------------------
struct LstmCtx {
  uint4 wreg[4][4];
  float sl, Ac, Bc;
  int kq, m;
};

__device__ __forceinline__ void lstm_step(
    LstmCtx& cx, __fp16 (*hist)[128], int row_r, int row_w, ushort gxh,
    float& c)
{
  const float L2E = 1.4426950408889634f;
  float a0 = 0.f, a1 = 0.f, a2 = 0.f, a3 = 0.f;
  float b0 = 0.f, b1 = 0.f, b2 = 0.f, b3 = 0.f;
  const uint4* z4 = (const uint4*)(&hist[row_r][cx.kq * 32]);
#pragma unroll
  for (int i = 0; i < 2; ++i) {
    uint4 z = z4[i];
    a0 = fdot2(z.x, cx.wreg[0][i].x, a0);
    a0 = fdot2(z.y, cx.wreg[0][i].y, a0);
    a0 = fdot2(z.z, cx.wreg[0][i].z, a0);
    a0 = fdot2(z.w, cx.wreg[0][i].w, a0);
    a1 = fdot2(z.x, cx.wreg[1][i].x, a1);
    a1 = fdot2(z.y, cx.wreg[1][i].y, a1);
    a1 = fdot2(z.z, cx.wreg[1][i].z, a1);
    a1 = fdot2(z.w, cx.wreg[1][i].w, a1);
    a2 = fdot2(z.x, cx.wreg[2][i].x, a2);
    a2 = fdot2(z.y, cx.wreg[2][i].y, a2);
    a2 = fdot2(z.z, cx.wreg[2][i].z, a2);
    a2 = fdot2(z.w, cx.wreg[2][i].w, a2);
    a3 = fdot2(z.x, cx.wreg[3][i].x, a3);
    a3 = fdot2(z.y, cx.wreg[3][i].y, a3);
    a3 = fdot2(z.z, cx.wreg[3][i].z, a3);
    a3 = fdot2(z.w, cx.wreg[3][i].w, a3);
  }
#pragma unroll
  for (int i = 2; i < 4; ++i) {
    uint4 z = z4[i];
    b0 = fdot2(z.x, cx.wreg[0][i].x, b0);
    b0 = fdot2(z.y, cx.wreg[0][i].y, b0);
    b0 = fdot2(z.z, cx.wreg[0][i].z, b0);
    b0 = fdot2(z.w, cx.wreg[0][i].w, b0);
    b1 = fdot2(z.x, cx.wreg[1][i].x, b1);
    b1 = fdot2(z.y, cx.wreg[1][i].y, b1);
    b1 = fdot2(z.z, cx.wreg[1][i].z, b1);
    b1 = fdot2(z.w, cx.wreg[1][i].w, b1);
    b2 = fdot2(z.x, cx.wreg[2][i].x, b2);
    b2 = fdot2(z.y, cx.wreg[2][i].y, b2);
    b2 = fdot2(z.z, cx.wreg[2][i].z, b2);
    b2 = fdot2(z.w, cx.wreg[2][i].w, b2);
    b3 = fdot2(z.x, cx.wreg[3][i].x, b3);
    b3 = fdot2(z.y, cx.wreg[3][i].y, b3);
    b3 = fdot2(z.z, cx.wreg[3][i].z, b3);
    b3 = fdot2(z.w, cx.wreg[3][i].w, b3);
  }
  a0 += b0; a1 += b1; a2 += b2; a3 += b3;
  a0 = quad_add(a0);
  a1 = quad_add(a1);
  a2 = quad_add(a2);
  a3 = quad_add(a3);
  float s01 = (cx.kq & 1) ? a1 : a0;
  float s23 = (cx.kq & 1) ? a3 : a2;
  float own = (cx.kq & 2) ? s23 : s01;
  own += (float)__builtin_bit_cast(__fp16, gxh);
  float e = fexp2(own * cx.sl);
  float r = frcp(1.f + e);
  float out = cx.Ac * r + cx.Bc;
  float ig = quad_bcast<0x00>(out);
  float fg = quad_bcast<0x55>(out);
  float gg = quad_bcast<0xAA>(out);
  float og = quad_bcast<0xFF>(out);
  c = fg * c + ig * gg;
  float e2 = fexp2(c * (2.f * L2E));
  float r2 = frcp(1.f + e2);
  float th = 1.f - 2.f * r2;
  float hv = og * th;

  if (cx.kq == 0) hist[row_w][cx.m] = (__fp16)hv;
  __builtin_amdgcn_sched_barrier(0);
  asm volatile("s_waitcnt lgkmcnt(0)");
  __builtin_amdgcn_sched_barrier(0);
  __builtin_amdgcn_s_barrier();
}

__device__ __forceinline__ void lstm_init(LstmCtx& cx, const uint* whh,
                                          int d, int tid)
{
  const float L2E = 1.4426950408889634f;
  cx.kq = tid & 3;
  cx.m = tid >> 2;
  const bool isg = (cx.kq == 2);
  cx.sl = isg ? (2.f * L2E) : (-L2E);
  cx.Ac = isg ? -2.f : 1.f;
  cx.Bc = isg ? 1.f : 0.f;
  const uint4* wh4 = (const uint4*)whh + (size_t)d * 8192;
#pragma unroll
  for (int g = 0; g < 4; ++g) {
    const uint4* row = wh4 + ((size_t)(g * 128 + cx.m)) * 16 + cx.kq * 4;
#pragma unroll
    for (int i = 0; i < 4; ++i) cx.wreg[g][i] = row[i];
  }
}

// ---------------------------------------------------------------------------
// Chunked lstm (small-ws fallback).
// ---------------------------------------------------------------------------
__global__ __attribute__((amdgpu_waves_per_eu(2, 2))) __launch_bounds__(512)
void lstm_kernel(
    const uint* __restrict__ gatex, const uint* __restrict__ whh,
    const float* __restrict__ h0, const float* __restrict__ c0,
    float* __restrict__ statec, uint* __restrict__ hh, int chunk)
{
  const int wg = blockIdx.x;
  const int d = wg >> 7, b = wg & 127;
  const int tid = threadIdx.x;

  __shared__ __align__(16) __fp16 hist[128][128];   // 32 KB
  LstmCtx cx;
  lstm_init(cx, whh, d, tid);

  float c = (chunk == 0) ? c0[(size_t)(d * 128 + b) * 128 + cx.m]
                         : statec[(size_t)(d * 128 + b) * 128 + cx.m];

  if (tid < 64) {
    uint* h127 = (uint*)&hist[127][0];
    if (chunk == 0) {
      float2 hv = ((const float2*)(h0 + (size_t)(d * 128 + b) * 128))[tid];
      h127[tid] = packh2(hv.x, hv.y);
    } else {
      int sprev = d ? (511 - (chunk * 128 - 1)) : (chunk * 128 - 1);
      h127[tid] = hh[((size_t)(d * 512 + sprev) * 128 + b) * 64 + tid];
    }
  }
  const ushort* gxp = (const ushort*)gatex + (size_t)d * 8388608 +
                      (size_t)b * 512 + 4 * cx.m + cx.kq;

  ushort g0 = gxp[0];
  ushort g1 = gxp[(size_t)1 * 65536];
  ushort g2 = gxp[(size_t)2 * 65536];
  ushort g3 = gxp[(size_t)3 * 65536];
  __syncthreads();

  for (int tl = 0; tl < 128; tl += 4) {
    int i0 = tl + 4 > 127 ? 127 : tl + 4;
    int i1 = tl + 5 > 127 ? 127 : tl + 5;
    int i2 = tl + 6 > 127 ? 127 : tl + 6;
    int i3 = tl + 7 > 127 ? 127 : tl + 7;
    ushort n0 = gxp[(size_t)i0 * 65536];
    ushort n1 = gxp[(size_t)i1 * 65536];
    ushort n2 = gxp[(size_t)i2 * 65536];
    ushort n3 = gxp[(size_t)i3 * 65536];
    lstm_step(cx, hist, (tl + 127) & 127, tl + 0, g0, c);
    lstm_step(cx, hist, (tl + 0) & 127, tl + 1, g1, c);
    lstm_step(cx, hist, (tl + 1) & 127, tl + 2, g2, c);
    lstm_step(cx, hist, (tl + 2) & 127, tl + 3, g3, c);
    g0 = n0; g1 = n1; g2 = n2; g3 = n3;
  }

  if (cx.kq == 0) statec[(size_t)(d * 128 + b) * 128 + cx.m] = c;

  int base = chunk * 128;
  for (int i = tid; i < 2048; i += 512) {
    int sl2 = i >> 4, q4 = i & 15;
    int s = d ? (511 - (base + sl2)) : (base + sl2);
    *(uint4*)(&hh[((size_t)(d * 512 + s) * 128 + b) * 64 + q4 * 4]) =
        *(const uint4*)((const uint*)&hist[sl2][0] + q4 * 4);
  }
}

// ---------------------------------------------------------------------------
// All-timestep lstm (big-ws path; verified 293-296us).
// ---------------------------------------------------------------------------
__global__ __attribute__((amdgpu_waves_per_eu(2, 2))) __launch_bounds__(512)
void lstm_all_kernel(
    const uint* __restrict__ gatex, const uint* __restrict__ whh,
    const float* __restrict__ h0, const float* __restrict__ c0,
    uint* __restrict__ hh)
{
  const int wg = blockIdx.x;
  const int d = wg >> 7, b = wg & 127;
  const int tid = threadIdx.x;

  __shared__ __align__(16) __fp16 hist[128][128];   // 32 KB
  LstmCtx cx;
  lstm_init(cx, whh, d, tid);

  float c = c0[(size_t)(d * 128 + b) * 128 + cx.m];

  if (tid < 64) {
    uint* h127 = (uint*)&hist[127][0];
    float2 hv = ((const float2*)(h0 + (size_t)(d * 128 + b) * 128))[tid];
    h127[tid] = packh2(hv.x, hv.y);
  }
  const ushort* gxp = (const ushort*)gatex + (size_t)d * 33554432 +
                      (size_t)b * 512 + 4 * cx.m + cx.kq;

  ushort g0 = gxp[0];
  ushort g1 = gxp[(size_t)1 * 65536];
  ushort g2 = gxp[(size_t)2 * 65536];
  ushort g3 = gxp[(size_t)3 * 65536];
  __syncthreads();

  for (int tl = 0; tl < 512; tl += 4) {
    int i0 = tl + 4 > 511 ? 511 : tl + 4;
    int i1 = tl + 5 > 511 ? 511 : tl + 5;
    int i2 = tl + 6 > 511 ? 511 : tl + 6;
    int i3 = tl + 7 > 511 ? 511 : tl + 7;
    ushort n0 = gxp[(size_t)i0 * 65536];
    ushort n1 = gxp[(size_t)i1 * 65536];
    ushort n2 = gxp[(size_t)i2 * 65536];
    ushort n3 = gxp[(size_t)i3 * 65536];
    lstm_step(cx, hist, (tl + 127) & 127, (tl + 0) & 127, g0, c);
    lstm_step(cx, hist, (tl + 0) & 127, (tl + 1) & 127, g1, c);
    lstm_step(cx, hist, (tl + 1) & 127, (tl + 2) & 127, g2, c);
    lstm_step(cx, hist, (tl + 2) & 127, (tl + 3) & 127, g3, c);
    g0 = n0; g1 = n1; g2 = n2; g3 = n3;

    if (((tl + 3) & 127) == 127) {
      int base = ((tl + 3) >> 7) * 128;
      for (int i = tid; i < 2048; i += 512) {
        int sl2 = i >> 4, q4 = i & 15;
        int s = d ? (511 - (base + sl2)) : (base + sl2);
        *(uint4*)(&hh[((size_t)(d * 512 + s) * 128 + b) * 64 + q4 * 4]) =
            *(const uint4*)((const uint*)&hist[sl2][0] + q4 * 4);
      }
      __syncthreads();
    }
  }
}

// ---------------------------------------------------------------------------
// Output projection — MFMA GEMM [65536x256]x[256x32], zero LDS (verified).
// ---------------------------------------------------------------------------
__global__ __launch_bounds__(256) void outproj_kernel(
    const uint* __restrict__ hh, const uint* __restrict__ woutp,
    const float* __restrict__ bout, float* __restrict__ feats)
{
  int tid = threadIdx.x;
  int w = tid >> 6, lane = tid & 63;
  int q = lane >> 4, c = lane & 15;
  int row0 = blockIdx.x * 64 + w * 16;

  const uint4* wp4 = (const uint4*)woutp;
  uint4 bf0[8], bf1[8];
#pragma unroll
  for (int ks = 0; ks < 8; ++ks) {
    bf0[ks] = wp4[(size_t)c * 32 + ks * 4 + q];
    bf1[ks] = wp4[(size_t)(16 + c) * 32 + ks * 4 + q];
  }

  int rr = row0 + c;
  int br = rr >> 9, sr = rr & 511;
  const uint4* af4 = (const uint4*)(hh + ((size_t)(sr * BATCH + br)) * 64);
  const uint4* ab4 = (const uint4*)(hh + ((size_t)((SEQ + sr) * BATCH + br)) * 64);

  floatx4 acc0 = (floatx4){0.f, 0.f, 0.f, 0.f};
  floatx4 acc1 = (floatx4){0.f, 0.f, 0.f, 0.f};
#pragma unroll
  for (int ks = 0; ks < 8; ++ks) {
    uint4 a = (ks < 4) ? af4[ks * 4 + q] : ab4[(ks - 4) * 4 + q];
    half8_t af = __builtin_bit_cast(half8_t, a);
    acc0 = __builtin_amdgcn_mfma_f32_16x16x32_f16(
        af, __builtin_bit_cast(half8_t, bf0[ks]), acc0, 0, 0, 0);
    acc1 = __builtin_amdgcn_mfma_f32_16x16x32_f16(
        af, __builtin_bit_cast(half8_t, bf1[ks]), acc1, 0, 0, 0);
  }

  float bb0 = bout[c], bb1 = bout[16 + c];
#pragma unroll
  for (int reg = 0; reg < 4; ++reg) {
    int orow = row0 + q * 4 + reg;
    feats[(size_t)orow * 32 + c] = acc0[reg] + bb0;
    feats[(size_t)orow * 32 + 16 + c] = acc1[reg] + bb1;
  }
}

// ---------------------------------------------------------------------------
// CRF stage A (unchanged, verified)
// ---------------------------------------------------------------------------
__global__ __launch_bounds__(64) void crf_seg_kernel(
    const float* __restrict__ feats, const float* __restrict__ trans,
    uint* __restrict__ segP, float* __restrict__ segL)
{
  const float L2E = 1.4426950408889634f;
  int blk = blockIdx.x;
  int b = blk >> 5, j = blk & 31;
  int tstart = 1 + 16 * j;
  int nsteps = (j == 31) ? 15 : 16;
  int lane = threadIdx.x;
  int c = lane & 15, q = lane >> 4;

  half8_t afr[2];
#pragma unroll
  for (int rt = 0; rt < 2; ++rt) {
    const float* trow = trans + (rt * 16 + c) * 32 + q * 8;
    float e[8];
#pragma unroll
    for (int i = 0; i < 8; ++i) e[i] = fexp2(trow[i] * L2E);
    uint4 u;
    u.x = packh2(e[0], e[1]); u.y = packh2(e[2], e[3]);
    u.z = packh2(e[4], e[5]); u.w = packh2(e[6], e[7]);
    afr[rt] = __builtin_bit_cast(half8_t, u);
  }
  half8_t bfr[2];
#pragma unroll
  for (int ct = 0; ct < 2; ++ct) {
    uint4 u;
    uint vals[8];
#pragma unroll
    for (int i = 0; i < 8; ++i)
      vals[i] = ((q * 8 + i) == (ct * 16 + c)) ? 0x3C00u : 0u;
    u.x = vals[0] | (vals[1] << 16);
    u.y = vals[2] | (vals[3] << 16);
    u.z = vals[4] | (vals[5] << 16);
    u.w = vals[6] | (vals[7] << 16);
    bfr[ct] = __builtin_bit_cast(half8_t, u);
  }

  __shared__ __fp16 P16[32 * 36];

  const float* fb = feats + ((size_t)b * SEQ + tstart) * NTAG;
  float Lacc = 0.f;
  float4 pre0 = *(const float4*)(fb + q * 4);
  float4 pre1 = *(const float4*)(fb + 16 + q * 4);

  for (int s = 0; s < nsteps; ++s) {
    float4 f0 = pre0, f1 = pre1;
    if (s + 1 < nsteps) {
      pre0 = *(const float4*)(fb + (s + 1) * 32 + q * 4);
      pre1 = *(const float4*)(fb + (s + 1) * 32 + 16 + q * 4);
    }
    floatx4 z4 = (floatx4){0.f, 0.f, 0.f, 0.f};
    floatx4 c00 = __builtin_amdgcn_mfma_f32_16x16x32_f16(afr[0], bfr[0], z4, 0, 0, 0);
    floatx4 c01 = __builtin_amdgcn_mfma_f32_16x16x32_f16(afr[0], bfr[1], z4, 0, 0, 0);
    floatx4 c10 = __builtin_amdgcn_mfma_f32_16x16x32_f16(afr[1], bfr[0], z4, 0, 0, 0);
    floatx4 c11 = __builtin_amdgcn_mfma_f32_16x16x32_f16(afr[1], bfr[1], z4, 0, 0, 0);
    float pf0[4], pf1[4];
    pf0[0] = fexp2(f0.x * L2E); pf0[1] = fexp2(f0.y * L2E);
    pf0[2] = fexp2(f0.z * L2E); pf0[3] = fexp2(f0.w * L2E);
    pf1[0] = fexp2(f1.x * L2E); pf1[1] = fexp2(f1.y * L2E);
    pf1[2] = fexp2(f1.z * L2E); pf1[3] = fexp2(f1.w * L2E);
    float v00[4], v01[4], v10[4], v11[4];
#pragma unroll
    for (int rg = 0; rg < 4; ++rg) {
      v00[rg] = c00[rg] * pf0[rg];
      v01[rg] = c01[rg] * pf0[rg];
      v10[rg] = c10[rg] * pf1[rg];
      v11[rg] = c11[rg] * pf1[rg];
    }
    float mx = 0.f;
#pragma unroll
    for (int rg = 0; rg < 4; ++rg)
      mx = fmaxf(mx, fmaxf(fmaxf(v00[rg], v01[rg]), fmaxf(v10[rg], v11[rg])));
    uint ub = (uint)__builtin_amdgcn_readfirstlane((int)__builtin_bit_cast(uint, mx));
    int e = (int)((ub >> 23) & 255u);
    Lacc += (float)(e - 127);
    float sc = __builtin_bit_cast(float, (uint)((254 - e) << 23));

    __syncthreads();
    {
      uint2 wv2;
      wv2.x = packh2(v00[0] * sc, v00[1] * sc);
      wv2.y = packh2(v00[2] * sc, v00[3] * sc);
      *(uint2*)(&P16[c * 36 + q * 4]) = wv2;
      wv2.x = packh2(v10[0] * sc, v10[1] * sc);
      wv2.y = packh2(v10[2] * sc, v10[3] * sc);
      *(uint2*)(&P16[c * 36 + 16 + q * 4]) = wv2;
      wv2.x = packh2(v01[0] * sc, v01[1] * sc);
      wv2.y = packh2(v01[2] * sc, v01[3] * sc);
      *(uint2*)(&P16[(16 + c) * 36 + q * 4]) = wv2;
      wv2.x = packh2(v11[0] * sc, v11[1] * sc);
      wv2.y = packh2(v11[2] * sc, v11[3] * sc);
      *(uint2*)(&P16[(16 + c) * 36 + 16 + q * 4]) = wv2;
    }
    __syncthreads();
    {
      uint2 lo0 = *(const uint2*)(&P16[c * 36 + q * 8]);
      uint2 hi0 = *(const uint2*)(&P16[c * 36 + q * 8 + 4]);
      uint4 u0; u0.x = lo0.x; u0.y = lo0.y; u0.z = hi0.x; u0.w = hi0.y;
      bfr[0] = __builtin_bit_cast(half8_t, u0);
      uint2 lo1 = *(const uint2*)(&P16[(16 + c) * 36 + q * 8]);
      uint2 hi1 = *(const uint2*)(&P16[(16 + c) * 36 + q * 8 + 4]);
      uint4 u1; u1.x = lo1.x; u1.y = lo1.y; u1.z = hi1.x; u1.w = hi1.y;
      bfr[1] = __builtin_bit_cast(half8_t, u1);
    }
  }
  __syncthreads();
  uint* gp = segP + (size_t)blk * 512;
  if (lane < 32) {
    int i = lane;
#pragma unroll
    for (int tp = 0; tp < 16; ++tp) {
      uint lo = (uint)__builtin_bit_cast(unsigned short, P16[(2 * tp) * 36 + i]);
      uint hi = (uint)__builtin_bit_cast(unsigned short, P16[(2 * tp + 1) * 36 + i]);
      gp[i * 16 + tp] = lo | (hi << 16);
    }
  }
  if (lane == 0) segL[blk] = Lacc;
}

// ---------------------------------------------------------------------------
// CRF stage B + numerator merged (verified)
// ---------------------------------------------------------------------------
__global__ __launch_bounds__(64) void crf_comb_kernel(
    const int* __restrict__ tags, const float* __restrict__ feats,
    const float* __restrict__ trans, const uint* __restrict__ segP,
    const float* __restrict__ segL, float* __restrict__ num,
    float* __restrict__ den)
{
  const float L2E = 1.4426950408889634f, LN2 = 0.6931471805599453f;
  int b = blockIdx.x, l = threadIdx.x;

  {
    const int* tb = tags + b * SEQ;
    float acc = 0.f;
    for (int s = l; s < SEQ; s += 64) {
      int tg = tb[s];
      int pv = (s == 0) ? START_TAG : tb[s - 1];
      acc += trans[pv * NTAG + tg] + feats[((size_t)b * SEQ + s) * NTAG + tg];
    }
#pragma unroll
    for (int msk = 1; msk < 64; msk <<= 1) acc += __shfl_xor(acc, msk);
    if (l == 0) num[b] = acc + trans[tb[SEQ - 1] * NTAG + END_TAG];
  }

  int i = l & 31, hp = l >> 5;
  const float* fb = feats + (size_t)b * SEQ * NTAG;

  float sT = 0.f;
  for (int p = 0; p < 32; ++p) sT += fexp2(trans[i * 32 + p] * L2E);
  float v = (1.f + sT) * fexp2(fb[i] * L2E);
  float L = -10000.f * L2E;

  float vo = __shfl_xor(v, 1);
  uint pv = (i & 1) ? packh2(vo, v) : packh2(v, vo);

  const uint* gp0 = segP + (size_t)b * 32 * 512 + i * 16 + hp * 8;
  uint4 ra = *(const uint4*)(gp0);
  uint4 rb = *(const uint4*)(gp0 + 4);

  for (int seg = 0; seg < 32; ++seg) {
    uint4 ca = ra, cb = rb;
    if (seg + 1 < 32) {
      ra = *(const uint4*)(gp0 + (seg + 1) * 512);
      rb = *(const uint4*)(gp0 + (seg + 1) * 512 + 4);
    }
    float g0 = __shfl(__builtin_bit_cast(float, pv), hp * 16 + 0);
    float g1 = __shfl(__builtin_bit_cast(float, pv), hp * 16 + 2);
    float g2 = __shfl(__builtin_bit_cast(float, pv), hp * 16 + 4);
    float g3 = __shfl(__builtin_bit_cast(float, pv), hp * 16 + 6);
    float g4 = __shfl(__builtin_bit_cast(float, pv), hp * 16 + 8);
    float g5 = __shfl(__builtin_bit_cast(float, pv), hp * 16 + 10);
    float g6 = __shfl(__builtin_bit_cast(float, pv), hp * 16 + 12);
    float g7 = __shfl(__builtin_bit_cast(float, pv), hp * 16 + 14);
    float acc = 0.f;
    acc = fdot2(__builtin_bit_cast(uint, g0), ca.x, acc);
    acc = fdot2(__builtin_bit_cast(uint, g1), ca.y, acc);
    acc = fdot2(__builtin_bit_cast(uint, g2), ca.z, acc);
    acc = fdot2(__builtin_bit_cast(uint, g3), ca.w, acc);
    acc = fdot2(__builtin_bit_cast(uint, g4), cb.x, acc);
    acc = fdot2(__builtin_bit_cast(uint, g5), cb.y, acc);
    acc = fdot2(__builtin_bit_cast(uint, g6), cb.z, acc);
    acc = fdot2(__builtin_bit_cast(uint, g7), cb.w, acc);
    float sm = acc + __shfl_xor(acc, 32);
    uint ub = (uint)__builtin_amdgcn_readfirstlane((int)__builtin_bit_cast(uint, sm));
    int e = (int)((ub >> 23) & 255u);
    L += (float)(e - 127) + segL[b * 32 + seg];
    float sc = __builtin_bit_cast(float, (uint)((254 - e) << 23));
    v = sm * sc;
    float vo2 = __shfl_xor(v, 1);
    pv = (i & 1) ? packh2(vo2, v) : packh2(v, vo2);
  }
  float wv = v * fexp2(trans[i * 32 + END_TAG] * L2E);
#pragma unroll
  for (int msk = 1; msk <= 16; msk <<= 1) wv += __shfl_xor(wv, msk);
  if (l == 0) den[b] = (L + flog2(wv)) * LN2;
}

__global__ __launch_bounds__(128) void final_kernel(
    const float* __restrict__ num, const float* __restrict__ den,
    float* __restrict__ out)
{
  int tid = threadIdx.x;
  float v = num[tid] - den[tid];
#pragma unroll
  for (int msk = 1; msk < 64; msk <<= 1) v += __shfl_xor(v, msk);
  __shared__ float tmp[2];
  if ((tid & 63) == 0) tmp[tid >> 6] = v;
  __syncthreads();
  if (tid == 0) out[0] = (tmp[0] + tmp[1]) * (1.f / 128.f);
}

// ---------------------------------------------------------------------------
// Workspace layouts. sentT (256KB) before hh; embedH (8.4MB) INSIDE the hh
// region (hh dead until lstm, which runs after gemmx in the big path; the
// small path's gemmx uses fp32 embed directly, so the clobber is harmless).
// Small (ws < 169MB): chunked gatex, 13 dispatches.
// Big  (ws >= 168820736): gatexAll = [34603008, 168820736); feats/segP/segL
// overlay it after lstm. 7 dispatches.
// ---------------------------------------------------------------------------
extern "C" void kernel_launch(void* const* d_in, const int* in_sizes, int n_in,
                              void* d_out, int out_size, void* d_ws, size_t ws_size,
                              hipStream_t stream)
{
  const int* sentence = (const int*)d_in[0];
  const int* tags = (const int*)d_in[1];
  const float* embed = (const float*)d_in[2];
  const float* Wihf = (const float*)d_in[3];
  const float* Whhf = (const float*)d_in[4];
  const float* bihf = (const float*)d_in[5];
  const float* bhhf = (const float*)d_in[6];
  const float* Wihb = (const float*)d_in[7];
  const float* Whhb = (const float*)d_in[8];
  const float* bihb = (const float*)d_in[9];
  const float* bhhb = (const float*)d_in[10];
  const float* Wout = (const float*)d_in[11];
  const float* bout = (const float*)d_in[12];
  const float* trans = (const float*)d_in[13];
  const float* h0 = (const float*)d_in[14];
  const float* c0 = (const float*)d_in[15];
  float* out = (float*)d_out;

  char* ws = (char*)d_ws;
  uint* wihI = (uint*)(ws + 0);
  uint* whh = (uint*)(ws + 262144);
  uint* woutp = (uint*)(ws + 524288);
  float* biasI = (float*)(ws + 540672);
  float* numb = (float*)(ws + 544768);
  float* denb = (float*)(ws + 545280);
  float* statec = (float*)(ws + 545792);
  int* sentT = (int*)(ws + 700416);
  uint* hh = (uint*)(ws + 1048576);
  uint* embH = (uint*)(ws + 1048576);   // overlays hh; dead before lstm
  uint* gatex = (uint*)(ws + 34603008);
  float* feats = (float*)(ws + 34603008);
  uint* segP = (uint*)(ws + 42991616);
  float* segL = (float*)(ws + 51380224);

  hipLaunchKernelGGL(prep_kernel, dim3(8980), dim3(256), 0, stream,
                     Wihf, Whhf, bihf, bhhf, Wihb, Whhb, bihb, bhhb, Wout,
                     sentence, embed, wihI, whh, woutp, biasI, sentT, embH);

  bool big = ws_size >= 168820736ull;
  if (big) {
    hipLaunchKernelGGL(gemmx_all_kernel, dim3(4096), dim3(256), 0, stream,
                       sentT, embH, wihI, biasI, gatex);
    hipLaunchKernelGGL(lstm_all_kernel, dim3(256), dim3(512), 0, stream,
                       gatex, whh, h0, c0, hh);
  } else {
    for (int c = 0; c < 4; ++c) {
      hipLaunchKernelGGL(gemmx_kernel, dim3(1024), dim3(256), 0, stream,
                         sentT, embed, wihI, biasI, gatex, c);
      hipLaunchKernelGGL(lstm_kernel, dim3(256), dim3(512), 0, stream,
                         gatex, whh, h0, c0, statec, hh, c);
    }
  }

  hipLaunchKernelGGL(outproj_kernel, dim3(1024), dim3(256), 0, stream,
                     hh, woutp, bout, feats);
  hipLaunchKernelGGL(crf_seg_kernel, dim3(4096), dim3(64), 0, stream,
                     feats, trans, segP, segL);
  hipLaunchKernelGGL(crf_comb_kernel, dim3(128), dim3(64), 0, stream,
                     tags, feats, trans, segP, segL, numb, denb);
  hipLaunchKernelGGL(final_kernel, dim3(1), dim3(128), 0, stream,
                     numb, denb, out);
}